// Round 9
// baseline (729.406 us; speedup 1.0000x reference)
//
#include <hip/hip_runtime.h>
#include <stdint.h>

// ---------------- geometry ----------------
// B=8, C=256, H=W=128, HW=16384, 4 heads of d_k=64
// idx: HS=WS=2<<idx, S=HS*HS, OH=OW=64>>idx, NSP=OH*OW
// gather:  q[s=(i,j)][d=(c,ohi,owi)] = Q[lo+c][ohi*HS+i][owi*WS+j], s=i*WS+j
// scatter: Y[lo+c][i*OH+ohi][j*OW+owi] = y[s][d]   (transposed vs gather!)
// NHWC buffers (Qn,Kn,Vn,Yn): element (p, c) at [p*256 + (c ^ ((p&7)<<3))]
// granule rule: 8-ch granule g of pixel p sits at granule slot (g ^ (p&7)).

#define DEVI static __device__ __forceinline__

typedef short bf8 __attribute__((ext_vector_type(8)));   // 8 bf16 (4 VGPRs)
typedef float f32x4 __attribute__((ext_vector_type(4)));

DEVI unsigned short f2bf(float f) {
  unsigned u = __builtin_bit_cast(unsigned, f);
  u = (u + 0x7fffu + ((u >> 16) & 1u)) >> 16;
  return (unsigned short)u;
}
DEVI float bf2f(unsigned short h) {
  unsigned u = ((unsigned)h) << 16;
  return __builtin_bit_cast(float, u);
}

DEVI void gload16(const void* g, void* l) {
  __builtin_amdgcn_global_load_lds(
      (const __attribute__((address_space(1))) unsigned int*)g,
      (__attribute__((address_space(3))) unsigned int*)l, 16, 0, 0);
}

// ---------------- ws layout (bytes) ----------------
static const size_t WB_OFF  = 0;                        // bf16 [3][256][256]
static const size_t WOB_OFF = 393216;                   // bf16 [256][2304] k=(e*256+c)
static const size_t QN_OFF  = 1572864;                  // bf16 NHWC-swz [8][16384][256]; co overlay after grams
static const size_t KN_OFF  = QN_OFF + 67108864;
static const size_t VN_OFF  = KN_OFF + 67108864;
static const size_t YN_OFF  = VN_OFF + 67108864;        // bf16 NHWC-swz (also part3 overlay)
static const size_t SC_OFF  = YN_OFF + 67108864;        // f32 scores idx0-2 (34944 floats used)
static const size_t PRB_OFF = SC_OFF + 2236928;         // bf16 probs (559232)
static const size_t BNP_OFF = PRB_OFF + 1118464;        // f32 [512][256][2]
static const size_t BNS_OFF = BNP_OFF + 4194304;        // f32 [2][256]
static const size_t ZP_OFF  = BNS_OFF + 2048;           // 256B zero page for OOB gloads
static const size_t WS_NEED = ZP_OFF + 256;

// ---------------- prep: convert weights to bf16 (wo reordered) ----------------
__global__ void k_prep(const float* __restrict__ wq, const float* __restrict__ wk,
                       const float* __restrict__ wv, const float* __restrict__ wo,
                       unsigned short* __restrict__ Wb, unsigned short* __restrict__ Wob) {
  int i = blockIdx.x * 256 + threadIdx.x;        // grid covers 786432 exactly
  if (i < 196608) {
    int z = i >> 16, r = i & 65535;
    const float* w = (z == 0) ? wq : (z == 1) ? wk : wv;
    Wb[i] = f2bf(w[r]);
  } else {
    int j = i - 196608;
    int o = j / 2304, k = j - o * 2304;
    int e = k >> 8, c = k & 255;
    Wob[j] = f2bf(wo[(o * 256 + c) * 9 + e]);    // Wob[o][e*256+c] = wo[o][c][e]
  }
}

__global__ void k_zero2(float* __restrict__ a, int na, float* __restrict__ b2, int nb) {
  int i = blockIdx.x * 256 + threadIdx.x;
  for (; i < na + nb; i += gridDim.x * 256) {
    if (i < na) a[i] = 0.f; else b2[i - na] = 0.f;
  }
}

// ---------------- fused QKV projection (R5 structure, 48KB LDS, 3 blk/CU) ----------------
__global__ __launch_bounds__(256, 3) void k_qkv(
    const float* __restrict__ x, const unsigned short* __restrict__ Wb,
    const float* __restrict__ bq, const float* __restrict__ bk, const float* __restrict__ bv,
    unsigned short* __restrict__ Qn, unsigned short* __restrict__ Kn,
    unsigned short* __restrict__ Vn) {
  const int pt = blockIdx.x, b = blockIdx.y;
  const int p0 = pt * 64;
  const int tid = threadIdx.x;

  __shared__ __align__(16) unsigned short xt[64 * 256];  // input tile [p][c'] swizzled 32KB
  __shared__ __align__(16) unsigned short ot[32 * 256];  // output chunk buffer 16KB

  const float* xb = x + (size_t)b * 256 * 16384;
  for (int k = 0; k < 16; ++k) {
    int i = tid + k * 256;
    int c = i >> 4, p4 = (i & 15) * 4;
    float4 v = *(const float4*)(xb + (size_t)c * 16384 + p0 + p4);
    xt[(p4 + 0) * 256 + (c ^ (((p4 + 0) & 7) << 3))] = f2bf(v.x);
    xt[(p4 + 1) * 256 + (c ^ (((p4 + 1) & 7) << 3))] = f2bf(v.y);
    xt[(p4 + 2) * 256 + (c ^ (((p4 + 2) & 7) << 3))] = f2bf(v.z);
    xt[(p4 + 3) * 256 + (c ^ (((p4 + 3) & 7) << 3))] = f2bf(v.w);
  }
  __syncthreads();

  const int wave = tid >> 6, lane = tid & 63;
  const int lr = lane & 15, lk = lane >> 4;
  const int obase = wave * 64;

  for (int z = 0; z < 3; ++z) {
    const unsigned short* Wz = Wb + (size_t)z * 65536;
    f32x4 acc[4][4];
    for (int m = 0; m < 4; ++m)
      for (int n = 0; n < 4; ++n)
        for (int r = 0; r < 4; ++r) acc[m][n][r] = 0.f;

    for (int ks = 0; ks < 8; ++ks) {
      int c0 = ks * 32 + lk * 8;
      bf8 a[4], bb[4];
#pragma unroll
      for (int m = 0; m < 4; ++m)
        a[m] = *(const bf8*)(Wz + (size_t)(obase + m * 16 + lr) * 256 + c0);
#pragma unroll
      for (int n = 0; n < 4; ++n) {
        int p = n * 16 + lr;
        bb[n] = *(const bf8*)(&xt[p * 256 + (c0 ^ ((p & 7) << 3))]);
      }
      __builtin_amdgcn_s_setprio(1);
#pragma unroll
      for (int m = 0; m < 4; ++m)
#pragma unroll
        for (int n = 0; n < 4; ++n)
          acc[m][n] = __builtin_amdgcn_mfma_f32_16x16x32_bf16(a[m], bb[n], acc[m][n], 0, 0, 0);
      __builtin_amdgcn_s_setprio(0);
    }

    const float* bias = (z == 0) ? bq : (z == 1) ? bk : bv;
    unsigned short* On = (z == 0) ? Qn : (z == 1) ? Kn : Vn;
    // epilogue in two 32-px chunks through the 16KB ot buffer
    for (int h = 0; h < 2; ++h) {
      __syncthreads();   // prior ot consumers done
#pragma unroll
      for (int m = 0; m < 4; ++m) {
        int ob4 = obase + m * 16 + lk * 4;
        float4 b4 = *(const float4*)(bias + ob4);
#pragma unroll
        for (int nn = 0; nn < 2; ++nn) {
          int n = h * 2 + nn;
          int pch = nn * 16 + lr;            // chunk-local pixel 0..31
          ushort4 v4;
          v4.x = f2bf(acc[m][n][0] + b4.x);
          v4.y = f2bf(acc[m][n][1] + b4.y);
          v4.z = f2bf(acc[m][n][2] + b4.z);
          v4.w = f2bf(acc[m][n][3] + b4.w);
          *(ushort4*)(&ot[pch * 256 + (ob4 ^ ((pch & 7) << 3))]) = v4;
        }
      }
      __syncthreads();
      unsigned short* gb = On + ((size_t)b * 16384 + p0 + h * 32) * 256;
#pragma unroll
      for (int i = 0; i < 4; ++i) {
        int ch = tid + i * 256;              // 1024 cells x 16B = 16KB
        *(uint4*)(gb + ch * 8) = *(const uint4*)(&ot[ch * 8]);
      }
    }
  }
}

// ---------------- Gram via MFMA, idx 0..2 ----------------
template <int IDX>
__global__ __launch_bounds__(256) void k_gram(
    const unsigned short* __restrict__ Qn, const unsigned short* __restrict__ Kn,
    float* __restrict__ scores) {
  constexpr int HS = 2 << IDX, S = HS * HS, OH = 64 >> IDX, NSP = OH * OH;
  constexpr int SPW = (IDX == 2) ? 2 : 8;
  constexpr int DSUB = SPW * 64;
  constexpr int SPB = NSP / 32;
  constexpr int STEPS = SPB / SPW;
  constexpr int ROWS = S;
  constexpr int TPT = S * SPW * 8 / 256;
  constexpr int SCOFF = (IDX == 0) ? 0 : (IDX == 1) ? 128 : 2176;
  constexpr int HC = IDX * 64;
  constexpr int MT = (IDX == 2) ? 4 : 1;

  const int chk = blockIdx.x, b = blockIdx.y;
  const int tid = threadIdx.x;
  const int wave = tid >> 6, lane = tid & 63, lr = lane & 15, lk = lane >> 4;

  __shared__ __align__(16) unsigned short qg[ROWS * DSUB];
  __shared__ __align__(16) unsigned short kg[ROWS * DSUB];
  __shared__ float red[S * S];

  const size_t base = (size_t)b * 16384 * 256;

  f32x4 acc[MT][MT];
  for (int m = 0; m < MT; ++m)
    for (int n = 0; n < MT; ++n)
      for (int r = 0; r < 4; ++r) acc[m][n][r] = 0.f;

  for (int st = 0; st < STEPS; ++st) {
    const int sp0 = chk * SPB + st * SPW;
    __syncthreads();
#pragma unroll
    for (int r = 0; r < TPT; ++r) {
      int task = tid + r * 256;
      int cg = task & 7, pl = task >> 3;
      int spl = pl >> (2 * (IDX + 1)), s = pl & (S - 1);
      int sp = sp0 + spl;
      int ohi = sp >> (6 - IDX), owi = sp & (OH - 1);
      int ii = s >> (IDX + 1), jj = s & (HS - 1);
      int p = (ohi * HS + ii) * 128 + owi * HS + jj;
      size_t gaddr = base + (size_t)p * 256 + HC + ((cg ^ (p & 7)) << 3);
      int laddr = s * DSUB + (((spl * 8 + cg) ^ (s & 7)) << 3);
      *(uint4*)(qg + laddr) = *(const uint4*)(Qn + gaddr);
      *(uint4*)(kg + laddr) = *(const uint4*)(Kn + gaddr);
    }
    __syncthreads();
    if (IDX == 2) {
      int kgid = wave * 4 + lk;
      bf8 a[4], bb[4];
#pragma unroll
      for (int m = 0; m < 4; ++m) {
        int row = m * 16 + lr;
        int off = row * DSUB + ((kgid ^ (row & 7)) << 3);
        a[m] = *(const bf8*)(qg + off);
        bb[m] = *(const bf8*)(kg + off);
      }
#pragma unroll
      for (int m = 0; m < 4; ++m)
#pragma unroll
        for (int n = 0; n < 4; ++n)
          acc[m][n] = __builtin_amdgcn_mfma_f32_16x16x32_bf16(a[m], bb[n], acc[m][n], 0, 0, 0);
    } else {
      int row = lr & (ROWS - 1);
#pragma unroll
      for (int kk = 0; kk < 4; ++kk) {
        int kgid = (wave * 4 + kk) * 4 + lk;
        int off = row * DSUB + ((kgid ^ (row & 7)) << 3);
        bf8 a = *(const bf8*)(qg + off);
        bf8 bb = *(const bf8*)(kg + off);
        acc[0][0] = __builtin_amdgcn_mfma_f32_16x16x32_bf16(a, bb, acc[0][0], 0, 0, 0);
      }
    }
  }

  __syncthreads();
  for (int i2 = tid; i2 < S * S; i2 += 256) red[i2] = 0.f;
  __syncthreads();
  if (IDX == 2) {
#pragma unroll
    for (int m = 0; m < 4; ++m)
#pragma unroll
      for (int n = 0; n < 4; ++n)
#pragma unroll
        for (int r = 0; r < 4; ++r)
          atomicAdd(&red[(m * 16 + lk * 4 + r) * 64 + n * 16 + lr], acc[m][n][r]);
  } else if (IDX == 1) {
#pragma unroll
    for (int r = 0; r < 4; ++r)
      atomicAdd(&red[(lk * 4 + r) * 16 + lr], acc[0][0][r]);
  } else {
    if (lk == 0 && lr < 4) {
#pragma unroll
      for (int r = 0; r < 4; ++r)
        atomicAdd(&red[r * 4 + lr], acc[0][0][r]);
    }
  }
  __syncthreads();
  float* sc = scores + SCOFF + (size_t)b * S * S;
  for (int i2 = tid; i2 < S * S; i2 += 256) atomicAdd(sc + i2, red[i2]);
}

// ---------------- Gram idx3: 256x256x4096 GEMM, partials ----------------
__global__ __launch_bounds__(256) void k_gram3(
    const unsigned short* __restrict__ Qn, const unsigned short* __restrict__ Kn,
    float* __restrict__ part3) {
  const int qc = blockIdx.x, tq = blockIdx.y, b = blockIdx.z;
  const int tid = threadIdx.x;
  const int wave = tid >> 6, lane = tid & 63, lr = lane & 15, lk = lane >> 4;

  __shared__ __align__(16) unsigned short qg[256 * 64];
  __shared__ __align__(16) unsigned short kg[64 * 64];

  const size_t base = (size_t)b * 16384 * 256;

  f32x4 acc[4][4];
  for (int m = 0; m < 4; ++m)
    for (int n = 0; n < 4; ++n)
      for (int r = 0; r < 4; ++r) acc[m][n][r] = 0.f;

  for (int st = 0; st < 8; ++st) {
    int sp = qc * 8 + st;
    int ohi = sp >> 3, owi = sp & 7;
    __syncthreads();
#pragma unroll
    for (int r = 0; r < 8; ++r) {
      int task = tid + r * 256;
      int cg = task & 7, s = task >> 3;
      int p = (ohi * 16 + (s >> 4)) * 128 + owi * 16 + (s & 15);
      uint4 v = *(const uint4*)(Qn + base + (size_t)p * 256 + 192 + ((cg ^ (p & 7)) << 3));
      *(uint4*)(qg + s * 64 + ((cg ^ (s & 7)) << 3)) = v;
    }
#pragma unroll
    for (int r = 0; r < 2; ++r) {
      int task = tid + r * 256;
      int cg = task & 7, tl = task >> 3;
      int p = (ohi * 16 + tq * 4 + (tl >> 4)) * 128 + owi * 16 + (tl & 15);
      uint4 v = *(const uint4*)(Kn + base + (size_t)p * 256 + 192 + ((cg ^ (p & 7)) << 3));
      *(uint4*)(kg + tl * 64 + ((cg ^ (tl & 7)) << 3)) = v;
    }
    __syncthreads();
#pragma unroll
    for (int kk = 0; kk < 2; ++kk) {
      int kgid = kk * 4 + lk;
      bf8 a[4], bb[4];
#pragma unroll
      for (int m = 0; m < 4; ++m) {
        int row = wave * 64 + m * 16 + lr;
        a[m] = *(const bf8*)(qg + row * 64 + ((kgid ^ (row & 7)) << 3));
      }
#pragma unroll
      for (int n = 0; n < 4; ++n) {
        int rowb = n * 16 + lr;
        bb[n] = *(const bf8*)(kg + rowb * 64 + ((kgid ^ (rowb & 7)) << 3));
      }
#pragma unroll
      for (int m = 0; m < 4; ++m)
#pragma unroll
        for (int n = 0; n < 4; ++n)
          acc[m][n] = __builtin_amdgcn_mfma_f32_16x16x32_bf16(a[m], bb[n], acc[m][n], 0, 0, 0);
    }
  }

  float* pb = part3 + (((size_t)qc * 8 + b) * 65536);
#pragma unroll
  for (int m = 0; m < 4; ++m)
#pragma unroll
    for (int r = 0; r < 4; ++r) {
      int srow = wave * 64 + m * 16 + lk * 4 + r;
#pragma unroll
      for (int n = 0; n < 4; ++n)
        pb[srow * 256 + tq * 64 + n * 16 + lr] = acc[m][n][r];
    }
}

// ---------------- softmax idx0-2 (fp32 scores -> bf16 probs) ----------------
__global__ __launch_bounds__(256) void k_softmax(const float* __restrict__ scores,
                                                 unsigned short* __restrict__ prb) {
  const int idx = blockIdx.x, b = blockIdx.y;
  const int S = 4 << (2 * idx);
  const int off = (idx == 0 ? 0 : idx == 1 ? 128 : 2176) + b * S * S;
  const int s = threadIdx.x;
  if (s >= S) return;
  const float scale = rsqrtf(64.0f * (float)(4096 >> (2 * idx)));
  const float* row = scores + off + s * S;
  float m = -1e30f;
  for (int t = 0; t < S; ++t) m = fmaxf(m, row[t]);
  m *= scale;
  float sum = 0.f;
  for (int t = 0; t < S; ++t) sum += __expf(row[t] * scale - m);
  float inv = 1.0f / sum;
  unsigned short* prow = prb + off + s * S;
  for (int t = 0; t < S; ++t) prow[t] = f2bf(__expf(row[t] * scale - m) * inv);
}

// ---------------- softmax idx3: sum 8 partials + softmax ----------------
__global__ __launch_bounds__(256) void k_softmax3(const float* __restrict__ part3,
                                                  unsigned short* __restrict__ prb) {
  const int sc_ = blockIdx.x, b = blockIdx.y;
  const int tid = threadIdx.x;
  const int s = sc_ * 32 + (tid >> 3);
  const int t0 = (tid & 7) * 32;
  float v[32];
#pragma unroll
  for (int k = 0; k < 32; ++k) v[k] = 0.f;
  for (int q = 0; q < 8; ++q) {
    const float4* pp = (const float4*)(part3 + (((size_t)q * 8 + b) * 256 + s) * 256 + t0);
#pragma unroll
    for (int k = 0; k < 8; ++k) {
      float4 u = pp[k];
      v[k * 4 + 0] += u.x; v[k * 4 + 1] += u.y; v[k * 4 + 2] += u.z; v[k * 4 + 3] += u.w;
    }
  }
  const float scale = 1.0f / 64.0f;
  float m = -1e30f;
#pragma unroll
  for (int k = 0; k < 32; ++k) { v[k] *= scale; m = fmaxf(m, v[k]); }
  m = fmaxf(m, __shfl_xor(m, 1));
  m = fmaxf(m, __shfl_xor(m, 2));
  m = fmaxf(m, __shfl_xor(m, 4));
  float sum = 0.f;
#pragma unroll
  for (int k = 0; k < 32; ++k) { v[k] = __expf(v[k] - m); sum += v[k]; }
  sum += __shfl_xor(sum, 1);
  sum += __shfl_xor(sum, 2);
  sum += __shfl_xor(sum, 4);
  float inv = 1.0f / sum;
  unsigned short* prw = prb + 34944 + (size_t)b * 65536 + s * 256 + t0;
#pragma unroll
  for (int k8 = 0; k8 < 4; ++k8) {
    unsigned short tmp[8];
#pragma unroll
    for (int e = 0; e < 8; ++e) tmp[e] = f2bf(v[k8 * 8 + e] * inv);
    *(uint4*)(prw + k8 * 8) = *(const uint4*)tmp;
  }
}

// ---------------- PV small S (idx 0,1,2): per-head, NHWC in/out ----------------
template <int IDX>
__global__ __launch_bounds__(256) void k_pv(
    const unsigned short* __restrict__ Vn, const unsigned short* __restrict__ prb,
    unsigned short* __restrict__ Yn) {
  constexpr int HS = 2 << IDX, S = HS * HS, OH = 64 >> IDX;
  constexpr int IT = (IDX == 0) ? 8 : (IDX == 1) ? 4 : 1;
  constexpr int POFF = (IDX == 0) ? 0 : (IDX == 1) ? 128 : 2176;
  const int bx = blockIdx.x, b = blockIdx.y;
  const int c = threadIdx.x & 63, spg = threadIdx.x >> 6;
  __shared__ __align__(16) float pl[S * S];
  const unsigned short* pr = prb + POFF + (size_t)b * S * S;
  for (int i = threadIdx.x; i < S * S; i += 256) pl[i] = bf2f(pr[i]);
  __syncthreads();
  const int hc = IDX * 64;
  const unsigned short* vb = Vn + (size_t)b * 16384 * 256;
  unsigned short* yb = Yn + (size_t)b * 16384 * 256;
  for (int it = 0; it < IT; ++it) {
    int sp = bx * (4 * IT) + it * 4 + spg;
    int ohi = sp >> (6 - IDX), owi = sp & (OH - 1);
    float v[S];
#pragma unroll
    for (int t = 0; t < S; ++t) {
      int po = (ohi * HS + t / HS) * 128 + owi * HS + (t % HS);
      v[t] = bf2f(vb[(size_t)po * 256 + ((hc + c) ^ ((po & 7) << 3))]);
    }
    for (int s = 0; s < S; ++s) {
      const float4* p4 = (const float4*)(pl + s * S);
      float a = 0.f;
#pragma unroll
      for (int t4 = 0; t4 < S / 4; ++t4) {
        float4 pp = p4[t4];
        a += pp.x * v[t4 * 4] + pp.y * v[t4 * 4 + 1] + pp.z * v[t4 * 4 + 2] + pp.w * v[t4 * 4 + 3];
      }
      int po = ((s >> (IDX + 1)) * OH + ohi) * 128 + (s & (HS - 1)) * OH + owi;
      yb[(size_t)po * 256 + ((hc + c) ^ ((po & 7) << 3))] = f2bf(a);
    }
  }
}

// ---------------- PV idx3 (S=256): MFMA GEMM per (b, sp) ----------------
__global__ __launch_bounds__(256) void k_pv3(
    const unsigned short* __restrict__ Vn, const unsigned short* __restrict__ prb,
    unsigned short* __restrict__ Yn) {
  const int sp = blockIdx.x, b = blockIdx.y;
  const int ohi = sp >> 3, owi = sp & 7;
  const int tid = threadIdx.x;
  __shared__ __align__(16) unsigned short vl[64 * 256];
  const unsigned short* vb = Vn + (size_t)b * 16384 * 256;
  {
    int t = tid;
    int po = (ohi * 16 + (t >> 4)) * 128 + owi * 16 + (t & 15);
    const unsigned short* src = vb + (size_t)po * 256;
    int xv = (po & 7) << 3;
#pragma unroll
    for (int g = 0; g < 8; ++g) {
      ushort4 lo = *(const ushort4*)(src + ((192 + g * 8) ^ xv));
      ushort4 hi = *(const ushort4*)(src + ((192 + g * 8) ^ xv) + 4);
      unsigned short vv[8] = {lo.x, lo.y, lo.z, lo.w, hi.x, hi.y, hi.z, hi.w};
#pragma unroll
      for (int e = 0; e < 8; ++e) {
        int cc = g * 8 + e;
        vl[cc * 256 + (t ^ ((cc & 7) << 3))] = vv[e];
      }
    }
  }
  __syncthreads();

  const int wave = tid >> 6, lane = tid & 63;
  const int lr = lane & 15, lk = lane >> 4;
  const int sb = wave * 64;
  const unsigned short* pr = prb + 34944 + (size_t)b * 65536;

  f32x4 acc[4][4];
  for (int m = 0; m < 4; ++m)
    for (int n = 0; n < 4; ++n)
      for (int r = 0; r < 4; ++r) acc[m][n][r] = 0.f;

  for (int kk = 0; kk < 8; ++kk) {
    int t0 = kk * 32 + lk * 8;
    bf8 a[4], bb[4];
#pragma unroll
    for (int m = 0; m < 4; ++m)
      a[m] = *(const bf8*)(pr + (size_t)(sb + m * 16 + lr) * 256 + t0);
#pragma unroll
    for (int n = 0; n < 4; ++n) {
      int cc = n * 16 + lr;
      bb[n] = *(const bf8*)(&vl[cc * 256 + (t0 ^ ((cc & 7) << 3))]);
    }
#pragma unroll
    for (int m = 0; m < 4; ++m)
#pragma unroll
      for (int n = 0; n < 4; ++n)
        acc[m][n] = __builtin_amdgcn_mfma_f32_16x16x32_bf16(a[m], bb[n], acc[m][n], 0, 0, 0);
  }

  unsigned short* yb = Yn + (size_t)b * 16384 * 256;
#pragma unroll
  for (int m = 0; m < 4; ++m) {
#pragma unroll
    for (int r = 0; r < 4; ++r) {
      int s = sb + m * 16 + lk * 4 + r;
      int si = s >> 4, sj = s & 15;
      int po = (si * 8 + ohi) * 128 + sj * 8 + owi;
#pragma unroll
      for (int n = 0; n < 4; ++n) {
        int cc = 192 + n * 16 + lr;
        yb[(size_t)po * 256 + (cc ^ (owi << 3))] = f2bf(acc[m][n][r]);
      }
    }
  }
}

// ---------------- 3x3 conv: 256x256x2304 GEMM, 8-slot ring ----------------
// e-outer loop (dy/dx scalar, KT&3 and parity constexpr); per-lane address
// invariants hoisted; A and B fragments register-cached (B0@r0 reused r2,
// B1@r1 reused r3). Stage order [A0,B0,B1,A1], vmcnt(6): first-use dist >=3,
// slot-overwrite last-reader at P-4. One barrier/phase.
#define CPHASE(Q_, R_, DOSTAGE_, WM_)                                            \
  do {                                                                           \
    constexpr int PK_ = (Q_) & 1;                                                \
    if (DOSTAGE_) {                                                              \
      constexpr int QN_ = ((Q_) + 1) & 3;                                        \
      constexpr bool NE_ = ((Q_) == 3);                                          \
      const int sdy = NE_ ? dyN : dy, sdx = NE_ ? dxN : dx;                      \
      const int se = NE_ ? (e + 1) : e;                                          \
      constexpr int slot_ = (1 - PK_) * 4 + (R_);                                \
      if ((R_) == 0) STAGE_A(slot_, 0, se, QN_);                                 \
      else if ((R_) == 1) STAGE_B(slot_, 0, sdy, sdx, QN_);                      \
      else if ((R_) == 2) STAGE_B(slot_, 1, sdy, sdx, QN_);                      \
      else STAGE_A(slot_, 1, se, QN_);                                           \
    }                                                                            \
    if ((WM_) == 0) { asm volatile("s_waitcnt vmcnt(6)" ::: "memory"); }         \
    else if ((WM_) == 1) { asm volatile("s_waitcnt vmcnt(0)" ::: "memory"); }    \
    __builtin_amdgcn_s_barrier();                                                \
    asm volatile("" ::: "memory");                                               \
    {                                                                            \
      constexpr int mh_ = (R_) >> 1, nh_ = (R_) & 1;                             \
      if (nh_ == 0) {                                                            \
        constexpr int sA_ = PK_ * 4 + (mh_ ? 3 : 0);                             \
        _Pragma("unroll") for (int m2 = 0; m2 < 4; ++m2) {                       \
          int row = wm * 64 + m2 * 16 + lr;                                      \
          _Pragma("unroll") for (int kk = 0; kk < 2; ++kk)                       \
            areg[m2][kk] = *(const bf8*)(&lds[sA_][row * 64 +                    \
                (((kk * 4 + lk) ^ (row & 7)) << 3)]);                            \
        }                                                                        \
      }                                                                          \
      if ((R_) < 2) {                                                            \
        constexpr int sB_ = PK_ * 4 + ((R_) ? 2 : 1);                            \
        _Pragma("unroll") for (int n2 = 0; n2 < 2; ++n2) {                       \
          int row = wn * 32 + n2 * 16 + lr;                                      \
          _Pragma("unroll") for (int kk = 0; kk < 2; ++kk)                       \
            breg[R_][n2][kk] = *(const bf8*)(&lds[sB_][row * 64 +                \
                (((kk * 4 + lk) ^ (row & 7)) << 3)]);                            \
        }                                                                        \
      }                                                                          \
      __builtin_amdgcn_s_setprio(1);                                             \
      _Pragma("unroll") for (int kk = 0; kk < 2; ++kk)                           \
        _Pragma("unroll") for (int m2 = 0; m2 < 4; ++m2)                         \
          _Pragma("unroll") for (int n2 = 0; n2 < 2; ++n2)                       \
            acc[mh_ * 4 + m2][nh_ * 2 + n2] =                                    \
                __builtin_amdgcn_mfma_f32_16x16x32_bf16(                         \
                    areg[m2][kk], breg[nh_][n2][kk],                             \
                    acc[mh_ * 4 + m2][nh_ * 2 + n2], 0, 0, 0);                   \
      __builtin_amdgcn_s_setprio(0);                                             \
      asm volatile("" ::: "memory");                                             \
    }                                                                            \
  } while (0)

__global__ __launch_bounds__(512, 2) void k_conv(
    const unsigned short* __restrict__ Yn, const unsigned short* __restrict__ Wob,
    const float* __restrict__ bo, const unsigned short* __restrict__ zp,
    unsigned short* __restrict__ co, float* __restrict__ bnp) {
  __shared__ __align__(16) unsigned short lds[8][8192];  // 8 x 16KB half-tile slots

  const int bid = blockIdx.x;
  const int swz = (bid & 7) * 64 + (bid >> 3);   // XCD-chunked, bijective (512=8*64)
  const int b = swz >> 6, tile = swz & 63;
  const int y0 = (tile >> 3) * 16, x0 = (tile & 7) * 16;
  const int tid = threadIdx.x;
  const int wave = tid >> 6, lane = tid & 63;
  const int lr = lane & 15, lk = lane >> 4;
  const int wm = wave >> 2, wn = wave & 3;
  const int cg = lane & 7;

  const unsigned short* yb = Yn + (size_t)b * 16384 * 256;

  // ---- per-lane staging invariants ----
  const int rp0 = wave * 16 + (lane >> 3), rp1 = rp0 + 8;
  const int kg0 = cg ^ (rp0 & 7), kg1 = cg ^ (rp1 & 7);
  const int aoffA0 = ((rp0 >> 6) * 128 + (rp0 & 63)) * 2304 + kg0 * 8;
  const int aoffA1 = ((rp1 >> 6) * 128 + (rp1 & 63)) * 2304 + kg1 * 8;
  const int n00 = ((rp0 >> 5) & 3) * 64 + (rp0 & 31);
  const int n01 = ((rp1 >> 5) & 3) * 64 + (rp1 & 31);
  const int hB0 = y0 + (n00 >> 4), wB0 = x0 + (n00 & 15);
  const int hB1 = y0 + (n01 >> 4), wB1 = x0 + (n01 & 15);
  const int ppB0 = hB0 * 128 + wB0, ppB1 = hB1 * 128 + wB1;
  const int ld0 = (wave * 2 + 0) * 512, ld1 = (wave * 2 + 1) * 512;

  auto STAGE_A = [&](int slot, int T, int eS, int qS) {
    const unsigned short* basep = Wob + eS * 256 + qS * 64 + T * 147456;
    gload16(basep + aoffA0, &lds[slot][ld0]);
    gload16(basep + aoffA1, &lds[slot][ld1]);
  };
  auto STAGE_B = [&](int slot, int T3, int dyS, int dxS, int qS) {
    const int so = dyS * 128 + dxS + T3 * 256;
    const int hS = dyS + T3 * 2;
    const int q8 = qS * 8;
    {
      int pp = ppB0 + so;
      int h = hB0 + hS, w = wB0 + dxS;
      const unsigned short* s1 = yb + (ptrdiff_t)pp * 256 + ((q8 + (kg0 ^ (pp & 7))) << 3);
      const unsigned short* src = ((unsigned)h < 128u && (unsigned)w < 128u) ? s1 : zp;
      gload16(src, &lds[slot][ld0]);
    }
    {
      int pp = ppB1 + so;
      int h = hB1 + hS, w = wB1 + dxS;
      const unsigned short* s1 = yb + (ptrdiff_t)pp * 256 + ((q8 + (kg1 ^ (pp & 7))) << 3);
      const unsigned short* src = ((unsigned)h < 128u && (unsigned)w < 128u) ? s1 : zp;
      gload16(src, &lds[slot][ld1]);
    }
  };

  f32x4 acc[8][4];
#pragma unroll
  for (int m = 0; m < 8; ++m)
#pragma unroll
    for (int n = 0; n < 4; ++n)
#pragma unroll
      for (int r = 0; r < 4; ++r) acc[m][n][r] = 0.f;

  bf8 areg[4][2];
  bf8 breg[2][2][2];

  // prologue: all 4 halves of KT0 (e=0: dy=-1,dx=-1), drain once
  STAGE_A(0, 0, 0, 0); STAGE_B(1, 0, -1, -1, 0); STAGE_B(2, 1, -1, -1, 0); STAGE_A(3, 1, 0, 0);
  asm volatile("s_waitcnt vmcnt(0)" ::: "memory");

  int dy = -1, dx = -1;
  for (int e = 0; e < 8; ++e) {      // KT 0..31
    int dyN = ((e + 1) >= 6) ? 1 : (((e + 1) >= 3) ? 0 : -1);
    int dxN = (e + 1) - (dyN + 1) * 3 - 1;
    CPHASE(0, 0, true, 0); CPHASE(0, 1, true, 0); CPHASE(0, 2, true, 0); CPHASE(0, 3, true, 0);
    CPHASE(1, 0, true, 0); CPHASE(1, 1, true, 0); CPHASE(1, 2, true, 0); CPHASE(1, 3, true, 0);
    CPHASE(2, 0, true, 0); CPHASE(2, 1, true, 0); CPHASE(2, 2, true, 0); CPHASE(2, 3, true, 0);
    CPHASE(3, 0, true, 0); CPHASE(3, 1, true, 0); CPHASE(3, 2, true, 0); CPHASE(3, 3, true, 0);
    dy = dyN; dx = dxN;
  }
  {                                   // tail e=8: KT 32..35 (dy=dx=1)
    const int e = 8;
    const int dyN = 1, dxN = 1;
    CPHASE(0, 0, true, 0); CPHASE(0, 1, true, 0); CPHASE(0, 2, true, 0); CPHASE(0, 3, true, 0);
    CPHASE(1, 0, true, 0); CPHASE(1, 1, true, 0); CPHASE(1, 2, true, 0); CPHASE(1, 3, true, 0);
    CPHASE(2, 0, true, 0); CPHASE(2, 1, true, 0); CPHASE(2, 2, true, 0); CPHASE(2, 3, true, 0);
    CPHASE(3, 0, false, 1); CPHASE(3, 1, false, 2); CPHASE(3, 2, false, 2); CPHASE(3, 3, false, 2);
  }

  __syncthreads();
  // epilogue: bias + bf16 out write (planar) + BN partials (exact f32 stats)
  unsigned short* cb = co + (size_t)b * 256 * 16384;
  float* red1 = (float*)&lds[0][0];     // [8][128]
  float* red2 = red1 + 1024;
#pragma unroll
  for (int m = 0; m < 8; ++m) {
#pragma unroll
    for (int r = 0; r < 4; ++r) {
      int o = wm * 128 + m * 16 + lk * 4 + r;
      float bvv = bo[o];
      float s1 = 0.f, s2 = 0.f;
#pragma unroll
      for (int n = 0; n < 4; ++n) {
        int pix = wn * 64 + n * 16 + lr;
        int py = pix >> 4, px = pix & 15;
        float v = acc[m][n][r] + bvv;
        cb[(size_t)o * 16384 + (y0 + py) * 128 + x0 + px] = f2bf(v);
        s1 += v;
        s2 += v * v;
      }
      for (int off = 1; off < 16; off <<= 1) {
        s1 += __shfl_xor(s1, off, 64);
        s2 += __shfl_xor(s2, off, 64);
      }
      if (lr == 0) {
        int ol = m * 16 + lk * 4 + r;
        red1[wave * 128 + ol] = s1;
        red2[wave * 128 + ol] = s2;
      }
    }
  }
  __syncthreads();
  {
    int o = tid & 255, stat = tid >> 8;
    int wm2 = o >> 7, ol = o & 127;
    const float* rd = stat ? red2 : red1;
    float s = rd[(wm2 * 4 + 0) * 128 + ol] + rd[(wm2 * 4 + 1) * 128 + ol] +
              rd[(wm2 * 4 + 2) * 128 + ol] + rd[(wm2 * 4 + 3) * 128 + ol];
    bnp[((size_t)(b * 64 + tile) * 256 + o) * 2 + stat] = s;
  }
}

// ---------------- BN reduce + apply ----------------
__global__ __launch_bounds__(256) void k_bnred(
    const float* __restrict__ bnp, const float* __restrict__ gamma,
    const float* __restrict__ beta, float* __restrict__ bns) {
  const int o = blockIdx.x;
  const int tid = threadIdx.x;
  float s1 = 0.f, s2 = 0.f;
  for (int k = tid; k < 512; k += 256) {
    s1 += bnp[((size_t)k * 256 + o) * 2 + 0];
    s2 += bnp[((size_t)k * 256 + o) * 2 + 1];
  }
  __shared__ float r1[256], r2[256];
  r1[tid] = s1; r2[tid] = s2;
  __syncthreads();
  for (int off = 128; off > 0; off >>= 1) {
    if (tid < off) { r1[tid] += r1[tid + off]; r2[tid] += r2[tid + off]; }
    __syncthreads();
  }
  if (tid == 0) {
    const float cnt = 8.0f * 16384.0f;
    float mean = r1[0] / cnt;
    float var = r2[0] / cnt - mean * mean;
    float sc = gamma[o] * rsqrtf(var + 1e-5f);
    bns[o] = sc;
    bns[256 + o] = beta[o] - mean * sc;
  }
}

__global__ void k_bnapply(const unsigned short* __restrict__ co, float* __restrict__ out,
                          const float* __restrict__ bns) {
  size_t i = ((size_t)blockIdx.x * 256 + threadIdx.x) * 8;
  const size_t total = 33554432;
  const size_t stride = (size_t)gridDim.x * 256 * 8;
  for (; i < total; i += stride) {
    uint4 v = *(const uint4*)(co + i);
    int o = (int)((i >> 14) & 255);
    float sc = bns[o], shv = bns[256 + o];
    const unsigned short* pv = (const unsigned short*)&v;
    float r[8];
#pragma unroll
    for (int e = 0; e < 8; ++e) {
      float f = bf2f(pv[e]) * sc + shv;
      r[e] = f > 0.f ? f : 0.2f * f;
    }
    *(float4*)(out + i) = *(const float4*)&r[0];
    *(float4*)(out + i + 4) = *(const float4*)&r[4];
  }
}

// ---------------- launcher ----------------
extern "C" void kernel_launch(void* const* d_in, const int* in_sizes, int n_in,
                              void* d_out, int out_size, void* d_ws, size_t ws_size,
                              hipStream_t stream) {
  if (ws_size < WS_NEED) return;

  const float* x     = (const float*)d_in[0];
  const float* wq    = (const float*)d_in[1];
  const float* bq    = (const float*)d_in[2];
  const float* wk    = (const float*)d_in[3];
  const float* bk    = (const float*)d_in[4];
  const float* wv    = (const float*)d_in[5];
  const float* bv    = (const float*)d_in[6];
  const float* wo    = (const float*)d_in[7];
  const float* bo    = (const float*)d_in[8];
  const float* gamma = (const float*)d_in[9];
  const float* beta  = (const float*)d_in[10];
  float* out = (float*)d_out;
  char* ws = (char*)d_ws;

  unsigned short* Wb  = (unsigned short*)(ws + WB_OFF);
  unsigned short* Wob = (unsigned short*)(ws + WOB_OFF);
  unsigned short* Qn  = (unsigned short*)(ws + QN_OFF);
  unsigned short* Kn  = (unsigned short*)(ws + KN_OFF);
  unsigned short* Vn  = (unsigned short*)(ws + VN_OFF);
  unsigned short* Yn  = (unsigned short*)(ws + YN_OFF);
  float* part3 = (float*)(ws + YN_OFF);          // overlay: used before Yn is written
  unsigned short* co = (unsigned short*)(ws + QN_OFF);  // overlay: Qn dead after grams
  float* scores = (float*)(ws + SC_OFF);
  unsigned short* prb = (unsigned short*)(ws + PRB_OFF);
  float* bnp    = (float*)(ws + BNP_OFF);
  float* bns    = (float*)(ws + BNS_OFF);
  unsigned short* zp = (unsigned short*)(ws + ZP_OFF);

  k_prep<<<dim3(3072), dim3(256), 0, stream>>>(wq, wk, wv, wo, Wb, Wob);
  k_zero2<<<dim3(137), dim3(256), 0, stream>>>(scores, 34944, (float*)zp, 64);
  k_qkv<<<dim3(256, 8), dim3(256), 0, stream>>>(x, Wb, bq, bk, bv, Qn, Kn, Vn);
  k_gram<0><<<dim3(32, 8), dim3(256), 0, stream>>>(Qn, Kn, scores);
  k_gram<1><<<dim3(32, 8), dim3(256), 0, stream>>>(Qn, Kn, scores);
  k_gram<2><<<dim3(32, 8), dim3(256), 0, stream>>>(Qn, Kn, scores);
  k_gram3<<<dim3(8, 4, 8), dim3(256), 0, stream>>>(Qn, Kn, part3);
  k_softmax<<<dim3(3, 8), dim3(256), 0, stream>>>(scores, prb);
  k_softmax3<<<dim3(8, 8), dim3(256), 0, stream>>>(part3, prb);
  k_pv<0><<<dim3(128, 8), dim3(256), 0, stream>>>(Vn, prb, Yn);
  k_pv<1><<<dim3(64, 8), dim3(256), 0, stream>>>(Vn, prb, Yn);
  k_pv<2><<<dim3(64, 8), dim3(256), 0, stream>>>(Vn, prb, Yn);
  k_pv3<<<dim3(64, 8), dim3(256), 0, stream>>>(Vn, prb, Yn);
  k_conv<<<dim3(512), dim3(512), 0, stream>>>(Yn, Wob, bo, zp, co, bnp);
  k_bnred<<<dim3(256), dim3(256), 0, stream>>>(bnp, gamma, beta, bns);
  k_bnapply<<<dim3(4096), dim3(256), 0, stream>>>(co, out, bns);
}

// Round 10
// 551.726 us; speedup vs baseline: 1.3220x; 1.3220x over previous
//
#include <hip/hip_runtime.h>
#include <stdint.h>

// ---------------- geometry ----------------
// B=8, C=256, H=W=128, HW=16384, 4 heads of d_k=64
// idx: HS=WS=2<<idx, S=HS*HS, OH=OW=64>>idx, NSP=OH*OW
// gather:  q[s=(i,j)][d=(c,ohi,owi)] = Q[lo+c][ohi*HS+i][owi*WS+j], s=i*WS+j
// scatter: Y[lo+c][i*OH+ohi][j*OW+owi] = y[s][d]   (transposed vs gather!)
// NHWC buffers (Qn,Kn,Vn,Yn): element (p, c) at [p*256 + (c ^ ((p&7)<<3))]
// granule rule: 8-ch granule g of pixel p sits at granule slot (g ^ (p&7)).

#define DEVI static __device__ __forceinline__

typedef short bf8 __attribute__((ext_vector_type(8)));   // 8 bf16 (4 VGPRs)
typedef float f32x4 __attribute__((ext_vector_type(4)));

DEVI unsigned short f2bf(float f) {
  unsigned u = __builtin_bit_cast(unsigned, f);
  u = (u + 0x7fffu + ((u >> 16) & 1u)) >> 16;
  return (unsigned short)u;
}
DEVI float bf2f(unsigned short h) {
  unsigned u = ((unsigned)h) << 16;
  return __builtin_bit_cast(float, u);
}

DEVI void gload16(const void* g, void* l) {
  __builtin_amdgcn_global_load_lds(
      (const __attribute__((address_space(1))) unsigned int*)g,
      (__attribute__((address_space(3))) unsigned int*)l, 16, 0, 0);
}

// ---------------- ws layout (bytes) ----------------
static const size_t WB_OFF  = 0;                        // bf16 [3][256][256]
static const size_t WOB_OFF = 393216;                   // bf16 [256][2304] k=(e*256+c)
static const size_t QN_OFF  = 1572864;                  // bf16 NHWC-swz [8][16384][256]; co overlay after grams
static const size_t KN_OFF  = QN_OFF + 67108864;
static const size_t VN_OFF  = KN_OFF + 67108864;
static const size_t YN_OFF  = VN_OFF + 67108864;        // bf16 NHWC-swz (also part3 overlay)
static const size_t SC_OFF  = YN_OFF + 67108864;        // f32 scores idx0-2 (34944 floats used)
static const size_t PRB_OFF = SC_OFF + 2236928;         // bf16 probs (559232)
static const size_t BNP_OFF = PRB_OFF + 1118464;        // f32 [512][256][2]
static const size_t BNS_OFF = BNP_OFF + 4194304;        // f32 [2][256]
static const size_t ZP_OFF  = BNS_OFF + 2048;           // 256B zero page for OOB gloads
static const size_t WS_NEED = ZP_OFF + 256;

// ---------------- prep: convert weights to bf16 (wo reordered) ----------------
__global__ void k_prep(const float* __restrict__ wq, const float* __restrict__ wk,
                       const float* __restrict__ wv, const float* __restrict__ wo,
                       unsigned short* __restrict__ Wb, unsigned short* __restrict__ Wob) {
  int i = blockIdx.x * 256 + threadIdx.x;        // grid covers 786432 exactly
  if (i < 196608) {
    int z = i >> 16, r = i & 65535;
    const float* w = (z == 0) ? wq : (z == 1) ? wk : wv;
    Wb[i] = f2bf(w[r]);
  } else {
    int j = i - 196608;
    int o = j / 2304, k = j - o * 2304;
    int e = k >> 8, c = k & 255;
    Wob[j] = f2bf(wo[(o * 256 + c) * 9 + e]);    // Wob[o][e*256+c] = wo[o][c][e]
  }
}

__global__ void k_zero2(float* __restrict__ a, int na, float* __restrict__ b2, int nb) {
  int i = blockIdx.x * 256 + threadIdx.x;
  for (; i < na + nb; i += gridDim.x * 256) {
    if (i < na) a[i] = 0.f; else b2[i - na] = 0.f;
  }
}

// ---------------- fused QKV projection (48KB LDS, 3 blk/CU) ----------------
// staging: lane = pixel, wave-strided c-quads -> coalesced global reads +
// ds_write_b64 packed LDS writes (granule-XOR spread, ~8-way vs old 16-way scalar)
__global__ __launch_bounds__(256, 3) void k_qkv(
    const float* __restrict__ x, const unsigned short* __restrict__ Wb,
    const float* __restrict__ bq, const float* __restrict__ bk, const float* __restrict__ bv,
    unsigned short* __restrict__ Qn, unsigned short* __restrict__ Kn,
    unsigned short* __restrict__ Vn) {
  const int pt = blockIdx.x, b = blockIdx.y;
  const int p0 = pt * 64;
  const int tid = threadIdx.x;

  __shared__ __align__(16) unsigned short xt[64 * 256];  // input tile [p][c'] swizzled 32KB
  __shared__ __align__(16) unsigned short ot[32 * 256];  // output chunk buffer 16KB

  const int wave = tid >> 6, lane = tid & 63;

  {
    const float* xb = x + (size_t)b * 256 * 16384 + p0;
    const int xsw = (lane & 7) << 3;
#pragma unroll
    for (int it = 0; it < 16; ++it) {
      int c4 = (it * 4 + wave) * 4;          // c4 covers {0,4,...,252} exactly once
      unsigned short tmp[4];
#pragma unroll
      for (int j = 0; j < 4; ++j)
        tmp[j] = f2bf(xb[(size_t)(c4 + j) * 16384 + lane]);
      *(ushort4*)(&xt[lane * 256 + (c4 ^ xsw)]) = *(const ushort4*)tmp;
    }
  }
  __syncthreads();

  const int lr = lane & 15, lk = lane >> 4;
  const int obase = wave * 64;

  for (int z = 0; z < 3; ++z) {
    const unsigned short* Wz = Wb + (size_t)z * 65536;
    f32x4 acc[4][4];
    for (int m = 0; m < 4; ++m)
      for (int n = 0; n < 4; ++n)
        for (int r = 0; r < 4; ++r) acc[m][n][r] = 0.f;

    for (int ks = 0; ks < 8; ++ks) {
      int c0 = ks * 32 + lk * 8;
      bf8 a[4], bb[4];
#pragma unroll
      for (int m = 0; m < 4; ++m)
        a[m] = *(const bf8*)(Wz + (size_t)(obase + m * 16 + lr) * 256 + c0);
#pragma unroll
      for (int n = 0; n < 4; ++n) {
        int p = n * 16 + lr;
        bb[n] = *(const bf8*)(&xt[p * 256 + (c0 ^ ((p & 7) << 3))]);
      }
      __builtin_amdgcn_s_setprio(1);
#pragma unroll
      for (int m = 0; m < 4; ++m)
#pragma unroll
        for (int n = 0; n < 4; ++n)
          acc[m][n] = __builtin_amdgcn_mfma_f32_16x16x32_bf16(a[m], bb[n], acc[m][n], 0, 0, 0);
      __builtin_amdgcn_s_setprio(0);
    }

    const float* bias = (z == 0) ? bq : (z == 1) ? bk : bv;
    unsigned short* On = (z == 0) ? Qn : (z == 1) ? Kn : Vn;
    // epilogue in two 32-px chunks through the 16KB ot buffer
    for (int h = 0; h < 2; ++h) {
      __syncthreads();   // prior ot consumers done
#pragma unroll
      for (int m = 0; m < 4; ++m) {
        int ob4 = obase + m * 16 + lk * 4;
        float4 b4 = *(const float4*)(bias + ob4);
#pragma unroll
        for (int nn = 0; nn < 2; ++nn) {
          int n = h * 2 + nn;
          int pch = nn * 16 + lr;            // chunk-local pixel 0..31
          ushort4 v4;
          v4.x = f2bf(acc[m][n][0] + b4.x);
          v4.y = f2bf(acc[m][n][1] + b4.y);
          v4.z = f2bf(acc[m][n][2] + b4.z);
          v4.w = f2bf(acc[m][n][3] + b4.w);
          *(ushort4*)(&ot[pch * 256 + (ob4 ^ ((pch & 7) << 3))]) = v4;
        }
      }
      __syncthreads();
      unsigned short* gb = On + ((size_t)b * 16384 + p0 + h * 32) * 256;
#pragma unroll
      for (int i = 0; i < 4; ++i) {
        int ch = tid + i * 256;              // 1024 cells x 16B = 16KB
        *(uint4*)(gb + ch * 8) = *(const uint4*)(&ot[ch * 8]);
      }
    }
  }
}

// ---------------- Gram via MFMA, idx 0..2 ----------------
template <int IDX>
__global__ __launch_bounds__(256) void k_gram(
    const unsigned short* __restrict__ Qn, const unsigned short* __restrict__ Kn,
    float* __restrict__ scores) {
  constexpr int HS = 2 << IDX, S = HS * HS, OH = 64 >> IDX, NSP = OH * OH;
  constexpr int SPW = (IDX == 2) ? 2 : 8;
  constexpr int DSUB = SPW * 64;
  constexpr int SPB = NSP / 32;
  constexpr int STEPS = SPB / SPW;
  constexpr int ROWS = S;
  constexpr int TPT = S * SPW * 8 / 256;
  constexpr int SCOFF = (IDX == 0) ? 0 : (IDX == 1) ? 128 : 2176;
  constexpr int HC = IDX * 64;
  constexpr int MT = (IDX == 2) ? 4 : 1;

  const int chk = blockIdx.x, b = blockIdx.y;
  const int tid = threadIdx.x;
  const int wave = tid >> 6, lane = tid & 63, lr = lane & 15, lk = lane >> 4;

  __shared__ __align__(16) unsigned short qg[ROWS * DSUB];
  __shared__ __align__(16) unsigned short kg[ROWS * DSUB];
  __shared__ float red[S * S];

  const size_t base = (size_t)b * 16384 * 256;

  f32x4 acc[MT][MT];
  for (int m = 0; m < MT; ++m)
    for (int n = 0; n < MT; ++n)
      for (int r = 0; r < 4; ++r) acc[m][n][r] = 0.f;

  for (int st = 0; st < STEPS; ++st) {
    const int sp0 = chk * SPB + st * SPW;
    __syncthreads();
#pragma unroll
    for (int r = 0; r < TPT; ++r) {
      int task = tid + r * 256;
      int cg = task & 7, pl = task >> 3;
      int spl = pl >> (2 * (IDX + 1)), s = pl & (S - 1);
      int sp = sp0 + spl;
      int ohi = sp >> (6 - IDX), owi = sp & (OH - 1);
      int ii = s >> (IDX + 1), jj = s & (HS - 1);
      int p = (ohi * HS + ii) * 128 + owi * HS + jj;
      size_t gaddr = base + (size_t)p * 256 + HC + ((cg ^ (p & 7)) << 3);
      int laddr = s * DSUB + (((spl * 8 + cg) ^ (s & 7)) << 3);
      *(uint4*)(qg + laddr) = *(const uint4*)(Qn + gaddr);
      *(uint4*)(kg + laddr) = *(const uint4*)(Kn + gaddr);
    }
    __syncthreads();
    if (IDX == 2) {
      int kgid = wave * 4 + lk;
      bf8 a[4], bb[4];
#pragma unroll
      for (int m = 0; m < 4; ++m) {
        int row = m * 16 + lr;
        int off = row * DSUB + ((kgid ^ (row & 7)) << 3);
        a[m] = *(const bf8*)(qg + off);
        bb[m] = *(const bf8*)(kg + off);
      }
#pragma unroll
      for (int m = 0; m < 4; ++m)
#pragma unroll
        for (int n = 0; n < 4; ++n)
          acc[m][n] = __builtin_amdgcn_mfma_f32_16x16x32_bf16(a[m], bb[n], acc[m][n], 0, 0, 0);
    } else {
      int row = lr & (ROWS - 1);
#pragma unroll
      for (int kk = 0; kk < 4; ++kk) {
        int kgid = (wave * 4 + kk) * 4 + lk;
        int off = row * DSUB + ((kgid ^ (row & 7)) << 3);
        bf8 a = *(const bf8*)(qg + off);
        bf8 bb = *(const bf8*)(kg + off);
        acc[0][0] = __builtin_amdgcn_mfma_f32_16x16x32_bf16(a, bb, acc[0][0], 0, 0, 0);
      }
    }
  }

  __syncthreads();
  for (int i2 = tid; i2 < S * S; i2 += 256) red[i2] = 0.f;
  __syncthreads();
  if (IDX == 2) {
#pragma unroll
    for (int m = 0; m < 4; ++m)
#pragma unroll
      for (int n = 0; n < 4; ++n)
#pragma unroll
        for (int r = 0; r < 4; ++r)
          atomicAdd(&red[(m * 16 + lk * 4 + r) * 64 + n * 16 + lr], acc[m][n][r]);
  } else if (IDX == 1) {
#pragma unroll
    for (int r = 0; r < 4; ++r)
      atomicAdd(&red[(lk * 4 + r) * 16 + lr], acc[0][0][r]);
  } else {
    if (lk == 0 && lr < 4) {
#pragma unroll
      for (int r = 0; r < 4; ++r)
        atomicAdd(&red[r * 4 + lr], acc[0][0][r]);
    }
  }
  __syncthreads();
  float* sc = scores + SCOFF + (size_t)b * S * S;
  for (int i2 = tid; i2 < S * S; i2 += 256) atomicAdd(sc + i2, red[i2]);
}

// ---------------- Gram idx3: 256x256x4096 GEMM, partials ----------------
__global__ __launch_bounds__(256) void k_gram3(
    const unsigned short* __restrict__ Qn, const unsigned short* __restrict__ Kn,
    float* __restrict__ part3) {
  const int qc = blockIdx.x, tq = blockIdx.y, b = blockIdx.z;
  const int tid = threadIdx.x;
  const int wave = tid >> 6, lane = tid & 63, lr = lane & 15, lk = lane >> 4;

  __shared__ __align__(16) unsigned short qg[256 * 64];
  __shared__ __align__(16) unsigned short kg[64 * 64];

  const size_t base = (size_t)b * 16384 * 256;

  f32x4 acc[4][4];
  for (int m = 0; m < 4; ++m)
    for (int n = 0; n < 4; ++n)
      for (int r = 0; r < 4; ++r) acc[m][n][r] = 0.f;

  for (int st = 0; st < 8; ++st) {
    int sp = qc * 8 + st;
    int ohi = sp >> 3, owi = sp & 7;
    __syncthreads();
#pragma unroll
    for (int r = 0; r < 8; ++r) {
      int task = tid + r * 256;
      int cg = task & 7, s = task >> 3;
      int p = (ohi * 16 + (s >> 4)) * 128 + owi * 16 + (s & 15);
      uint4 v = *(const uint4*)(Qn + base + (size_t)p * 256 + 192 + ((cg ^ (p & 7)) << 3));
      *(uint4*)(qg + s * 64 + ((cg ^ (s & 7)) << 3)) = v;
    }
#pragma unroll
    for (int r = 0; r < 2; ++r) {
      int task = tid + r * 256;
      int cg = task & 7, tl = task >> 3;
      int p = (ohi * 16 + tq * 4 + (tl >> 4)) * 128 + owi * 16 + (tl & 15);
      uint4 v = *(const uint4*)(Kn + base + (size_t)p * 256 + 192 + ((cg ^ (p & 7)) << 3));
      *(uint4*)(kg + tl * 64 + ((cg ^ (tl & 7)) << 3)) = v;
    }
    __syncthreads();
#pragma unroll
    for (int kk = 0; kk < 2; ++kk) {
      int kgid = kk * 4 + lk;
      bf8 a[4], bb[4];
#pragma unroll
      for (int m = 0; m < 4; ++m) {
        int row = wave * 64 + m * 16 + lr;
        a[m] = *(const bf8*)(qg + row * 64 + ((kgid ^ (row & 7)) << 3));
      }
#pragma unroll
      for (int n = 0; n < 4; ++n) {
        int rowb = n * 16 + lr;
        bb[n] = *(const bf8*)(kg + rowb * 64 + ((kgid ^ (rowb & 7)) << 3));
      }
#pragma unroll
      for (int m = 0; m < 4; ++m)
#pragma unroll
        for (int n = 0; n < 4; ++n)
          acc[m][n] = __builtin_amdgcn_mfma_f32_16x16x32_bf16(a[m], bb[n], acc[m][n], 0, 0, 0);
    }
  }

  float* pb = part3 + (((size_t)qc * 8 + b) * 65536);
#pragma unroll
  for (int m = 0; m < 4; ++m)
#pragma unroll
    for (int r = 0; r < 4; ++r) {
      int srow = wave * 64 + m * 16 + lk * 4 + r;
#pragma unroll
      for (int n = 0; n < 4; ++n)
        pb[srow * 256 + tq * 64 + n * 16 + lr] = acc[m][n][r];
    }
}

// ---------------- softmax idx0-2 (fp32 scores -> bf16 probs) ----------------
__global__ __launch_bounds__(256) void k_softmax(const float* __restrict__ scores,
                                                 unsigned short* __restrict__ prb) {
  const int idx = blockIdx.x, b = blockIdx.y;
  const int S = 4 << (2 * idx);
  const int off = (idx == 0 ? 0 : idx == 1 ? 128 : 2176) + b * S * S;
  const int s = threadIdx.x;
  if (s >= S) return;
  const float scale = rsqrtf(64.0f * (float)(4096 >> (2 * idx)));
  const float* row = scores + off + s * S;
  float m = -1e30f;
  for (int t = 0; t < S; ++t) m = fmaxf(m, row[t]);
  m *= scale;
  float sum = 0.f;
  for (int t = 0; t < S; ++t) sum += __expf(row[t] * scale - m);
  float inv = 1.0f / sum;
  unsigned short* prow = prb + off + s * S;
  for (int t = 0; t < S; ++t) prow[t] = f2bf(__expf(row[t] * scale - m) * inv);
}

// ---------------- softmax idx3: sum 8 partials + softmax ----------------
__global__ __launch_bounds__(256) void k_softmax3(const float* __restrict__ part3,
                                                  unsigned short* __restrict__ prb) {
  const int sc_ = blockIdx.x, b = blockIdx.y;
  const int tid = threadIdx.x;
  const int s = sc_ * 32 + (tid >> 3);
  const int t0 = (tid & 7) * 32;
  float v[32];
#pragma unroll
  for (int k = 0; k < 32; ++k) v[k] = 0.f;
  for (int q = 0; q < 8; ++q) {
    const float4* pp = (const float4*)(part3 + (((size_t)q * 8 + b) * 256 + s) * 256 + t0);
#pragma unroll
    for (int k = 0; k < 8; ++k) {
      float4 u = pp[k];
      v[k * 4 + 0] += u.x; v[k * 4 + 1] += u.y; v[k * 4 + 2] += u.z; v[k * 4 + 3] += u.w;
    }
  }
  const float scale = 1.0f / 64.0f;
  float m = -1e30f;
#pragma unroll
  for (int k = 0; k < 32; ++k) { v[k] *= scale; m = fmaxf(m, v[k]); }
  m = fmaxf(m, __shfl_xor(m, 1));
  m = fmaxf(m, __shfl_xor(m, 2));
  m = fmaxf(m, __shfl_xor(m, 4));
  float sum = 0.f;
#pragma unroll
  for (int k = 0; k < 32; ++k) { v[k] = __expf(v[k] - m); sum += v[k]; }
  sum += __shfl_xor(sum, 1);
  sum += __shfl_xor(sum, 2);
  sum += __shfl_xor(sum, 4);
  float inv = 1.0f / sum;
  unsigned short* prw = prb + 34944 + (size_t)b * 65536 + s * 256 + t0;
#pragma unroll
  for (int k8 = 0; k8 < 4; ++k8) {
    unsigned short tmp[8];
#pragma unroll
    for (int e = 0; e < 8; ++e) tmp[e] = f2bf(v[k8 * 8 + e] * inv);
    *(uint4*)(prw + k8 * 8) = *(const uint4*)tmp;
  }
}

// ---------------- PV small S (idx 0,1,2): per-head, NHWC in/out ----------------
template <int IDX>
__global__ __launch_bounds__(256) void k_pv(
    const unsigned short* __restrict__ Vn, const unsigned short* __restrict__ prb,
    unsigned short* __restrict__ Yn) {
  constexpr int HS = 2 << IDX, S = HS * HS, OH = 64 >> IDX;
  constexpr int IT = (IDX == 0) ? 8 : (IDX == 1) ? 4 : 1;
  constexpr int POFF = (IDX == 0) ? 0 : (IDX == 1) ? 128 : 2176;
  const int bx = blockIdx.x, b = blockIdx.y;
  const int c = threadIdx.x & 63, spg = threadIdx.x >> 6;
  __shared__ __align__(16) float pl[S * S];
  const unsigned short* pr = prb + POFF + (size_t)b * S * S;
  for (int i = threadIdx.x; i < S * S; i += 256) pl[i] = bf2f(pr[i]);
  __syncthreads();
  const int hc = IDX * 64;
  const unsigned short* vb = Vn + (size_t)b * 16384 * 256;
  unsigned short* yb = Yn + (size_t)b * 16384 * 256;
  for (int it = 0; it < IT; ++it) {
    int sp = bx * (4 * IT) + it * 4 + spg;
    int ohi = sp >> (6 - IDX), owi = sp & (OH - 1);
    float v[S];
#pragma unroll
    for (int t = 0; t < S; ++t) {
      int po = (ohi * HS + t / HS) * 128 + owi * HS + (t % HS);
      v[t] = bf2f(vb[(size_t)po * 256 + ((hc + c) ^ ((po & 7) << 3))]);
    }
    for (int s = 0; s < S; ++s) {
      const float4* p4 = (const float4*)(pl + s * S);
      float a = 0.f;
#pragma unroll
      for (int t4 = 0; t4 < S / 4; ++t4) {
        float4 pp = p4[t4];
        a += pp.x * v[t4 * 4] + pp.y * v[t4 * 4 + 1] + pp.z * v[t4 * 4 + 2] + pp.w * v[t4 * 4 + 3];
      }
      int po = ((s >> (IDX + 1)) * OH + ohi) * 128 + (s & (HS - 1)) * OH + owi;
      yb[(size_t)po * 256 + ((hc + c) ^ ((po & 7) << 3))] = f2bf(a);
    }
  }
}

// ---------------- PV idx3 (S=256): MFMA GEMM per (b, sp) ----------------
__global__ __launch_bounds__(256) void k_pv3(
    const unsigned short* __restrict__ Vn, const unsigned short* __restrict__ prb,
    unsigned short* __restrict__ Yn) {
  const int sp = blockIdx.x, b = blockIdx.y;
  const int ohi = sp >> 3, owi = sp & 7;
  const int tid = threadIdx.x;
  __shared__ __align__(16) unsigned short vl[64 * 256];
  const unsigned short* vb = Vn + (size_t)b * 16384 * 256;
  {
    int t = tid;
    int po = (ohi * 16 + (t >> 4)) * 128 + owi * 16 + (t & 15);
    const unsigned short* src = vb + (size_t)po * 256;
    int xv = (po & 7) << 3;
#pragma unroll
    for (int g = 0; g < 8; ++g) {
      ushort4 lo = *(const ushort4*)(src + ((192 + g * 8) ^ xv));
      ushort4 hi = *(const ushort4*)(src + ((192 + g * 8) ^ xv) + 4);
      unsigned short vv[8] = {lo.x, lo.y, lo.z, lo.w, hi.x, hi.y, hi.z, hi.w};
#pragma unroll
      for (int e = 0; e < 8; ++e) {
        int cc = g * 8 + e;
        vl[cc * 256 + (t ^ ((cc & 7) << 3))] = vv[e];
      }
    }
  }
  __syncthreads();

  const int wave = tid >> 6, lane = tid & 63;
  const int lr = lane & 15, lk = lane >> 4;
  const int sb = wave * 64;
  const unsigned short* pr = prb + 34944 + (size_t)b * 65536;

  f32x4 acc[4][4];
  for (int m = 0; m < 4; ++m)
    for (int n = 0; n < 4; ++n)
      for (int r = 0; r < 4; ++r) acc[m][n][r] = 0.f;

  for (int kk = 0; kk < 8; ++kk) {
    int t0 = kk * 32 + lk * 8;
    bf8 a[4], bb[4];
#pragma unroll
    for (int m = 0; m < 4; ++m)
      a[m] = *(const bf8*)(pr + (size_t)(sb + m * 16 + lr) * 256 + t0);
#pragma unroll
    for (int n = 0; n < 4; ++n) {
      int cc = n * 16 + lr;
      bb[n] = *(const bf8*)(&vl[cc * 256 + (t0 ^ ((cc & 7) << 3))]);
    }
#pragma unroll
    for (int m = 0; m < 4; ++m)
#pragma unroll
      for (int n = 0; n < 4; ++n)
        acc[m][n] = __builtin_amdgcn_mfma_f32_16x16x32_bf16(a[m], bb[n], acc[m][n], 0, 0, 0);
  }

  unsigned short* yb = Yn + (size_t)b * 16384 * 256;
#pragma unroll
  for (int m = 0; m < 4; ++m) {
#pragma unroll
    for (int r = 0; r < 4; ++r) {
      int s = sb + m * 16 + lk * 4 + r;
      int si = s >> 4, sj = s & 15;
      int po = (si * 8 + ohi) * 128 + sj * 8 + owi;
#pragma unroll
      for (int n = 0; n < 4; ++n) {
        int cc = 192 + n * 16 + lr;
        yb[(size_t)po * 256 + (cc ^ (owi << 3))] = f2bf(acc[m][n][r]);
      }
    }
  }
}

// ---------------- 3x3 conv: 256x256x2304 GEMM, 8-slot ring (R7 known-good) ----------------
#define CONV_PHASE(KT_, R_, PK_, DOSTAGE_, WAITMODE_)                            \
  do {                                                                           \
    if (DOSTAGE_) {                                                              \
      constexpr int type_ = (R_ == 0) ? 0 : (R_ == 1) ? 2 : (R_ == 2) ? 3 : 1;   \
      STAGE((1 - (PK_)) * 4 + (R_), type_, (KT_) + 1);                           \
    }                                                                            \
    if ((WAITMODE_) == 0) { asm volatile("s_waitcnt vmcnt(6)" ::: "memory"); }   \
    else if ((WAITMODE_) == 1) { asm volatile("s_waitcnt vmcnt(0)" ::: "memory"); } \
    __builtin_amdgcn_s_barrier();                                                \
    asm volatile("" ::: "memory");                                               \
    {                                                                            \
      constexpr int mh_ = (R_) >> 1, nh_ = (R_) & 1;                             \
      constexpr int sA_ = (PK_) * 4 + (mh_ ? 3 : 0);                             \
      constexpr int sB_ = (PK_) * 4 + (nh_ ? 2 : 1);                             \
      if (nh_ == 0) {                                                            \
        _Pragma("unroll") for (int m2 = 0; m2 < 4; ++m2) {                       \
          int row = wm * 64 + m2 * 16 + lr;                                      \
          _Pragma("unroll") for (int kk = 0; kk < 2; ++kk)                       \
            areg[m2][kk] = *(const bf8*)(&lds[sA_][row * 64 +                    \
                (((kk * 4 + lk) ^ (row & 7)) << 3)]);                            \
        }                                                                        \
      }                                                                          \
      bf8 breg[2][2];                                                            \
      _Pragma("unroll") for (int n2 = 0; n2 < 2; ++n2) {                         \
        int row = wn * 32 + n2 * 16 + lr;                                        \
        _Pragma("unroll") for (int kk = 0; kk < 2; ++kk)                         \
          breg[n2][kk] = *(const bf8*)(&lds[sB_][row * 64 +                      \
              (((kk * 4 + lk) ^ (row & 7)) << 3)]);                              \
      }                                                                          \
      __builtin_amdgcn_s_setprio(1);                                             \
      _Pragma("unroll") for (int kk = 0; kk < 2; ++kk)                           \
        _Pragma("unroll") for (int m2 = 0; m2 < 4; ++m2)                         \
          _Pragma("unroll") for (int n2 = 0; n2 < 2; ++n2)                       \
            acc[mh_ * 4 + m2][nh_ * 2 + n2] =                                    \
                __builtin_amdgcn_mfma_f32_16x16x32_bf16(                         \
                    areg[m2][kk], breg[n2][kk],                                  \
                    acc[mh_ * 4 + m2][nh_ * 2 + n2], 0, 0, 0);                   \
      __builtin_amdgcn_s_setprio(0);                                             \
      asm volatile("" ::: "memory");                                             \
    }                                                                            \
  } while (0)

__global__ __launch_bounds__(512, 2) void k_conv(
    const unsigned short* __restrict__ Yn, const unsigned short* __restrict__ Wob,
    const float* __restrict__ bo, const unsigned short* __restrict__ zp,
    unsigned short* __restrict__ co, float* __restrict__ bnp) {
  __shared__ __align__(16) unsigned short lds[8][8192];  // 8 x 16KB half-tile slots

  const int bid = blockIdx.x;
  const int swz = (bid & 7) * 64 + (bid >> 3);   // XCD-chunked, bijective (512=8*64)
  const int b = swz >> 6, tile = swz & 63;
  const int y0 = (tile >> 3) * 16, x0 = (tile & 7) * 16;
  const int tid = threadIdx.x;
  const int wave = tid >> 6, lane = tid & 63;
  const int lr = lane & 15, lk = lane >> 4;
  const int wm = wave >> 2, wn = wave & 3;
  const int cg = lane & 7;

  const unsigned short* yb = Yn + (size_t)b * 16384 * 256;

  auto STAGE = [&](int slot, int type, int KT) {
    if (type < 2) {
      const unsigned short* wsrc = Wob + (KT >> 2) * 256 + (KT & 3) * 64;
#pragma unroll
      for (int j = 0; j < 2; ++j) {
        int rp = (wave * 2 + j) * 8 + (lane >> 3);   // LDS row 0..127
        int o = ((rp >> 6) & 1) * 128 + type * 64 + (rp & 63);
        int kg = cg ^ (rp & 7);
        gload16(wsrc + o * 2304 + (kg << 3), &lds[slot][(wave * 2 + j) * 512]);
      }
    } else {
      int e = KT >> 2;
      int dy = e / 3 - 1, dx = e % 3 - 1, c8 = (KT & 3) * 8;
#pragma unroll
      for (int j = 0; j < 2; ++j) {
        int rp = (wave * 2 + j) * 8 + (lane >> 3);
        int n = ((rp >> 5) & 3) * 64 + (type - 2) * 32 + (rp & 31);
        int kg = cg ^ (rp & 7);
        int h = y0 + (n >> 4) + dy, ww = x0 + (n & 15) + dx;
        const unsigned short* src = zp;
        if (h >= 0 && h < 128 && ww >= 0 && ww < 128) {
          int pp = h * 128 + ww;
          src = yb + (size_t)pp * 256 + ((c8 + (kg ^ (pp & 7))) << 3);
        }
        gload16(src, &lds[slot][(wave * 2 + j) * 512]);
      }
    }
  };

  f32x4 acc[8][4];
#pragma unroll
  for (int m = 0; m < 8; ++m)
#pragma unroll
    for (int n = 0; n < 4; ++n)
#pragma unroll
      for (int r = 0; r < 4; ++r) acc[m][n][r] = 0.f;

  bf8 areg[4][2];

  STAGE(0, 0, 0); STAGE(1, 2, 0); STAGE(2, 3, 0); STAGE(3, 1, 0);
  asm volatile("s_waitcnt vmcnt(0)" ::: "memory");

  for (int gg = 0; gg < 17; ++gg) {
    const int k0 = gg * 2;
    CONV_PHASE(k0, 0, 0, true, 0);
    CONV_PHASE(k0, 1, 0, true, 0);
    CONV_PHASE(k0, 2, 0, true, 0);
    CONV_PHASE(k0, 3, 0, true, 0);
    CONV_PHASE(k0 + 1, 0, 1, true, 0);
    CONV_PHASE(k0 + 1, 1, 1, true, 0);
    CONV_PHASE(k0 + 1, 2, 1, true, 0);
    CONV_PHASE(k0 + 1, 3, 1, true, 0);
  }
  CONV_PHASE(34, 0, 0, true, 0);
  CONV_PHASE(34, 1, 0, true, 0);
  CONV_PHASE(34, 2, 0, true, 0);
  CONV_PHASE(34, 3, 0, true, 0);
  CONV_PHASE(35, 0, 1, false, 1);
  CONV_PHASE(35, 1, 1, false, 2);
  CONV_PHASE(35, 2, 1, false, 2);
  CONV_PHASE(35, 3, 1, false, 2);

  __syncthreads();
  unsigned short* cb = co + (size_t)b * 256 * 16384;
  float* red1 = (float*)&lds[0][0];     // [8][128]
  float* red2 = red1 + 1024;
#pragma unroll
  for (int m = 0; m < 8; ++m) {
#pragma unroll
    for (int r = 0; r < 4; ++r) {
      int o = wm * 128 + m * 16 + lk * 4 + r;
      float bvv = bo[o];
      float s1 = 0.f, s2 = 0.f;
#pragma unroll
      for (int n = 0; n < 4; ++n) {
        int pix = wn * 64 + n * 16 + lr;
        int py = pix >> 4, px = pix & 15;
        float v = acc[m][n][r] + bvv;
        cb[(size_t)o * 16384 + (y0 + py) * 128 + x0 + px] = f2bf(v);
        s1 += v;
        s2 += v * v;
      }
      for (int off = 1; off < 16; off <<= 1) {
        s1 += __shfl_xor(s1, off, 64);
        s2 += __shfl_xor(s2, off, 64);
      }
      if (lr == 0) {
        int ol = m * 16 + lk * 4 + r;
        red1[wave * 128 + ol] = s1;
        red2[wave * 128 + ol] = s2;
      }
    }
  }
  __syncthreads();
  {
    int o = tid & 255, stat = tid >> 8;
    int wm2 = o >> 7, ol = o & 127;
    const float* rd = stat ? red2 : red1;
    float s = rd[(wm2 * 4 + 0) * 128 + ol] + rd[(wm2 * 4 + 1) * 128 + ol] +
              rd[(wm2 * 4 + 2) * 128 + ol] + rd[(wm2 * 4 + 3) * 128 + ol];
    bnp[((size_t)(b * 64 + tile) * 256 + o) * 2 + stat] = s;
  }
}

// ---------------- BN reduce + apply ----------------
__global__ __launch_bounds__(256) void k_bnred(
    const float* __restrict__ bnp, const float* __restrict__ gamma,
    const float* __restrict__ beta, float* __restrict__ bns) {
  const int o = blockIdx.x;
  const int tid = threadIdx.x;
  float s1 = 0.f, s2 = 0.f;
  for (int k = tid; k < 512; k += 256) {
    s1 += bnp[((size_t)k * 256 + o) * 2 + 0];
    s2 += bnp[((size_t)k * 256 + o) * 2 + 1];
  }
  __shared__ float r1[256], r2[256];
  r1[tid] = s1; r2[tid] = s2;
  __syncthreads();
  for (int off = 128; off > 0; off >>= 1) {
    if (tid < off) { r1[tid] += r1[tid + off]; r2[tid] += r2[tid + off]; }
    __syncthreads();
  }
  if (tid == 0) {
    const float cnt = 8.0f * 16384.0f;
    float mean = r1[0] / cnt;
    float var = r2[0] / cnt - mean * mean;
    float sc = gamma[o] * rsqrtf(var + 1e-5f);
    bns[o] = sc;
    bns[256 + o] = beta[o] - mean * sc;
  }
}

__global__ void k_bnapply(const unsigned short* __restrict__ co, float* __restrict__ out,
                          const float* __restrict__ bns) {
  size_t i = ((size_t)blockIdx.x * 256 + threadIdx.x) * 8;
  const size_t total = 33554432;
  const size_t stride = (size_t)gridDim.x * 256 * 8;
  for (; i < total; i += stride) {
    uint4 v = *(const uint4*)(co + i);
    int o = (int)((i >> 14) & 255);
    float sc = bns[o], shv = bns[256 + o];
    const unsigned short* pv = (const unsigned short*)&v;
    float r[8];
#pragma unroll
    for (int e = 0; e < 8; ++e) {
      float f = bf2f(pv[e]) * sc + shv;
      r[e] = f > 0.f ? f : 0.2f * f;
    }
    *(float4*)(out + i) = *(const float4*)&r[0];
    *(float4*)(out + i + 4) = *(const float4*)&r[4];
  }
}

// ---------------- launcher ----------------
extern "C" void kernel_launch(void* const* d_in, const int* in_sizes, int n_in,
                              void* d_out, int out_size, void* d_ws, size_t ws_size,
                              hipStream_t stream) {
  if (ws_size < WS_NEED) return;

  const float* x     = (const float*)d_in[0];
  const float* wq    = (const float*)d_in[1];
  const float* bq    = (const float*)d_in[2];
  const float* wk    = (const float*)d_in[3];
  const float* bk    = (const float*)d_in[4];
  const float* wv    = (const float*)d_in[5];
  const float* bv    = (const float*)d_in[6];
  const float* wo    = (const float*)d_in[7];
  const float* bo    = (const float*)d_in[8];
  const float* gamma = (const float*)d_in[9];
  const float* beta  = (const float*)d_in[10];
  float* out = (float*)d_out;
  char* ws = (char*)d_ws;

  unsigned short* Wb  = (unsigned short*)(ws + WB_OFF);
  unsigned short* Wob = (unsigned short*)(ws + WOB_OFF);
  unsigned short* Qn  = (unsigned short*)(ws + QN_OFF);
  unsigned short* Kn  = (unsigned short*)(ws + KN_OFF);
  unsigned short* Vn  = (unsigned short*)(ws + VN_OFF);
  unsigned short* Yn  = (unsigned short*)(ws + YN_OFF);
  float* part3 = (float*)(ws + YN_OFF);          // overlay: used before Yn is written
  unsigned short* co = (unsigned short*)(ws + QN_OFF);  // overlay: Qn dead after grams
  float* scores = (float*)(ws + SC_OFF);
  unsigned short* prb = (unsigned short*)(ws + PRB_OFF);
  float* bnp    = (float*)(ws + BNP_OFF);
  float* bns    = (float*)(ws + BNS_OFF);
  unsigned short* zp = (unsigned short*)(ws + ZP_OFF);

  k_prep<<<dim3(3072), dim3(256), 0, stream>>>(wq, wk, wv, wo, Wb, Wob);
  k_zero2<<<dim3(137), dim3(256), 0, stream>>>(scores, 34944, (float*)zp, 64);
  k_qkv<<<dim3(256, 8), dim3(256), 0, stream>>>(x, Wb, bq, bk, bv, Qn, Kn, Vn);
  k_gram<0><<<dim3(32, 8), dim3(256), 0, stream>>>(Qn, Kn, scores);
  k_gram<1><<<dim3(32, 8), dim3(256), 0, stream>>>(Qn, Kn, scores);
  k_gram<2><<<dim3(32, 8), dim3(256), 0, stream>>>(Qn, Kn, scores);
  k_gram3<<<dim3(8, 4, 8), dim3(256), 0, stream>>>(Qn, Kn, part3);
  k_softmax<<<dim3(3, 8), dim3(256), 0, stream>>>(scores, prb);
  k_softmax3<<<dim3(8, 8), dim3(256), 0, stream>>>(part3, prb);
  k_pv<0><<<dim3(128, 8), dim3(256), 0, stream>>>(Vn, prb, Yn);
  k_pv<1><<<dim3(64, 8), dim3(256), 0, stream>>>(Vn, prb, Yn);
  k_pv<2><<<dim3(64, 8), dim3(256), 0, stream>>>(Vn, prb, Yn);
  k_pv3<<<dim3(64, 8), dim3(256), 0, stream>>>(Vn, prb, Yn);
  k_conv<<<dim3(512), dim3(512), 0, stream>>>(Yn, Wob, bo, zp, co, bnp);
  k_bnred<<<dim3(256), dim3(256), 0, stream>>>(bnp, gamma, beta, bns);
  k_bnapply<<<dim3(4096), dim3(256), 0, stream>>>(co, out, bns);
}

// Round 11
// 546.975 us; speedup vs baseline: 1.3335x; 1.0087x over previous
//
#include <hip/hip_runtime.h>
#include <stdint.h>

// ---------------- geometry ----------------
// B=8, C=256, H=W=128, HW=16384, 4 heads of d_k=64
// idx: HS=WS=2<<idx, S=HS*HS, OH=OW=64>>idx, NSP=OH*OW
// gather:  q[s=(i,j)][d=(c,ohi,owi)] = Q[lo+c][ohi*HS+i][owi*WS+j], s=i*WS+j
// scatter: Y[lo+c][i*OH+ohi][j*OW+owi] = y[s][d]   (transposed vs gather!)
// NHWC buffers (Qn,Kn,Vn,Yn): element (p, c) at [p*256 + (c ^ ((p&7)<<3))]
// granule rule: 8-ch granule g of pixel p sits at granule slot (g ^ (p&7)).

#define DEVI static __device__ __forceinline__

typedef short bf8 __attribute__((ext_vector_type(8)));   // 8 bf16 (4 VGPRs)
typedef float f32x4 __attribute__((ext_vector_type(4)));

DEVI unsigned short f2bf(float f) {
  unsigned u = __builtin_bit_cast(unsigned, f);
  u = (u + 0x7fffu + ((u >> 16) & 1u)) >> 16;
  return (unsigned short)u;
}
DEVI float bf2f(unsigned short h) {
  unsigned u = ((unsigned)h) << 16;
  return __builtin_bit_cast(float, u);
}

DEVI void gload16(const void* g, void* l) {
  __builtin_amdgcn_global_load_lds(
      (const __attribute__((address_space(1))) unsigned int*)g,
      (__attribute__((address_space(3))) unsigned int*)l, 16, 0, 0);
}

// ---------------- ws layout (bytes) ----------------
static const size_t WB_OFF  = 0;                        // bf16 [3][256][256]
static const size_t WOB_OFF = 393216;                   // bf16 [256][2304] k=(e*256+c)
static const size_t QN_OFF  = 1572864;                  // bf16 NHWC-swz [8][16384][256]; co overlay after grams
static const size_t KN_OFF  = QN_OFF + 67108864;
static const size_t VN_OFF  = KN_OFF + 67108864;
static const size_t YN_OFF  = VN_OFF + 67108864;        // bf16 NHWC-swz (also part3 overlay)
static const size_t SC_OFF  = YN_OFF + 67108864;        // f32 scores idx0-2 (34944 floats used)
static const size_t PRB_OFF = SC_OFF + 2236928;         // bf16 probs (559232)
static const size_t BNP_OFF = PRB_OFF + 1118464;        // f32 [512][256][2]
static const size_t BNS_OFF = BNP_OFF + 4194304;        // f32 [2][256]
static const size_t ZP_OFF  = BNS_OFF + 2048;           // 256B zero page for OOB gloads
static const size_t WS_NEED = ZP_OFF + 256;

// ---------------- prep: convert weights to bf16 (wo reordered) ----------------
__global__ void k_prep(const float* __restrict__ wq, const float* __restrict__ wk,
                       const float* __restrict__ wv, const float* __restrict__ wo,
                       unsigned short* __restrict__ Wb, unsigned short* __restrict__ Wob) {
  int i = blockIdx.x * 256 + threadIdx.x;        // grid covers 786432 exactly
  if (i < 196608) {
    int z = i >> 16, r = i & 65535;
    const float* w = (z == 0) ? wq : (z == 1) ? wk : wv;
    Wb[i] = f2bf(w[r]);
  } else {
    int j = i - 196608;
    int o = j / 2304, k = j - o * 2304;
    int e = k >> 8, c = k & 255;
    Wob[j] = f2bf(wo[(o * 256 + c) * 9 + e]);    // Wob[o][e*256+c] = wo[o][c][e]
  }
}

__global__ void k_zero2(float* __restrict__ a, int na, float* __restrict__ b2, int nb) {
  int i = blockIdx.x * 256 + threadIdx.x;
  for (; i < na + nb; i += gridDim.x * 256) {
    if (i < na) a[i] = 0.f; else b2[i - na] = 0.f;
  }
}

// ---------------- fused QKV projection (48KB LDS, 3 blk/CU) ----------------
__global__ __launch_bounds__(256, 3) void k_qkv(
    const float* __restrict__ x, const unsigned short* __restrict__ Wb,
    const float* __restrict__ bq, const float* __restrict__ bk, const float* __restrict__ bv,
    unsigned short* __restrict__ Qn, unsigned short* __restrict__ Kn,
    unsigned short* __restrict__ Vn) {
  const int pt = blockIdx.x, b = blockIdx.y;
  const int p0 = pt * 64;
  const int tid = threadIdx.x;

  __shared__ __align__(16) unsigned short xt[64 * 256];  // input tile [p][c'] swizzled 32KB
  __shared__ __align__(16) unsigned short ot[32 * 256];  // output chunk buffer 16KB

  const int wave = tid >> 6, lane = tid & 63;

  {
    const float* xb = x + (size_t)b * 256 * 16384 + p0;
    const int xsw = (lane & 7) << 3;
#pragma unroll
    for (int it = 0; it < 16; ++it) {
      int c4 = (it * 4 + wave) * 4;          // c4 covers {0,4,...,252} exactly once
      unsigned short tmp[4];
#pragma unroll
      for (int j = 0; j < 4; ++j)
        tmp[j] = f2bf(xb[(size_t)(c4 + j) * 16384 + lane]);
      *(ushort4*)(&xt[lane * 256 + (c4 ^ xsw)]) = *(const ushort4*)tmp;
    }
  }
  __syncthreads();

  const int lr = lane & 15, lk = lane >> 4;
  const int obase = wave * 64;

  for (int z = 0; z < 3; ++z) {
    const unsigned short* Wz = Wb + (size_t)z * 65536;
    f32x4 acc[4][4];
    for (int m = 0; m < 4; ++m)
      for (int n = 0; n < 4; ++n)
        for (int r = 0; r < 4; ++r) acc[m][n][r] = 0.f;

#pragma unroll 2
    for (int ks = 0; ks < 8; ++ks) {
      int c0 = ks * 32 + lk * 8;
      bf8 a[4], bb[4];
#pragma unroll
      for (int m = 0; m < 4; ++m)
        a[m] = *(const bf8*)(Wz + (size_t)(obase + m * 16 + lr) * 256 + c0);
#pragma unroll
      for (int n = 0; n < 4; ++n) {
        int p = n * 16 + lr;
        bb[n] = *(const bf8*)(&xt[p * 256 + (c0 ^ ((p & 7) << 3))]);
      }
      __builtin_amdgcn_s_setprio(1);
#pragma unroll
      for (int m = 0; m < 4; ++m)
#pragma unroll
        for (int n = 0; n < 4; ++n)
          acc[m][n] = __builtin_amdgcn_mfma_f32_16x16x32_bf16(a[m], bb[n], acc[m][n], 0, 0, 0);
      __builtin_amdgcn_s_setprio(0);
    }

    const float* bias = (z == 0) ? bq : (z == 1) ? bk : bv;
    unsigned short* On = (z == 0) ? Qn : (z == 1) ? Kn : Vn;
    // epilogue in two 32-px chunks through the 16KB ot buffer
    for (int h = 0; h < 2; ++h) {
      __syncthreads();   // prior ot consumers done
#pragma unroll
      for (int m = 0; m < 4; ++m) {
        int ob4 = obase + m * 16 + lk * 4;
        float4 b4 = *(const float4*)(bias + ob4);
#pragma unroll
        for (int nn = 0; nn < 2; ++nn) {
          int n = h * 2 + nn;
          int pch = nn * 16 + lr;            // chunk-local pixel 0..31
          ushort4 v4;
          v4.x = f2bf(acc[m][n][0] + b4.x);
          v4.y = f2bf(acc[m][n][1] + b4.y);
          v4.z = f2bf(acc[m][n][2] + b4.z);
          v4.w = f2bf(acc[m][n][3] + b4.w);
          *(ushort4*)(&ot[pch * 256 + (ob4 ^ ((pch & 7) << 3))]) = v4;
        }
      }
      __syncthreads();
      unsigned short* gb = On + ((size_t)b * 16384 + p0 + h * 32) * 256;
#pragma unroll
      for (int i = 0; i < 4; ++i) {
        int ch = tid + i * 256;              // 1024 cells x 16B = 16KB
        *(uint4*)(gb + ch * 8) = *(const uint4*)(&ot[ch * 8]);
      }
    }
  }
}

// ---------------- Gram bodies (merged dispatch) ----------------
template <int IDX>
DEVI void gram_body(int chk, int b,
                    const unsigned short* __restrict__ Qn,
                    const unsigned short* __restrict__ Kn,
                    float* __restrict__ scores, char* smem) {
  constexpr int HS = 2 << IDX, S = HS * HS, OH = 64 >> IDX, NSP = OH * OH;
  constexpr int SPW = (IDX == 2) ? 2 : 8;
  constexpr int DSUB = SPW * 64;
  constexpr int SPB = NSP / 32;
  constexpr int STEPS = SPB / SPW;
  constexpr int ROWS = S;
  constexpr int TPT = S * SPW * 8 / 256;
  constexpr int SCOFF = (IDX == 0) ? 0 : (IDX == 1) ? 128 : 2176;
  constexpr int HC = IDX * 64;
  constexpr int MT = (IDX == 2) ? 4 : 1;

  unsigned short* qg = (unsigned short*)smem;                       // ROWS*DSUB
  unsigned short* kg = (unsigned short*)(smem + ROWS * DSUB * 2);
  float* red = (float*)(smem + ROWS * DSUB * 4);                    // S*S floats

  const int tid = threadIdx.x;
  const int wave = tid >> 6, lane = tid & 63, lr = lane & 15, lk = lane >> 4;
  const size_t base = (size_t)b * 16384 * 256;

  f32x4 acc[MT][MT];
  for (int m = 0; m < MT; ++m)
    for (int n = 0; n < MT; ++n)
      for (int r = 0; r < 4; ++r) acc[m][n][r] = 0.f;

  for (int st = 0; st < STEPS; ++st) {
    const int sp0 = chk * SPB + st * SPW;
    __syncthreads();
#pragma unroll
    for (int r = 0; r < TPT; ++r) {
      int task = tid + r * 256;
      int cg = task & 7, pl = task >> 3;
      int spl = pl >> (2 * (IDX + 1)), s = pl & (S - 1);
      int sp = sp0 + spl;
      int ohi = sp >> (6 - IDX), owi = sp & (OH - 1);
      int ii = s >> (IDX + 1), jj = s & (HS - 1);
      int p = (ohi * HS + ii) * 128 + owi * HS + jj;
      size_t gaddr = base + (size_t)p * 256 + HC + ((cg ^ (p & 7)) << 3);
      int laddr = s * DSUB + (((spl * 8 + cg) ^ (s & 7)) << 3);
      *(uint4*)(qg + laddr) = *(const uint4*)(Qn + gaddr);
      *(uint4*)(kg + laddr) = *(const uint4*)(Kn + gaddr);
    }
    __syncthreads();
    if (IDX == 2) {
      int kgid = wave * 4 + lk;
      bf8 a[4], bb[4];
#pragma unroll
      for (int m = 0; m < 4; ++m) {
        int row = m * 16 + lr;
        int off = row * DSUB + ((kgid ^ (row & 7)) << 3);
        a[m] = *(const bf8*)(qg + off);
        bb[m] = *(const bf8*)(kg + off);
      }
#pragma unroll
      for (int m = 0; m < MT; ++m)
#pragma unroll
        for (int n = 0; n < MT; ++n)
          acc[m][n] = __builtin_amdgcn_mfma_f32_16x16x32_bf16(a[m], bb[n], acc[m][n], 0, 0, 0);
    } else {
      int row = lr & (ROWS - 1);
#pragma unroll
      for (int kk = 0; kk < 4; ++kk) {
        int kgid = (wave * 4 + kk) * 4 + lk;
        int off = row * DSUB + ((kgid ^ (row & 7)) << 3);
        bf8 a = *(const bf8*)(qg + off);
        bf8 bb = *(const bf8*)(kg + off);
        acc[0][0] = __builtin_amdgcn_mfma_f32_16x16x32_bf16(a, bb, acc[0][0], 0, 0, 0);
      }
    }
  }

  __syncthreads();
  for (int i2 = tid; i2 < S * S; i2 += 256) red[i2] = 0.f;
  __syncthreads();
  if (IDX == 2) {
#pragma unroll
    for (int m = 0; m < MT; ++m)
#pragma unroll
      for (int n = 0; n < MT; ++n)
#pragma unroll
        for (int r = 0; r < 4; ++r)
          atomicAdd(&red[(m * 16 + lk * 4 + r) * 64 + n * 16 + lr], acc[m][n][r]);
  } else if (IDX == 1) {
#pragma unroll
    for (int r = 0; r < 4; ++r)
      atomicAdd(&red[(lk * 4 + r) * 16 + lr], acc[0][0][r]);
  } else {
    if (lk == 0 && lr < 4) {
#pragma unroll
      for (int r = 0; r < 4; ++r)
        atomicAdd(&red[r * 4 + lr], acc[0][0][r]);
    }
  }
  __syncthreads();
  float* sc = scores + SCOFF + (size_t)b * S * S;
  for (int i2 = tid; i2 < S * S; i2 += 256) atomicAdd(sc + i2, red[i2]);
}

DEVI void gram3_body(int qc, int tq, int b,
                     const unsigned short* __restrict__ Qn,
                     const unsigned short* __restrict__ Kn,
                     float* __restrict__ part3, char* smem) {
  unsigned short* qg = (unsigned short*)smem;            // 256*64 = 32KB
  unsigned short* kg = (unsigned short*)(smem + 32768);  // 64*64  = 8KB

  const int tid = threadIdx.x;
  const int wave = tid >> 6, lane = tid & 63, lr = lane & 15, lk = lane >> 4;
  const size_t base = (size_t)b * 16384 * 256;

  f32x4 acc[4][4];
  for (int m = 0; m < 4; ++m)
    for (int n = 0; n < 4; ++n)
      for (int r = 0; r < 4; ++r) acc[m][n][r] = 0.f;

  for (int st = 0; st < 8; ++st) {
    int sp = qc * 8 + st;
    int ohi = sp >> 3, owi = sp & 7;
    __syncthreads();
#pragma unroll
    for (int r = 0; r < 8; ++r) {
      int task = tid + r * 256;
      int cg = task & 7, s = task >> 3;
      int p = (ohi * 16 + (s >> 4)) * 128 + owi * 16 + (s & 15);
      uint4 v = *(const uint4*)(Qn + base + (size_t)p * 256 + 192 + ((cg ^ (p & 7)) << 3));
      *(uint4*)(qg + s * 64 + ((cg ^ (s & 7)) << 3)) = v;
    }
#pragma unroll
    for (int r = 0; r < 2; ++r) {
      int task = tid + r * 256;
      int cg = task & 7, tl = task >> 3;
      int p = (ohi * 16 + tq * 4 + (tl >> 4)) * 128 + owi * 16 + (tl & 15);
      uint4 v = *(const uint4*)(Kn + base + (size_t)p * 256 + 192 + ((cg ^ (p & 7)) << 3));
      *(uint4*)(kg + tl * 64 + ((cg ^ (tl & 7)) << 3)) = v;
    }
    __syncthreads();
#pragma unroll
    for (int kk = 0; kk < 2; ++kk) {
      int kgid = kk * 4 + lk;
      bf8 a[4], bb[4];
#pragma unroll
      for (int m = 0; m < 4; ++m) {
        int row = wave * 64 + m * 16 + lr;
        a[m] = *(const bf8*)(qg + row * 64 + ((kgid ^ (row & 7)) << 3));
      }
#pragma unroll
      for (int n = 0; n < 4; ++n) {
        int rowb = n * 16 + lr;
        bb[n] = *(const bf8*)(kg + rowb * 64 + ((kgid ^ (rowb & 7)) << 3));
      }
#pragma unroll
      for (int m = 0; m < 4; ++m)
#pragma unroll
        for (int n = 0; n < 4; ++n)
          acc[m][n] = __builtin_amdgcn_mfma_f32_16x16x32_bf16(a[m], bb[n], acc[m][n], 0, 0, 0);
    }
  }

  float* pb = part3 + (((size_t)qc * 8 + b) * 65536);
#pragma unroll
  for (int m = 0; m < 4; ++m)
#pragma unroll
    for (int r = 0; r < 4; ++r) {
      int srow = wave * 64 + m * 16 + lk * 4 + r;
#pragma unroll
      for (int n = 0; n < 4; ++n)
        pb[srow * 256 + tq * 64 + n * 16 + lr] = acc[m][n][r];
    }
}

// merged gram dispatch: grid (128, 8)
__global__ __launch_bounds__(256) void k_gramA(
    const unsigned short* __restrict__ Qn, const unsigned short* __restrict__ Kn,
    float* __restrict__ scores, float* __restrict__ part3) {
  __shared__ __align__(16) char smem[49152];
  const int bx = blockIdx.x, b = blockIdx.y;
  if (bx < 32)       gram_body<0>(bx, b, Qn, Kn, scores, smem);
  else if (bx < 64)  gram_body<1>(bx - 32, b, Qn, Kn, scores, smem);
  else if (bx < 96)  gram_body<2>(bx - 64, b, Qn, Kn, scores, smem);
  else               gram3_body((bx - 96) & 7, (bx - 96) >> 3, b, Qn, Kn, part3, smem);
}

// ---------------- softmax bodies (merged) ----------------
DEVI void softmax_body(int idx, int b, const float* __restrict__ scores,
                       unsigned short* __restrict__ prb) {
  const int S = 4 << (2 * idx);
  const int off = (idx == 0 ? 0 : idx == 1 ? 128 : 2176) + b * S * S;
  const int s = threadIdx.x;
  if (s >= S) return;
  const float scale = rsqrtf(64.0f * (float)(4096 >> (2 * idx)));
  const float* row = scores + off + s * S;
  float m = -1e30f;
  for (int t = 0; t < S; ++t) m = fmaxf(m, row[t]);
  m *= scale;
  float sum = 0.f;
  for (int t = 0; t < S; ++t) sum += __expf(row[t] * scale - m);
  float inv = 1.0f / sum;
  unsigned short* prow = prb + off + s * S;
  for (int t = 0; t < S; ++t) prow[t] = f2bf(__expf(row[t] * scale - m) * inv);
}

DEVI void softmax3_body(int sc_, int b, const float* __restrict__ part3,
                        unsigned short* __restrict__ prb) {
  const int tid = threadIdx.x;
  const int s = sc_ * 32 + (tid >> 3);
  const int t0 = (tid & 7) * 32;
  float v[32];
#pragma unroll
  for (int k = 0; k < 32; ++k) v[k] = 0.f;
  for (int q = 0; q < 8; ++q) {
    const float4* pp = (const float4*)(part3 + (((size_t)q * 8 + b) * 256 + s) * 256 + t0);
#pragma unroll
    for (int k = 0; k < 8; ++k) {
      float4 u = pp[k];
      v[k * 4 + 0] += u.x; v[k * 4 + 1] += u.y; v[k * 4 + 2] += u.z; v[k * 4 + 3] += u.w;
    }
  }
  const float scale = 1.0f / 64.0f;
  float m = -1e30f;
#pragma unroll
  for (int k = 0; k < 32; ++k) { v[k] *= scale; m = fmaxf(m, v[k]); }
  m = fmaxf(m, __shfl_xor(m, 1));
  m = fmaxf(m, __shfl_xor(m, 2));
  m = fmaxf(m, __shfl_xor(m, 4));
  float sum = 0.f;
#pragma unroll
  for (int k = 0; k < 32; ++k) { v[k] = __expf(v[k] - m); sum += v[k]; }
  sum += __shfl_xor(sum, 1);
  sum += __shfl_xor(sum, 2);
  sum += __shfl_xor(sum, 4);
  float inv = 1.0f / sum;
  unsigned short* prw = prb + 34944 + (size_t)b * 65536 + s * 256 + t0;
#pragma unroll
  for (int k8 = 0; k8 < 4; ++k8) {
    unsigned short tmp[8];
#pragma unroll
    for (int e = 0; e < 8; ++e) tmp[e] = f2bf(v[k8 * 8 + e] * inv);
    *(uint4*)(prw + k8 * 8) = *(const uint4*)tmp;
  }
}

// merged softmax dispatch: grid (11, 8)
__global__ __launch_bounds__(256) void k_smA(const float* __restrict__ scores,
                                             const float* __restrict__ part3,
                                             unsigned short* __restrict__ prb) {
  const int bx = blockIdx.x, b = blockIdx.y;
  if (bx < 3) softmax_body(bx, b, scores, prb);
  else        softmax3_body(bx - 3, b, part3, prb);
}

// ---------------- PV bodies (merged) ----------------
template <int IDX>
DEVI void pv_body(int bx, int b, const unsigned short* __restrict__ Vn,
                  const unsigned short* __restrict__ prb,
                  unsigned short* __restrict__ Yn, char* smem) {
  constexpr int HS = 2 << IDX, S = HS * HS, OH = 64 >> IDX;
  constexpr int IT = (IDX == 0) ? 8 : (IDX == 1) ? 4 : 1;
  constexpr int POFF = (IDX == 0) ? 0 : (IDX == 1) ? 128 : 2176;
  float* pl = (float*)smem;                          // S*S floats (<=16KB)
  const int c = threadIdx.x & 63, spg = threadIdx.x >> 6;
  const unsigned short* pr = prb + POFF + (size_t)b * S * S;
  for (int i = threadIdx.x; i < S * S; i += 256) pl[i] = bf2f(pr[i]);
  __syncthreads();
  const int hc = IDX * 64;
  const unsigned short* vb = Vn + (size_t)b * 16384 * 256;
  unsigned short* yb = Yn + (size_t)b * 16384 * 256;
  for (int it = 0; it < IT; ++it) {
    int sp = bx * (4 * IT) + it * 4 + spg;
    int ohi = sp >> (6 - IDX), owi = sp & (OH - 1);
    float v[S];
#pragma unroll
    for (int t = 0; t < S; ++t) {
      int po = (ohi * HS + t / HS) * 128 + owi * HS + (t % HS);
      v[t] = bf2f(vb[(size_t)po * 256 + ((hc + c) ^ ((po & 7) << 3))]);
    }
    for (int s = 0; s < S; ++s) {
      const float4* p4 = (const float4*)(pl + s * S);
      float a = 0.f;
#pragma unroll
      for (int t4 = 0; t4 < S / 4; ++t4) {
        float4 pp = p4[t4];
        a += pp.x * v[t4 * 4] + pp.y * v[t4 * 4 + 1] + pp.z * v[t4 * 4 + 2] + pp.w * v[t4 * 4 + 3];
      }
      int po = ((s >> (IDX + 1)) * OH + ohi) * 128 + (s & (HS - 1)) * OH + owi;
      yb[(size_t)po * 256 + ((hc + c) ^ ((po & 7) << 3))] = f2bf(a);
    }
  }
}

DEVI void pv3_body(int sp, int b, const unsigned short* __restrict__ Vn,
                   const unsigned short* __restrict__ prb,
                   unsigned short* __restrict__ Yn, char* smem) {
  unsigned short* vl = (unsigned short*)smem;        // 64*256 = 32KB
  const int ohi = sp >> 3, owi = sp & 7;
  const int tid = threadIdx.x;
  const unsigned short* vb = Vn + (size_t)b * 16384 * 256;
  {
    int t = tid;
    int po = (ohi * 16 + (t >> 4)) * 128 + owi * 16 + (t & 15);
    const unsigned short* src = vb + (size_t)po * 256;
    int xv = (po & 7) << 3;
#pragma unroll
    for (int g = 0; g < 8; ++g) {
      ushort4 lo = *(const ushort4*)(src + ((192 + g * 8) ^ xv));
      ushort4 hi = *(const ushort4*)(src + ((192 + g * 8) ^ xv) + 4);
      unsigned short vv[8] = {lo.x, lo.y, lo.z, lo.w, hi.x, hi.y, hi.z, hi.w};
#pragma unroll
      for (int e = 0; e < 8; ++e) {
        int cc = g * 8 + e;
        vl[cc * 256 + (t ^ ((cc & 7) << 3))] = vv[e];
      }
    }
  }
  __syncthreads();

  const int wave = tid >> 6, lane = tid & 63;
  const int lr = lane & 15, lk = lane >> 4;
  const int sb = wave * 64;
  const unsigned short* pr = prb + 34944 + (size_t)b * 65536;

  f32x4 acc[4][4];
  for (int m = 0; m < 4; ++m)
    for (int n = 0; n < 4; ++n)
      for (int r = 0; r < 4; ++r) acc[m][n][r] = 0.f;

  for (int kk = 0; kk < 8; ++kk) {
    int t0 = kk * 32 + lk * 8;
    bf8 a[4], bb[4];
#pragma unroll
    for (int m = 0; m < 4; ++m)
      a[m] = *(const bf8*)(pr + (size_t)(sb + m * 16 + lr) * 256 + t0);
#pragma unroll
    for (int n = 0; n < 4; ++n) {
      int cc = n * 16 + lr;
      bb[n] = *(const bf8*)(&vl[cc * 256 + (t0 ^ ((cc & 7) << 3))]);
    }
#pragma unroll
    for (int m = 0; m < 4; ++m)
#pragma unroll
      for (int n = 0; n < 4; ++n)
        acc[m][n] = __builtin_amdgcn_mfma_f32_16x16x32_bf16(a[m], bb[n], acc[m][n], 0, 0, 0);
  }

  unsigned short* yb = Yn + (size_t)b * 16384 * 256;
#pragma unroll
  for (int m = 0; m < 4; ++m) {
#pragma unroll
    for (int r = 0; r < 4; ++r) {
      int s = sb + m * 16 + lk * 4 + r;
      int si = s >> 4, sj = s & 15;
      int po = (si * 8 + ohi) * 128 + sj * 8 + owi;
#pragma unroll
      for (int n = 0; n < 4; ++n) {
        int cc = 192 + n * 16 + lr;
        yb[(size_t)po * 256 + (cc ^ (owi << 3))] = f2bf(acc[m][n][r]);
      }
    }
  }
}

// merged PV dispatch: grid (320, 8)
__global__ __launch_bounds__(256) void k_pvA(
    const unsigned short* __restrict__ Vn, const unsigned short* __restrict__ prb,
    unsigned short* __restrict__ Yn) {
  __shared__ __align__(16) char smem[32768];
  const int bx = blockIdx.x, b = blockIdx.y;
  if (bx < 128)      pv_body<0>(bx, b, Vn, prb, Yn, smem);
  else if (bx < 192) pv_body<1>(bx - 128, b, Vn, prb, Yn, smem);
  else if (bx < 256) pv_body<2>(bx - 192, b, Vn, prb, Yn, smem);
  else               pv3_body(bx - 256, b, Vn, prb, Yn, smem);
}

// ---------------- 3x3 conv: 256x256x2304 GEMM, 8-slot ring (R7 known-good) ----------------
#define CONV_PHASE(KT_, R_, PK_, DOSTAGE_, WAITMODE_)                            \
  do {                                                                           \
    if (DOSTAGE_) {                                                              \
      constexpr int type_ = (R_ == 0) ? 0 : (R_ == 1) ? 2 : (R_ == 2) ? 3 : 1;   \
      STAGE((1 - (PK_)) * 4 + (R_), type_, (KT_) + 1);                           \
    }                                                                            \
    if ((WAITMODE_) == 0) { asm volatile("s_waitcnt vmcnt(6)" ::: "memory"); }   \
    else if ((WAITMODE_) == 1) { asm volatile("s_waitcnt vmcnt(0)" ::: "memory"); } \
    __builtin_amdgcn_s_barrier();                                                \
    asm volatile("" ::: "memory");                                               \
    {                                                                            \
      constexpr int mh_ = (R_) >> 1, nh_ = (R_) & 1;                             \
      constexpr int sA_ = (PK_) * 4 + (mh_ ? 3 : 0);                             \
      constexpr int sB_ = (PK_) * 4 + (nh_ ? 2 : 1);                             \
      if (nh_ == 0) {                                                            \
        _Pragma("unroll") for (int m2 = 0; m2 < 4; ++m2) {                       \
          int row = wm * 64 + m2 * 16 + lr;                                      \
          _Pragma("unroll") for (int kk = 0; kk < 2; ++kk)                       \
            areg[m2][kk] = *(const bf8*)(&lds[sA_][row * 64 +                    \
                (((kk * 4 + lk) ^ (row & 7)) << 3)]);                            \
        }                                                                        \
      }                                                                          \
      bf8 breg[2][2];                                                            \
      _Pragma("unroll") for (int n2 = 0; n2 < 2; ++n2) {                         \
        int row = wn * 32 + n2 * 16 + lr;                                        \
        _Pragma("unroll") for (int kk = 0; kk < 2; ++kk)                         \
          breg[n2][kk] = *(const bf8*)(&lds[sB_][row * 64 +                      \
              (((kk * 4 + lk) ^ (row & 7)) << 3)]);                              \
      }                                                                          \
      __builtin_amdgcn_s_setprio(1);                                             \
      _Pragma("unroll") for (int kk = 0; kk < 2; ++kk)                           \
        _Pragma("unroll") for (int m2 = 0; m2 < 4; ++m2)                         \
          _Pragma("unroll") for (int n2 = 0; n2 < 2; ++n2)                       \
            acc[mh_ * 4 + m2][nh_ * 2 + n2] =                                    \
                __builtin_amdgcn_mfma_f32_16x16x32_bf16(                         \
                    areg[m2][kk], breg[n2][kk],                                  \
                    acc[mh_ * 4 + m2][nh_ * 2 + n2], 0, 0, 0);                   \
      __builtin_amdgcn_s_setprio(0);                                             \
      asm volatile("" ::: "memory");                                             \
    }                                                                            \
  } while (0)

__global__ __launch_bounds__(512, 2) void k_conv(
    const unsigned short* __restrict__ Yn, const unsigned short* __restrict__ Wob,
    const float* __restrict__ bo, const unsigned short* __restrict__ zp,
    unsigned short* __restrict__ co, float* __restrict__ bnp) {
  __shared__ __align__(16) unsigned short lds[8][8192];  // 8 x 16KB half-tile slots

  const int bid = blockIdx.x;
  const int swz = (bid & 7) * 64 + (bid >> 3);   // XCD-chunked, bijective (512=8*64)
  const int b = swz >> 6, tile = swz & 63;
  const int y0 = (tile >> 3) * 16, x0 = (tile & 7) * 16;
  const int tid = threadIdx.x;
  const int wave = tid >> 6, lane = tid & 63;
  const int lr = lane & 15, lk = lane >> 4;
  const int wm = wave >> 2, wn = wave & 3;
  const int cg = lane & 7;

  const unsigned short* yb = Yn + (size_t)b * 16384 * 256;

  auto STAGE = [&](int slot, int type, int KT) {
    if (type < 2) {
      const unsigned short* wsrc = Wob + (KT >> 2) * 256 + (KT & 3) * 64;
#pragma unroll
      for (int j = 0; j < 2; ++j) {
        int rp = (wave * 2 + j) * 8 + (lane >> 3);   // LDS row 0..127
        int o = ((rp >> 6) & 1) * 128 + type * 64 + (rp & 63);
        int kg = cg ^ (rp & 7);
        gload16(wsrc + o * 2304 + (kg << 3), &lds[slot][(wave * 2 + j) * 512]);
      }
    } else {
      int e = KT >> 2;
      int dy = e / 3 - 1, dx = e % 3 - 1, c8 = (KT & 3) * 8;
#pragma unroll
      for (int j = 0; j < 2; ++j) {
        int rp = (wave * 2 + j) * 8 + (lane >> 3);
        int n = ((rp >> 5) & 3) * 64 + (type - 2) * 32 + (rp & 31);
        int kg = cg ^ (rp & 7);
        int h = y0 + (n >> 4) + dy, ww = x0 + (n & 15) + dx;
        const unsigned short* src = zp;
        if (h >= 0 && h < 128 && ww >= 0 && ww < 128) {
          int pp = h * 128 + ww;
          src = yb + (size_t)pp * 256 + ((c8 + (kg ^ (pp & 7))) << 3);
        }
        gload16(src, &lds[slot][(wave * 2 + j) * 512]);
      }
    }
  };

  f32x4 acc[8][4];
#pragma unroll
  for (int m = 0; m < 8; ++m)
#pragma unroll
    for (int n = 0; n < 4; ++n)
#pragma unroll
      for (int r = 0; r < 4; ++r) acc[m][n][r] = 0.f;

  bf8 areg[4][2];

  STAGE(0, 0, 0); STAGE(1, 2, 0); STAGE(2, 3, 0); STAGE(3, 1, 0);
  asm volatile("s_waitcnt vmcnt(0)" ::: "memory");

  for (int gg = 0; gg < 17; ++gg) {
    const int k0 = gg * 2;
    CONV_PHASE(k0, 0, 0, true, 0);
    CONV_PHASE(k0, 1, 0, true, 0);
    CONV_PHASE(k0, 2, 0, true, 0);
    CONV_PHASE(k0, 3, 0, true, 0);
    CONV_PHASE(k0 + 1, 0, 1, true, 0);
    CONV_PHASE(k0 + 1, 1, 1, true, 0);
    CONV_PHASE(k0 + 1, 2, 1, true, 0);
    CONV_PHASE(k0 + 1, 3, 1, true, 0);
  }
  CONV_PHASE(34, 0, 0, true, 0);
  CONV_PHASE(34, 1, 0, true, 0);
  CONV_PHASE(34, 2, 0, true, 0);
  CONV_PHASE(34, 3, 0, true, 0);
  CONV_PHASE(35, 0, 1, false, 1);
  CONV_PHASE(35, 1, 1, false, 2);
  CONV_PHASE(35, 2, 1, false, 2);
  CONV_PHASE(35, 3, 1, false, 2);

  __syncthreads();
  unsigned short* cb = co + (size_t)b * 256 * 16384;
  float* red1 = (float*)&lds[0][0];     // [8][128]
  float* red2 = red1 + 1024;
#pragma unroll
  for (int m = 0; m < 8; ++m) {
#pragma unroll
    for (int r = 0; r < 4; ++r) {
      int o = wm * 128 + m * 16 + lk * 4 + r;
      float bvv = bo[o];
      float s1 = 0.f, s2 = 0.f;
#pragma unroll
      for (int n = 0; n < 4; ++n) {
        int pix = wn * 64 + n * 16 + lr;
        int py = pix >> 4, px = pix & 15;
        float v = acc[m][n][r] + bvv;
        cb[(size_t)o * 16384 + (y0 + py) * 128 + x0 + px] = f2bf(v);
        s1 += v;
        s2 += v * v;
      }
      for (int off = 1; off < 16; off <<= 1) {
        s1 += __shfl_xor(s1, off, 64);
        s2 += __shfl_xor(s2, off, 64);
      }
      if (lr == 0) {
        int ol = m * 16 + lk * 4 + r;
        red1[wave * 128 + ol] = s1;
        red2[wave * 128 + ol] = s2;
      }
    }
  }
  __syncthreads();
  {
    int o = tid & 255, stat = tid >> 8;
    int wm2 = o >> 7, ol = o & 127;
    const float* rd = stat ? red2 : red1;
    float s = rd[(wm2 * 4 + 0) * 128 + ol] + rd[(wm2 * 4 + 1) * 128 + ol] +
              rd[(wm2 * 4 + 2) * 128 + ol] + rd[(wm2 * 4 + 3) * 128 + ol];
    bnp[((size_t)(b * 64 + tile) * 256 + o) * 2 + stat] = s;
  }
}

// ---------------- BN reduce + apply ----------------
__global__ __launch_bounds__(256) void k_bnred(
    const float* __restrict__ bnp, const float* __restrict__ gamma,
    const float* __restrict__ beta, float* __restrict__ bns) {
  const int o = blockIdx.x;
  const int tid = threadIdx.x;
  float s1 = 0.f, s2 = 0.f;
  for (int k = tid; k < 512; k += 256) {
    s1 += bnp[((size_t)k * 256 + o) * 2 + 0];
    s2 += bnp[((size_t)k * 256 + o) * 2 + 1];
  }
  __shared__ float r1[256], r2[256];
  r1[tid] = s1; r2[tid] = s2;
  __syncthreads();
  for (int off = 128; off > 0; off >>= 1) {
    if (tid < off) { r1[tid] += r1[tid + off]; r2[tid] += r2[tid + off]; }
    __syncthreads();
  }
  if (tid == 0) {
    const float cnt = 8.0f * 16384.0f;
    float mean = r1[0] / cnt;
    float var = r2[0] / cnt - mean * mean;
    float sc = gamma[o] * rsqrtf(var + 1e-5f);
    bns[o] = sc;
    bns[256 + o] = beta[o] - mean * sc;
  }
}

__global__ void k_bnapply(const unsigned short* __restrict__ co, float* __restrict__ out,
                          const float* __restrict__ bns) {
  size_t i = ((size_t)blockIdx.x * 256 + threadIdx.x) * 8;
  const size_t total = 33554432;
  const size_t stride = (size_t)gridDim.x * 256 * 8;
  for (; i < total; i += stride) {
    uint4 v = *(const uint4*)(co + i);
    int o = (int)((i >> 14) & 255);
    float sc = bns[o], shv = bns[256 + o];
    const unsigned short* pv = (const unsigned short*)&v;
    float r[8];
#pragma unroll
    for (int e = 0; e < 8; ++e) {
      float f = bf2f(pv[e]) * sc + shv;
      r[e] = f > 0.f ? f : 0.2f * f;
    }
    *(float4*)(out + i) = *(const float4*)&r[0];
    *(float4*)(out + i + 4) = *(const float4*)&r[4];
  }
}

// ---------------- launcher ----------------
extern "C" void kernel_launch(void* const* d_in, const int* in_sizes, int n_in,
                              void* d_out, int out_size, void* d_ws, size_t ws_size,
                              hipStream_t stream) {
  if (ws_size < WS_NEED) return;

  const float* x     = (const float*)d_in[0];
  const float* wq    = (const float*)d_in[1];
  const float* bq    = (const float*)d_in[2];
  const float* wk    = (const float*)d_in[3];
  const float* bk    = (const float*)d_in[4];
  const float* wv    = (const float*)d_in[5];
  const float* bv    = (const float*)d_in[6];
  const float* wo    = (const float*)d_in[7];
  const float* bo    = (const float*)d_in[8];
  const float* gamma = (const float*)d_in[9];
  const float* beta  = (const float*)d_in[10];
  float* out = (float*)d_out;
  char* ws = (char*)d_ws;

  unsigned short* Wb  = (unsigned short*)(ws + WB_OFF);
  unsigned short* Wob = (unsigned short*)(ws + WOB_OFF);
  unsigned short* Qn  = (unsigned short*)(ws + QN_OFF);
  unsigned short* Kn  = (unsigned short*)(ws + KN_OFF);
  unsigned short* Vn  = (unsigned short*)(ws + VN_OFF);
  unsigned short* Yn  = (unsigned short*)(ws + YN_OFF);
  float* part3 = (float*)(ws + YN_OFF);          // overlay: used before Yn is written
  unsigned short* co = (unsigned short*)(ws + QN_OFF);  // overlay: Qn dead after grams
  float* scores = (float*)(ws + SC_OFF);
  unsigned short* prb = (unsigned short*)(ws + PRB_OFF);
  float* bnp    = (float*)(ws + BNP_OFF);
  float* bns    = (float*)(ws + BNS_OFF);
  unsigned short* zp = (unsigned short*)(ws + ZP_OFF);

  k_prep<<<dim3(3072), dim3(256), 0, stream>>>(wq, wk, wv, wo, Wb, Wob);
  k_zero2<<<dim3(137), dim3(256), 0, stream>>>(scores, 34944, (float*)zp, 64);
  k_qkv<<<dim3(256, 8), dim3(256), 0, stream>>>(x, Wb, bq, bk, bv, Qn, Kn, Vn);
  k_gramA<<<dim3(128, 8), dim3(256), 0, stream>>>(Qn, Kn, scores, part3);
  k_smA<<<dim3(11, 8), dim3(256), 0, stream>>>(scores, part3, prb);
  k_pvA<<<dim3(320, 8), dim3(256), 0, stream>>>(Vn, prb, Yn);
  k_conv<<<dim3(512), dim3(512), 0, stream>>>(Yn, Wob, bo, zp, co, bnp);
  k_bnred<<<dim3(256), dim3(256), 0, stream>>>(bnp, gamma, beta, bns);
  k_bnapply<<<dim3(4096), dim3(256), 0, stream>>>(co, out, bns);
}

// Round 12
// 545.192 us; speedup vs baseline: 1.3379x; 1.0033x over previous
//
#include <hip/hip_runtime.h>
#include <stdint.h>

// ---------------- geometry ----------------
// B=8, C=256, H=W=128, HW=16384, 4 heads of d_k=64
// idx: HS=WS=2<<idx, S=HS*HS, OH=OW=64>>idx, NSP=OH*OW
// gather:  q[s=(i,j)][d=(c,ohi,owi)] = Q[lo+c][ohi*HS+i][owi*WS+j], s=i*WS+j
// scatter: Y[lo+c][i*OH+ohi][j*OW+owi] = y[s][d]   (transposed vs gather!)
// NHWC buffers (Qn,Kn,Vn,Yn): element (p, c) at [p*256 + (c ^ ((p&7)<<3))]
// granule rule: 8-ch granule g of pixel p sits at granule slot (g ^ (p&7)).

#define DEVI static __device__ __forceinline__

typedef short bf8 __attribute__((ext_vector_type(8)));   // 8 bf16 (4 VGPRs)
typedef float f32x4 __attribute__((ext_vector_type(4)));

DEVI unsigned short f2bf(float f) {
  unsigned u = __builtin_bit_cast(unsigned, f);
  u = (u + 0x7fffu + ((u >> 16) & 1u)) >> 16;
  return (unsigned short)u;
}
DEVI float bf2f(unsigned short h) {
  unsigned u = ((unsigned)h) << 16;
  return __builtin_bit_cast(float, u);
}

DEVI void gload16(const void* g, void* l) {
  __builtin_amdgcn_global_load_lds(
      (const __attribute__((address_space(1))) unsigned int*)g,
      (__attribute__((address_space(3))) unsigned int*)l, 16, 0, 0);
}

// ---------------- ws layout (bytes) ----------------
static const size_t WB_OFF  = 0;                        // bf16 [3][256][256]
static const size_t WOB_OFF = 393216;                   // bf16 [256][2304] k=(e*256+c)
static const size_t QN_OFF  = 1572864;                  // bf16 NHWC-swz [8][16384][256]; co overlay after grams
static const size_t KN_OFF  = QN_OFF + 67108864;
static const size_t VN_OFF  = KN_OFF + 67108864;
static const size_t YN_OFF  = VN_OFF + 67108864;        // bf16 NHWC-swz (also part3 overlay)
static const size_t SC_OFF  = YN_OFF + 67108864;        // f32 scores idx0-2 (34944 floats used)
static const size_t PRB_OFF = SC_OFF + 2236928;         // bf16 probs (559232)
static const size_t BNP_OFF = PRB_OFF + 1118464;        // f32 [512][256][2]
static const size_t BNS_OFF = BNP_OFF + 4194304;        // f32 [2][256]
static const size_t ZP_OFF  = BNS_OFF + 2048;           // 256B zero page for OOB gloads
static const size_t WS_NEED = ZP_OFF + 256;

// ---------------- prep: weights -> bf16 (wo reordered) + zero scores/zp ----------------
__global__ void k_prep(const float* __restrict__ wq, const float* __restrict__ wk,
                       const float* __restrict__ wv, const float* __restrict__ wo,
                       unsigned short* __restrict__ Wb, unsigned short* __restrict__ Wob,
                       float* __restrict__ sc0, float* __restrict__ zp0) {
  int i = blockIdx.x * 256 + threadIdx.x;        // grid covers 786432 exactly
  if (i < 34944) sc0[i] = 0.f;
  else if (i < 35008) zp0[i - 34944] = 0.f;
  if (i < 196608) {
    int z = i >> 16, r = i & 65535;
    const float* w = (z == 0) ? wq : (z == 1) ? wk : wv;
    Wb[i] = f2bf(w[r]);
  } else {
    int j = i - 196608;
    int o = j / 2304, k = j - o * 2304;
    int e = k >> 8, c = k & 255;
    Wob[j] = f2bf(wo[(o * 256 + c) * 9 + e]);    // Wob[o][e*256+c] = wo[o][c][e]
  }
}

// ---------------- fused QKV projection (48KB LDS) ----------------
// staging: lane = pixel, wave-strided c-quads; loads batch-prefetched (32 in
// flight) before convert+ds_write to break the load->cvt->write latency chain.
__global__ __launch_bounds__(256, 2) void k_qkv(
    const float* __restrict__ x, const unsigned short* __restrict__ Wb,
    const float* __restrict__ bq, const float* __restrict__ bk, const float* __restrict__ bv,
    unsigned short* __restrict__ Qn, unsigned short* __restrict__ Kn,
    unsigned short* __restrict__ Vn) {
  const int pt = blockIdx.x, b = blockIdx.y;
  const int p0 = pt * 64;
  const int tid = threadIdx.x;

  __shared__ __align__(16) unsigned short xt[64 * 256];  // input tile [p][c'] swizzled 32KB
  __shared__ __align__(16) unsigned short ot[32 * 256];  // output chunk buffer 16KB

  const int wave = tid >> 6, lane = tid & 63;

  {
    const float* xb = x + (size_t)b * 256 * 16384 + p0;
    const int xsw = (lane & 7) << 3;
    float reg[32];
#pragma unroll
    for (int half = 0; half < 2; ++half) {
#pragma unroll
      for (int it = 0; it < 8; ++it) {
        int c4 = ((half * 8 + it) * 4 + wave) * 4;
#pragma unroll
        for (int j = 0; j < 4; ++j)
          reg[it * 4 + j] = xb[(size_t)(c4 + j) * 16384 + lane];
      }
#pragma unroll
      for (int it = 0; it < 8; ++it) {
        int c4 = ((half * 8 + it) * 4 + wave) * 4;
        unsigned short tmp[4];
#pragma unroll
        for (int j = 0; j < 4; ++j) tmp[j] = f2bf(reg[it * 4 + j]);
        *(ushort4*)(&xt[lane * 256 + (c4 ^ xsw)]) = *(const ushort4*)tmp;
      }
    }
  }
  __syncthreads();

  const int lr = lane & 15, lk = lane >> 4;
  const int obase = wave * 64;

  for (int z = 0; z < 3; ++z) {
    const unsigned short* Wz = Wb + (size_t)z * 65536;
    f32x4 acc[4][4];
    for (int m = 0; m < 4; ++m)
      for (int n = 0; n < 4; ++n)
        for (int r = 0; r < 4; ++r) acc[m][n][r] = 0.f;

#pragma unroll 2
    for (int ks = 0; ks < 8; ++ks) {
      int c0 = ks * 32 + lk * 8;
      bf8 a[4], bb[4];
#pragma unroll
      for (int m = 0; m < 4; ++m)
        a[m] = *(const bf8*)(Wz + (size_t)(obase + m * 16 + lr) * 256 + c0);
#pragma unroll
      for (int n = 0; n < 4; ++n) {
        int p = n * 16 + lr;
        bb[n] = *(const bf8*)(&xt[p * 256 + (c0 ^ ((p & 7) << 3))]);
      }
      __builtin_amdgcn_s_setprio(1);
#pragma unroll
      for (int m = 0; m < 4; ++m)
#pragma unroll
        for (int n = 0; n < 4; ++n)
          acc[m][n] = __builtin_amdgcn_mfma_f32_16x16x32_bf16(a[m], bb[n], acc[m][n], 0, 0, 0);
      __builtin_amdgcn_s_setprio(0);
    }

    const float* bias = (z == 0) ? bq : (z == 1) ? bk : bv;
    unsigned short* On = (z == 0) ? Qn : (z == 1) ? Kn : Vn;
    // epilogue in two 32-px chunks through the 16KB ot buffer
    for (int h = 0; h < 2; ++h) {
      __syncthreads();   // prior ot consumers done
#pragma unroll
      for (int m = 0; m < 4; ++m) {
        int ob4 = obase + m * 16 + lk * 4;
        float4 b4 = *(const float4*)(bias + ob4);
#pragma unroll
        for (int nn = 0; nn < 2; ++nn) {
          int n = h * 2 + nn;
          int pch = nn * 16 + lr;            // chunk-local pixel 0..31
          ushort4 v4;
          v4.x = f2bf(acc[m][n][0] + b4.x);
          v4.y = f2bf(acc[m][n][1] + b4.y);
          v4.z = f2bf(acc[m][n][2] + b4.z);
          v4.w = f2bf(acc[m][n][3] + b4.w);
          *(ushort4*)(&ot[pch * 256 + (ob4 ^ ((pch & 7) << 3))]) = v4;
        }
      }
      __syncthreads();
      unsigned short* gb = On + ((size_t)b * 16384 + p0 + h * 32) * 256;
#pragma unroll
      for (int i = 0; i < 4; ++i) {
        int ch = tid + i * 256;              // 1024 cells x 16B = 16KB
        *(uint4*)(gb + ch * 8) = *(const uint4*)(&ot[ch * 8]);
      }
    }
  }
}

// ---------------- Gram bodies (merged dispatch) ----------------
template <int IDX>
DEVI void gram_body(int chk, int b,
                    const unsigned short* __restrict__ Qn,
                    const unsigned short* __restrict__ Kn,
                    float* __restrict__ scores, char* smem) {
  constexpr int HS = 2 << IDX, S = HS * HS, OH = 64 >> IDX, NSP = OH * OH;
  constexpr int SPW = (IDX == 2) ? 2 : 8;
  constexpr int DSUB = SPW * 64;
  constexpr int SPB = NSP / 32;
  constexpr int STEPS = SPB / SPW;
  constexpr int ROWS = S;
  constexpr int TPT = S * SPW * 8 / 256;
  constexpr int SCOFF = (IDX == 0) ? 0 : (IDX == 1) ? 128 : 2176;
  constexpr int HC = IDX * 64;
  constexpr int MT = (IDX == 2) ? 4 : 1;

  unsigned short* qg = (unsigned short*)smem;                       // ROWS*DSUB
  unsigned short* kg = (unsigned short*)(smem + ROWS * DSUB * 2);
  float* red = (float*)(smem + ROWS * DSUB * 4);                    // S*S floats

  const int tid = threadIdx.x;
  const int wave = tid >> 6, lane = tid & 63, lr = lane & 15, lk = lane >> 4;
  const size_t base = (size_t)b * 16384 * 256;

  f32x4 acc[MT][MT];
  for (int m = 0; m < MT; ++m)
    for (int n = 0; n < MT; ++n)
      for (int r = 0; r < 4; ++r) acc[m][n][r] = 0.f;

  for (int st = 0; st < STEPS; ++st) {
    const int sp0 = chk * SPB + st * SPW;
    __syncthreads();
#pragma unroll
    for (int r = 0; r < TPT; ++r) {
      int task = tid + r * 256;
      int cg = task & 7, pl = task >> 3;
      int spl = pl >> (2 * (IDX + 1)), s = pl & (S - 1);
      int sp = sp0 + spl;
      int ohi = sp >> (6 - IDX), owi = sp & (OH - 1);
      int ii = s >> (IDX + 1), jj = s & (HS - 1);
      int p = (ohi * HS + ii) * 128 + owi * HS + jj;
      size_t gaddr = base + (size_t)p * 256 + HC + ((cg ^ (p & 7)) << 3);
      int laddr = s * DSUB + (((spl * 8 + cg) ^ (s & 7)) << 3);
      *(uint4*)(qg + laddr) = *(const uint4*)(Qn + gaddr);
      *(uint4*)(kg + laddr) = *(const uint4*)(Kn + gaddr);
    }
    __syncthreads();
    if (IDX == 2) {
      int kgid = wave * 4 + lk;
      bf8 a[4], bb[4];
#pragma unroll
      for (int m = 0; m < 4; ++m) {
        int row = m * 16 + lr;
        int off = row * DSUB + ((kgid ^ (row & 7)) << 3);
        a[m] = *(const bf8*)(qg + off);
        bb[m] = *(const bf8*)(kg + off);
      }
#pragma unroll
      for (int m = 0; m < MT; ++m)
#pragma unroll
        for (int n = 0; n < MT; ++n)
          acc[m][n] = __builtin_amdgcn_mfma_f32_16x16x32_bf16(a[m], bb[n], acc[m][n], 0, 0, 0);
    } else {
      int row = lr & (ROWS - 1);
#pragma unroll
      for (int kk = 0; kk < 4; ++kk) {
        int kgid = (wave * 4 + kk) * 4 + lk;
        int off = row * DSUB + ((kgid ^ (row & 7)) << 3);
        bf8 a = *(const bf8*)(qg + off);
        bf8 bb = *(const bf8*)(kg + off);
        acc[0][0] = __builtin_amdgcn_mfma_f32_16x16x32_bf16(a, bb, acc[0][0], 0, 0, 0);
      }
    }
  }

  __syncthreads();
  for (int i2 = tid; i2 < S * S; i2 += 256) red[i2] = 0.f;
  __syncthreads();
  if (IDX == 2) {
#pragma unroll
    for (int m = 0; m < MT; ++m)
#pragma unroll
      for (int n = 0; n < MT; ++n)
#pragma unroll
        for (int r = 0; r < 4; ++r)
          atomicAdd(&red[(m * 16 + lk * 4 + r) * 64 + n * 16 + lr], acc[m][n][r]);
  } else if (IDX == 1) {
#pragma unroll
    for (int r = 0; r < 4; ++r)
      atomicAdd(&red[(lk * 4 + r) * 16 + lr], acc[0][0][r]);
  } else {
    if (lk == 0 && lr < 4) {
#pragma unroll
      for (int r = 0; r < 4; ++r)
        atomicAdd(&red[r * 4 + lr], acc[0][0][r]);
    }
  }
  __syncthreads();
  float* sc = scores + SCOFF + (size_t)b * S * S;
  for (int i2 = tid; i2 < S * S; i2 += 256) atomicAdd(sc + i2, red[i2]);
}

DEVI void gram3_body(int qc, int tq, int b,
                     const unsigned short* __restrict__ Qn,
                     const unsigned short* __restrict__ Kn,
                     float* __restrict__ part3, char* smem) {
  unsigned short* qg = (unsigned short*)smem;            // 256*64 = 32KB
  unsigned short* kg = (unsigned short*)(smem + 32768);  // 64*64  = 8KB

  const int tid = threadIdx.x;
  const int wave = tid >> 6, lane = tid & 63, lr = lane & 15, lk = lane >> 4;
  const size_t base = (size_t)b * 16384 * 256;

  f32x4 acc[4][4];
  for (int m = 0; m < 4; ++m)
    for (int n = 0; n < 4; ++n)
      for (int r = 0; r < 4; ++r) acc[m][n][r] = 0.f;

  for (int st = 0; st < 8; ++st) {
    int sp = qc * 8 + st;
    int ohi = sp >> 3, owi = sp & 7;
    __syncthreads();
#pragma unroll
    for (int r = 0; r < 8; ++r) {
      int task = tid + r * 256;
      int cg = task & 7, s = task >> 3;
      int p = (ohi * 16 + (s >> 4)) * 128 + owi * 16 + (s & 15);
      uint4 v = *(const uint4*)(Qn + base + (size_t)p * 256 + 192 + ((cg ^ (p & 7)) << 3));
      *(uint4*)(qg + s * 64 + ((cg ^ (s & 7)) << 3)) = v;
    }
#pragma unroll
    for (int r = 0; r < 2; ++r) {
      int task = tid + r * 256;
      int cg = task & 7, tl = task >> 3;
      int p = (ohi * 16 + tq * 4 + (tl >> 4)) * 128 + owi * 16 + (tl & 15);
      uint4 v = *(const uint4*)(Kn + base + (size_t)p * 256 + 192 + ((cg ^ (p & 7)) << 3));
      *(uint4*)(kg + tl * 64 + ((cg ^ (tl & 7)) << 3)) = v;
    }
    __syncthreads();
#pragma unroll
    for (int kk = 0; kk < 2; ++kk) {
      int kgid = kk * 4 + lk;
      bf8 a[4], bb[4];
#pragma unroll
      for (int m = 0; m < 4; ++m) {
        int row = wave * 64 + m * 16 + lr;
        a[m] = *(const bf8*)(qg + row * 64 + ((kgid ^ (row & 7)) << 3));
      }
#pragma unroll
      for (int n = 0; n < 4; ++n) {
        int rowb = n * 16 + lr;
        bb[n] = *(const bf8*)(kg + rowb * 64 + ((kgid ^ (rowb & 7)) << 3));
      }
#pragma unroll
      for (int m = 0; m < 4; ++m)
#pragma unroll
        for (int n = 0; n < 4; ++n)
          acc[m][n] = __builtin_amdgcn_mfma_f32_16x16x32_bf16(a[m], bb[n], acc[m][n], 0, 0, 0);
    }
  }

  float* pb = part3 + (((size_t)qc * 8 + b) * 65536);
#pragma unroll
  for (int m = 0; m < 4; ++m)
#pragma unroll
    for (int r = 0; r < 4; ++r) {
      int srow = wave * 64 + m * 16 + lk * 4 + r;
#pragma unroll
      for (int n = 0; n < 4; ++n)
        pb[srow * 256 + tq * 64 + n * 16 + lr] = acc[m][n][r];
    }
}

// merged gram dispatch: grid (128, 8)
__global__ __launch_bounds__(256) void k_gramA(
    const unsigned short* __restrict__ Qn, const unsigned short* __restrict__ Kn,
    float* __restrict__ scores, float* __restrict__ part3) {
  __shared__ __align__(16) char smem[49152];
  const int bx = blockIdx.x, b = blockIdx.y;
  if (bx < 32)       gram_body<0>(bx, b, Qn, Kn, scores, smem);
  else if (bx < 64)  gram_body<1>(bx - 32, b, Qn, Kn, scores, smem);
  else if (bx < 96)  gram_body<2>(bx - 64, b, Qn, Kn, scores, smem);
  else               gram3_body((bx - 96) & 7, (bx - 96) >> 3, b, Qn, Kn, part3, smem);
}

// ---------------- softmax bodies (merged) ----------------
DEVI void softmax_body(int idx, int b, const float* __restrict__ scores,
                       unsigned short* __restrict__ prb) {
  const int S = 4 << (2 * idx);
  const int off = (idx == 0 ? 0 : idx == 1 ? 128 : 2176) + b * S * S;
  const int s = threadIdx.x;
  if (s >= S) return;
  const float scale = rsqrtf(64.0f * (float)(4096 >> (2 * idx)));
  const float* row = scores + off + s * S;
  float m = -1e30f;
  for (int t = 0; t < S; ++t) m = fmaxf(m, row[t]);
  m *= scale;
  float sum = 0.f;
  for (int t = 0; t < S; ++t) sum += __expf(row[t] * scale - m);
  float inv = 1.0f / sum;
  unsigned short* prow = prb + off + s * S;
  for (int t = 0; t < S; ++t) prow[t] = f2bf(__expf(row[t] * scale - m) * inv);
}

DEVI void softmax3_body(int sc_, int b, const float* __restrict__ part3,
                        unsigned short* __restrict__ prb) {
  const int tid = threadIdx.x;
  const int s = sc_ * 32 + (tid >> 3);
  const int t0 = (tid & 7) * 32;
  float v[32];
#pragma unroll
  for (int k = 0; k < 32; ++k) v[k] = 0.f;
  for (int q = 0; q < 8; ++q) {
    const float4* pp = (const float4*)(part3 + (((size_t)q * 8 + b) * 256 + s) * 256 + t0);
#pragma unroll
    for (int k = 0; k < 8; ++k) {
      float4 u = pp[k];
      v[k * 4 + 0] += u.x; v[k * 4 + 1] += u.y; v[k * 4 + 2] += u.z; v[k * 4 + 3] += u.w;
    }
  }
  const float scale = 1.0f / 64.0f;
  float m = -1e30f;
#pragma unroll
  for (int k = 0; k < 32; ++k) { v[k] *= scale; m = fmaxf(m, v[k]); }
  m = fmaxf(m, __shfl_xor(m, 1));
  m = fmaxf(m, __shfl_xor(m, 2));
  m = fmaxf(m, __shfl_xor(m, 4));
  float sum = 0.f;
#pragma unroll
  for (int k = 0; k < 32; ++k) { v[k] = __expf(v[k] - m); sum += v[k]; }
  sum += __shfl_xor(sum, 1);
  sum += __shfl_xor(sum, 2);
  sum += __shfl_xor(sum, 4);
  float inv = 1.0f / sum;
  unsigned short* prw = prb + 34944 + (size_t)b * 65536 + s * 256 + t0;
#pragma unroll
  for (int k8 = 0; k8 < 4; ++k8) {
    unsigned short tmp[8];
#pragma unroll
    for (int e = 0; e < 8; ++e) tmp[e] = f2bf(v[k8 * 8 + e] * inv);
    *(uint4*)(prw + k8 * 8) = *(const uint4*)tmp;
  }
}

// merged softmax dispatch: grid (11, 8)
__global__ __launch_bounds__(256) void k_smA(const float* __restrict__ scores,
                                             const float* __restrict__ part3,
                                             unsigned short* __restrict__ prb) {
  const int bx = blockIdx.x, b = blockIdx.y;
  if (bx < 3) softmax_body(bx, b, scores, prb);
  else        softmax3_body(bx - 3, b, part3, prb);
}

// ---------------- PV bodies (merged) ----------------
template <int IDX>
DEVI void pv_body(int bx, int b, const unsigned short* __restrict__ Vn,
                  const unsigned short* __restrict__ prb,
                  unsigned short* __restrict__ Yn, char* smem) {
  constexpr int HS = 2 << IDX, S = HS * HS, OH = 64 >> IDX;
  constexpr int IT = (IDX == 0) ? 8 : (IDX == 1) ? 4 : 1;
  constexpr int POFF = (IDX == 0) ? 0 : (IDX == 1) ? 128 : 2176;
  float* pl = (float*)smem;                          // S*S floats (<=16KB)
  const int c = threadIdx.x & 63, spg = threadIdx.x >> 6;
  const unsigned short* pr = prb + POFF + (size_t)b * S * S;
  for (int i = threadIdx.x; i < S * S; i += 256) pl[i] = bf2f(pr[i]);
  __syncthreads();
  const int hc = IDX * 64;
  const unsigned short* vb = Vn + (size_t)b * 16384 * 256;
  unsigned short* yb = Yn + (size_t)b * 16384 * 256;
  for (int it = 0; it < IT; ++it) {
    int sp = bx * (4 * IT) + it * 4 + spg;
    int ohi = sp >> (6 - IDX), owi = sp & (OH - 1);
    float v[S];
#pragma unroll
    for (int t = 0; t < S; ++t) {
      int po = (ohi * HS + t / HS) * 128 + owi * HS + (t % HS);
      v[t] = bf2f(vb[(size_t)po * 256 + ((hc + c) ^ ((po & 7) << 3))]);
    }
    for (int s = 0; s < S; ++s) {
      const float4* p4 = (const float4*)(pl + s * S);
      float a = 0.f;
#pragma unroll
      for (int t4 = 0; t4 < S / 4; ++t4) {
        float4 pp = p4[t4];
        a += pp.x * v[t4 * 4] + pp.y * v[t4 * 4 + 1] + pp.z * v[t4 * 4 + 2] + pp.w * v[t4 * 4 + 3];
      }
      int po = ((s >> (IDX + 1)) * OH + ohi) * 128 + (s & (HS - 1)) * OH + owi;
      yb[(size_t)po * 256 + ((hc + c) ^ ((po & 7) << 3))] = f2bf(a);
    }
  }
}

DEVI void pv3_body(int sp, int b, const unsigned short* __restrict__ Vn,
                   const unsigned short* __restrict__ prb,
                   unsigned short* __restrict__ Yn, char* smem) {
  unsigned short* vl = (unsigned short*)smem;        // 64*256 = 32KB
  const int ohi = sp >> 3, owi = sp & 7;
  const int tid = threadIdx.x;
  const unsigned short* vb = Vn + (size_t)b * 16384 * 256;
  {
    int t = tid;
    int po = (ohi * 16 + (t >> 4)) * 128 + owi * 16 + (t & 15);
    const unsigned short* src = vb + (size_t)po * 256;
    int xv = (po & 7) << 3;
#pragma unroll
    for (int g = 0; g < 8; ++g) {
      ushort4 lo = *(const ushort4*)(src + ((192 + g * 8) ^ xv));
      ushort4 hi = *(const ushort4*)(src + ((192 + g * 8) ^ xv) + 4);
      unsigned short vv[8] = {lo.x, lo.y, lo.z, lo.w, hi.x, hi.y, hi.z, hi.w};
#pragma unroll
      for (int e = 0; e < 8; ++e) {
        int cc = g * 8 + e;
        vl[cc * 256 + (t ^ ((cc & 7) << 3))] = vv[e];
      }
    }
  }
  __syncthreads();

  const int wave = tid >> 6, lane = tid & 63;
  const int lr = lane & 15, lk = lane >> 4;
  const int sb = wave * 64;
  const unsigned short* pr = prb + 34944 + (size_t)b * 65536;

  f32x4 acc[4][4];
  for (int m = 0; m < 4; ++m)
    for (int n = 0; n < 4; ++n)
      for (int r = 0; r < 4; ++r) acc[m][n][r] = 0.f;

  for (int kk = 0; kk < 8; ++kk) {
    int t0 = kk * 32 + lk * 8;
    bf8 a[4], bb[4];
#pragma unroll
    for (int m = 0; m < 4; ++m)
      a[m] = *(const bf8*)(pr + (size_t)(sb + m * 16 + lr) * 256 + t0);
#pragma unroll
    for (int n = 0; n < 4; ++n) {
      int cc = n * 16 + lr;
      bb[n] = *(const bf8*)(&vl[cc * 256 + (t0 ^ ((cc & 7) << 3))]);
    }
#pragma unroll
    for (int m = 0; m < 4; ++m)
#pragma unroll
      for (int n = 0; n < 4; ++n)
        acc[m][n] = __builtin_amdgcn_mfma_f32_16x16x32_bf16(a[m], bb[n], acc[m][n], 0, 0, 0);
  }

  unsigned short* yb = Yn + (size_t)b * 16384 * 256;
#pragma unroll
  for (int m = 0; m < 4; ++m) {
#pragma unroll
    for (int r = 0; r < 4; ++r) {
      int s = sb + m * 16 + lk * 4 + r;
      int si = s >> 4, sj = s & 15;
      int po = (si * 8 + ohi) * 128 + sj * 8 + owi;
#pragma unroll
      for (int n = 0; n < 4; ++n) {
        int cc = 192 + n * 16 + lr;
        yb[(size_t)po * 256 + (cc ^ (owi << 3))] = f2bf(acc[m][n][r]);
      }
    }
  }
}

// merged PV dispatch: grid (320, 8)
__global__ __launch_bounds__(256) void k_pvA(
    const unsigned short* __restrict__ Vn, const unsigned short* __restrict__ prb,
    unsigned short* __restrict__ Yn) {
  __shared__ __align__(16) char smem[32768];
  const int bx = blockIdx.x, b = blockIdx.y;
  if (bx < 128)      pv_body<0>(bx, b, Vn, prb, Yn, smem);
  else if (bx < 192) pv_body<1>(bx - 128, b, Vn, prb, Yn, smem);
  else if (bx < 256) pv_body<2>(bx - 192, b, Vn, prb, Yn, smem);
  else               pv3_body(bx - 256, b, Vn, prb, Yn, smem);
}

// ---------------- 3x3 conv: 256x256x2304 GEMM, 8-slot ring (known-good) ----------------
#define CONV_PHASE(KT_, R_, PK_, DOSTAGE_, WAITMODE_)                            \
  do {                                                                           \
    if (DOSTAGE_) {                                                              \
      constexpr int type_ = (R_ == 0) ? 0 : (R_ == 1) ? 2 : (R_ == 2) ? 3 : 1;   \
      STAGE((1 - (PK_)) * 4 + (R_), type_, (KT_) + 1);                           \
    }                                                                            \
    if ((WAITMODE_) == 0) { asm volatile("s_waitcnt vmcnt(6)" ::: "memory"); }   \
    else if ((WAITMODE_) == 1) { asm volatile("s_waitcnt vmcnt(0)" ::: "memory"); } \
    __builtin_amdgcn_s_barrier();                                                \
    asm volatile("" ::: "memory");                                               \
    {                                                                            \
      constexpr int mh_ = (R_) >> 1, nh_ = (R_) & 1;                             \
      constexpr int sA_ = (PK_) * 4 + (mh_ ? 3 : 0);                             \
      constexpr int sB_ = (PK_) * 4 + (nh_ ? 2 : 1);                             \
      if (nh_ == 0) {                                                            \
        _Pragma("unroll") for (int m2 = 0; m2 < 4; ++m2) {                       \
          int row = wm * 64 + m2 * 16 + lr;                                      \
          _Pragma("unroll") for (int kk = 0; kk < 2; ++kk)                       \
            areg[m2][kk] = *(const bf8*)(&lds[sA_][row * 64 +                    \
                (((kk * 4 + lk) ^ (row & 7)) << 3)]);                            \
        }                                                                        \
      }                                                                          \
      bf8 breg[2][2];                                                            \
      _Pragma("unroll") for (int n2 = 0; n2 < 2; ++n2) {                         \
        int row = wn * 32 + n2 * 16 + lr;                                        \
        _Pragma("unroll") for (int kk = 0; kk < 2; ++kk)                         \
          breg[n2][kk] = *(const bf8*)(&lds[sB_][row * 64 +                      \
              (((kk * 4 + lk) ^ (row & 7)) << 3)]);                              \
      }                                                                          \
      __builtin_amdgcn_s_setprio(1);                                             \
      _Pragma("unroll") for (int kk = 0; kk < 2; ++kk)                           \
        _Pragma("unroll") for (int m2 = 0; m2 < 4; ++m2)                         \
          _Pragma("unroll") for (int n2 = 0; n2 < 2; ++n2)                       \
            acc[mh_ * 4 + m2][nh_ * 2 + n2] =                                    \
                __builtin_amdgcn_mfma_f32_16x16x32_bf16(                         \
                    areg[m2][kk], breg[n2][kk],                                  \
                    acc[mh_ * 4 + m2][nh_ * 2 + n2], 0, 0, 0);                   \
      __builtin_amdgcn_s_setprio(0);                                             \
      asm volatile("" ::: "memory");                                             \
    }                                                                            \
  } while (0)

__global__ __launch_bounds__(512, 2) void k_conv(
    const unsigned short* __restrict__ Yn, const unsigned short* __restrict__ Wob,
    const float* __restrict__ bo, const unsigned short* __restrict__ zp,
    unsigned short* __restrict__ co, float* __restrict__ bnp) {
  __shared__ __align__(16) unsigned short lds[8][8192];  // 8 x 16KB half-tile slots

  const int bid = blockIdx.x;
  const int swz = (bid & 7) * 64 + (bid >> 3);   // XCD-chunked, bijective (512=8*64)
  const int b = swz >> 6, tile = swz & 63;
  const int y0 = (tile >> 3) * 16, x0 = (tile & 7) * 16;
  const int tid = threadIdx.x;
  const int wave = tid >> 6, lane = tid & 63;
  const int lr = lane & 15, lk = lane >> 4;
  const int wm = wave >> 2, wn = wave & 3;
  const int cg = lane & 7;

  const unsigned short* yb = Yn + (size_t)b * 16384 * 256;

  auto STAGE = [&](int slot, int type, int KT) {
    if (type < 2) {
      const unsigned short* wsrc = Wob + (KT >> 2) * 256 + (KT & 3) * 64;
#pragma unroll
      for (int j = 0; j < 2; ++j) {
        int rp = (wave * 2 + j) * 8 + (lane >> 3);   // LDS row 0..127
        int o = ((rp >> 6) & 1) * 128 + type * 64 + (rp & 63);
        int kg = cg ^ (rp & 7);
        gload16(wsrc + o * 2304 + (kg << 3), &lds[slot][(wave * 2 + j) * 512]);
      }
    } else {
      int e = KT >> 2;
      int dy = e / 3 - 1, dx = e % 3 - 1, c8 = (KT & 3) * 8;
#pragma unroll
      for (int j = 0; j < 2; ++j) {
        int rp = (wave * 2 + j) * 8 + (lane >> 3);
        int n = ((rp >> 5) & 3) * 64 + (type - 2) * 32 + (rp & 31);
        int kg = cg ^ (rp & 7);
        int h = y0 + (n >> 4) + dy, ww = x0 + (n & 15) + dx;
        const unsigned short* src = zp;
        if (h >= 0 && h < 128 && ww >= 0 && ww < 128) {
          int pp = h * 128 + ww;
          src = yb + (size_t)pp * 256 + ((c8 + (kg ^ (pp & 7))) << 3);
        }
        gload16(src, &lds[slot][(wave * 2 + j) * 512]);
      }
    }
  };

  f32x4 acc[8][4];
#pragma unroll
  for (int m = 0; m < 8; ++m)
#pragma unroll
    for (int n = 0; n < 4; ++n)
#pragma unroll
      for (int r = 0; r < 4; ++r) acc[m][n][r] = 0.f;

  bf8 areg[4][2];

  STAGE(0, 0, 0); STAGE(1, 2, 0); STAGE(2, 3, 0); STAGE(3, 1, 0);
  asm volatile("s_waitcnt vmcnt(0)" ::: "memory");

  for (int gg = 0; gg < 17; ++gg) {
    const int k0 = gg * 2;
    CONV_PHASE(k0, 0, 0, true, 0);
    CONV_PHASE(k0, 1, 0, true, 0);
    CONV_PHASE(k0, 2, 0, true, 0);
    CONV_PHASE(k0, 3, 0, true, 0);
    CONV_PHASE(k0 + 1, 0, 1, true, 0);
    CONV_PHASE(k0 + 1, 1, 1, true, 0);
    CONV_PHASE(k0 + 1, 2, 1, true, 0);
    CONV_PHASE(k0 + 1, 3, 1, true, 0);
  }
  CONV_PHASE(34, 0, 0, true, 0);
  CONV_PHASE(34, 1, 0, true, 0);
  CONV_PHASE(34, 2, 0, true, 0);
  CONV_PHASE(34, 3, 0, true, 0);
  CONV_PHASE(35, 0, 1, false, 1);
  CONV_PHASE(35, 1, 1, false, 2);
  CONV_PHASE(35, 2, 1, false, 2);
  CONV_PHASE(35, 3, 1, false, 2);

  __syncthreads();
  unsigned short* cb = co + (size_t)b * 256 * 16384;
  float* red1 = (float*)&lds[0][0];     // [8][128]
  float* red2 = red1 + 1024;
#pragma unroll
  for (int m = 0; m < 8; ++m) {
#pragma unroll
    for (int r = 0; r < 4; ++r) {
      int o = wm * 128 + m * 16 + lk * 4 + r;
      float bvv = bo[o];
      float s1 = 0.f, s2 = 0.f;
#pragma unroll
      for (int n = 0; n < 4; ++n) {
        int pix = wn * 64 + n * 16 + lr;
        int py = pix >> 4, px = pix & 15;
        float v = acc[m][n][r] + bvv;
        cb[(size_t)o * 16384 + (y0 + py) * 128 + x0 + px] = f2bf(v);
        s1 += v;
        s2 += v * v;
      }
      for (int off = 1; off < 16; off <<= 1) {
        s1 += __shfl_xor(s1, off, 64);
        s2 += __shfl_xor(s2, off, 64);
      }
      if (lr == 0) {
        int ol = m * 16 + lk * 4 + r;
        red1[wave * 128 + ol] = s1;
        red2[wave * 128 + ol] = s2;
      }
    }
  }
  __syncthreads();
  {
    int o = tid & 255, stat = tid >> 8;
    int wm2 = o >> 7, ol = o & 127;
    const float* rd = stat ? red2 : red1;
    float s = rd[(wm2 * 4 + 0) * 128 + ol] + rd[(wm2 * 4 + 1) * 128 + ol] +
              rd[(wm2 * 4 + 2) * 128 + ol] + rd[(wm2 * 4 + 3) * 128 + ol];
    bnp[((size_t)(b * 64 + tile) * 256 + o) * 2 + stat] = s;
  }
}

// ---------------- BN reduce + apply ----------------
__global__ __launch_bounds__(256) void k_bnred(
    const float* __restrict__ bnp, const float* __restrict__ gamma,
    const float* __restrict__ beta, float* __restrict__ bns) {
  const int o = blockIdx.x;
  const int tid = threadIdx.x;
  float s1 = 0.f, s2 = 0.f;
  for (int k = tid; k < 512; k += 256) {
    s1 += bnp[((size_t)k * 256 + o) * 2 + 0];
    s2 += bnp[((size_t)k * 256 + o) * 2 + 1];
  }
  __shared__ float r1[256], r2[256];
  r1[tid] = s1; r2[tid] = s2;
  __syncthreads();
  for (int off = 128; off > 0; off >>= 1) {
    if (tid < off) { r1[tid] += r1[tid + off]; r2[tid] += r2[tid + off]; }
    __syncthreads();
  }
  if (tid == 0) {
    const float cnt = 8.0f * 16384.0f;
    float mean = r1[0] / cnt;
    float var = r2[0] / cnt - mean * mean;
    float sc = gamma[o] * rsqrtf(var + 1e-5f);
    bns[o] = sc;
    bns[256 + o] = beta[o] - mean * sc;
  }
}

__global__ void k_bnapply(const unsigned short* __restrict__ co, float* __restrict__ out,
                          const float* __restrict__ bns) {
  size_t i = ((size_t)blockIdx.x * 256 + threadIdx.x) * 8;
  const size_t total = 33554432;
  const size_t stride = (size_t)gridDim.x * 256 * 8;
  for (; i < total; i += stride) {
    uint4 v = *(const uint4*)(co + i);
    int o = (int)((i >> 14) & 255);
    float sc = bns[o], shv = bns[256 + o];
    const unsigned short* pv = (const unsigned short*)&v;
    float r[8];
#pragma unroll
    for (int e = 0; e < 8; ++e) {
      float f = bf2f(pv[e]) * sc + shv;
      r[e] = f > 0.f ? f : 0.2f * f;
    }
    *(float4*)(out + i) = *(const float4*)&r[0];
    *(float4*)(out + i + 4) = *(const float4*)&r[4];
  }
}

// ---------------- launcher ----------------
extern "C" void kernel_launch(void* const* d_in, const int* in_sizes, int n_in,
                              void* d_out, int out_size, void* d_ws, size_t ws_size,
                              hipStream_t stream) {
  if (ws_size < WS_NEED) return;

  const float* x     = (const float*)d_in[0];
  const float* wq    = (const float*)d_in[1];
  const float* bq    = (const float*)d_in[2];
  const float* wk    = (const float*)d_in[3];
  const float* bk    = (const float*)d_in[4];
  const float* wv    = (const float*)d_in[5];
  const float* bv    = (const float*)d_in[6];
  const float* wo    = (const float*)d_in[7];
  const float* bo    = (const float*)d_in[8];
  const float* gamma = (const float*)d_in[9];
  const float* beta  = (const float*)d_in[10];
  float* out = (float*)d_out;
  char* ws = (char*)d_ws;

  unsigned short* Wb  = (unsigned short*)(ws + WB_OFF);
  unsigned short* Wob = (unsigned short*)(ws + WOB_OFF);
  unsigned short* Qn  = (unsigned short*)(ws + QN_OFF);
  unsigned short* Kn  = (unsigned short*)(ws + KN_OFF);
  unsigned short* Vn  = (unsigned short*)(ws + VN_OFF);
  unsigned short* Yn  = (unsigned short*)(ws + YN_OFF);
  float* part3 = (float*)(ws + YN_OFF);          // overlay: used before Yn is written
  unsigned short* co = (unsigned short*)(ws + QN_OFF);  // overlay: Qn dead after grams
  float* scores = (float*)(ws + SC_OFF);
  unsigned short* prb = (unsigned short*)(ws + PRB_OFF);
  float* bnp    = (float*)(ws + BNP_OFF);
  float* bns    = (float*)(ws + BNS_OFF);
  unsigned short* zp = (unsigned short*)(ws + ZP_OFF);

  k_prep<<<dim3(3072), dim3(256), 0, stream>>>(wq, wk, wv, wo, Wb, Wob, scores, (float*)zp);
  k_qkv<<<dim3(256, 8), dim3(256), 0, stream>>>(x, Wb, bq, bk, bv, Qn, Kn, Vn);
  k_gramA<<<dim3(128, 8), dim3(256), 0, stream>>>(Qn, Kn, scores, part3);
  k_smA<<<dim3(11, 8), dim3(256), 0, stream>>>(scores, part3, prb);
  k_pvA<<<dim3(320, 8), dim3(256), 0, stream>>>(Vn, prb, Yn);
  k_conv<<<dim3(512), dim3(512), 0, stream>>>(Yn, Wob, bo, zp, co, bnp);
  k_bnred<<<dim3(256), dim3(256), 0, stream>>>(bnp, gamma, beta, bns);
  k_bnapply<<<dim3(4096), dim3(256), 0, stream>>>(co, out, bns);
}

// Round 13
// 544.554 us; speedup vs baseline: 1.3395x; 1.0012x over previous
//
#include <hip/hip_runtime.h>
#include <stdint.h>

// ---------------- geometry ----------------
// B=8, C=256, H=W=128, HW=16384, 4 heads of d_k=64
// idx: HS=WS=2<<idx, S=HS*HS, OH=OW=64>>idx, NSP=OH*OW
// gather:  q[s=(i,j)][d=(c,ohi,owi)] = Q[lo+c][ohi*HS+i][owi*WS+j], s=i*WS+j
// scatter: Y[lo+c][i*OH+ohi][j*OW+owi] = y[s][d]   (transposed vs gather!)
// NHWC buffers (Qn,Kn,Vn,Yn): element (p, c) at [p*256 + (c ^ ((p&7)<<3))]
// granule rule: 8-ch granule g of pixel p sits at granule slot (g ^ (p&7)).

#define DEVI static __device__ __forceinline__

typedef short bf8 __attribute__((ext_vector_type(8)));   // 8 bf16 (4 VGPRs)
typedef float f32x4 __attribute__((ext_vector_type(4)));

DEVI unsigned short f2bf(float f) {
  unsigned u = __builtin_bit_cast(unsigned, f);
  u = (u + 0x7fffu + ((u >> 16) & 1u)) >> 16;
  return (unsigned short)u;
}
DEVI float bf2f(unsigned short h) {
  unsigned u = ((unsigned)h) << 16;
  return __builtin_bit_cast(float, u);
}

DEVI void gload16(const void* g, void* l) {
  __builtin_amdgcn_global_load_lds(
      (const __attribute__((address_space(1))) unsigned int*)g,
      (__attribute__((address_space(3))) unsigned int*)l, 16, 0, 0);
}

// ---------------- ws layout (bytes) ----------------
static const size_t WB_OFF  = 0;                        // bf16 [3][256][256]
static const size_t WOB_OFF = 393216;                   // bf16 [256][2304] k=(e*256+c)
static const size_t QN_OFF  = 1572864;                  // bf16 NHWC-swz [8][16384][256]; co overlay after grams
static const size_t KN_OFF  = QN_OFF + 67108864;
static const size_t VN_OFF  = KN_OFF + 67108864;
static const size_t YN_OFF  = VN_OFF + 67108864;        // bf16 NHWC-swz (also part3 overlay)
static const size_t SC_OFF  = YN_OFF + 67108864;        // f32 scores idx0-2 (34944 floats used)
static const size_t PRB_OFF = SC_OFF + 2236928;         // bf16 probs (559232)
static const size_t BNP_OFF = PRB_OFF + 1118464;        // f32 [512][256][2]
static const size_t BNS_OFF = BNP_OFF + 4194304;        // f32 [2][256]
static const size_t ZP_OFF  = BNS_OFF + 2048;           // 256B zero page for OOB gloads
static const size_t WS_NEED = ZP_OFF + 256;

// ---------------- prep: weights -> bf16 (wo reordered) + zero scores/zp ----------------
__global__ void k_prep(const float* __restrict__ wq, const float* __restrict__ wk,
                       const float* __restrict__ wv, const float* __restrict__ wo,
                       unsigned short* __restrict__ Wb, unsigned short* __restrict__ Wob,
                       float* __restrict__ sc0, float* __restrict__ zp0) {
  int i = blockIdx.x * 256 + threadIdx.x;        // grid covers 786432 exactly
  if (i < 34944) sc0[i] = 0.f;
  else if (i < 35008) zp0[i - 34944] = 0.f;
  if (i < 196608) {
    int z = i >> 16, r = i & 65535;
    const float* w = (z == 0) ? wq : (z == 1) ? wk : wv;
    Wb[i] = f2bf(w[r]);
  } else {
    int j = i - 196608;
    int o = j / 2304, k = j - o * 2304;
    int e = k >> 8, c = k & 255;
    Wob[j] = f2bf(wo[(o * 256 + c) * 9 + e]);    // Wob[o][e*256+c] = wo[o][c][e]
  }
}

// ---------------- fused QKV projection (48KB LDS, 3 blk/CU) ----------------
// staging: lane = pixel, wave-strided c-quads; loads batch-prefetched (16 in
// flight) before convert+ds_write; 3 blocks/CU kept (VGPR cap 170).
__global__ __launch_bounds__(256, 3) void k_qkv(
    const float* __restrict__ x, const unsigned short* __restrict__ Wb,
    const float* __restrict__ bq, const float* __restrict__ bk, const float* __restrict__ bv,
    unsigned short* __restrict__ Qn, unsigned short* __restrict__ Kn,
    unsigned short* __restrict__ Vn) {
  const int pt = blockIdx.x, b = blockIdx.y;
  const int p0 = pt * 64;
  const int tid = threadIdx.x;

  __shared__ __align__(16) unsigned short xt[64 * 256];  // input tile [p][c'] swizzled 32KB
  __shared__ __align__(16) unsigned short ot[32 * 256];  // output chunk buffer 16KB

  const int wave = tid >> 6, lane = tid & 63;

  {
    const float* xb = x + (size_t)b * 256 * 16384 + p0;
    const int xsw = (lane & 7) << 3;
    float reg[16];
#pragma unroll
    for (int q = 0; q < 4; ++q) {
#pragma unroll
      for (int it = 0; it < 4; ++it) {
        int c4 = ((q * 4 + it) * 4 + wave) * 4;
#pragma unroll
        for (int j = 0; j < 4; ++j)
          reg[it * 4 + j] = xb[(size_t)(c4 + j) * 16384 + lane];
      }
#pragma unroll
      for (int it = 0; it < 4; ++it) {
        int c4 = ((q * 4 + it) * 4 + wave) * 4;
        unsigned short tmp[4];
#pragma unroll
        for (int j = 0; j < 4; ++j) tmp[j] = f2bf(reg[it * 4 + j]);
        *(ushort4*)(&xt[lane * 256 + (c4 ^ xsw)]) = *(const ushort4*)tmp;
      }
    }
  }
  __syncthreads();

  const int lr = lane & 15, lk = lane >> 4;
  const int obase = wave * 64;

  for (int z = 0; z < 3; ++z) {
    const unsigned short* Wz = Wb + (size_t)z * 65536;
    f32x4 acc[4][4];
    for (int m = 0; m < 4; ++m)
      for (int n = 0; n < 4; ++n)
        for (int r = 0; r < 4; ++r) acc[m][n][r] = 0.f;

#pragma unroll 2
    for (int ks = 0; ks < 8; ++ks) {
      int c0 = ks * 32 + lk * 8;
      bf8 a[4], bb[4];
#pragma unroll
      for (int m = 0; m < 4; ++m)
        a[m] = *(const bf8*)(Wz + (size_t)(obase + m * 16 + lr) * 256 + c0);
#pragma unroll
      for (int n = 0; n < 4; ++n) {
        int p = n * 16 + lr;
        bb[n] = *(const bf8*)(&xt[p * 256 + (c0 ^ ((p & 7) << 3))]);
      }
      __builtin_amdgcn_s_setprio(1);
#pragma unroll
      for (int m = 0; m < 4; ++m)
#pragma unroll
        for (int n = 0; n < 4; ++n)
          acc[m][n] = __builtin_amdgcn_mfma_f32_16x16x32_bf16(a[m], bb[n], acc[m][n], 0, 0, 0);
      __builtin_amdgcn_s_setprio(0);
    }

    const float* bias = (z == 0) ? bq : (z == 1) ? bk : bv;
    unsigned short* On = (z == 0) ? Qn : (z == 1) ? Kn : Vn;
    // epilogue in two 32-px chunks through the 16KB ot buffer
    for (int h = 0; h < 2; ++h) {
      __syncthreads();   // prior ot consumers done
#pragma unroll
      for (int m = 0; m < 4; ++m) {
        int ob4 = obase + m * 16 + lk * 4;
        float4 b4 = *(const float4*)(bias + ob4);
#pragma unroll
        for (int nn = 0; nn < 2; ++nn) {
          int n = h * 2 + nn;
          int pch = nn * 16 + lr;            // chunk-local pixel 0..31
          ushort4 v4;
          v4.x = f2bf(acc[m][n][0] + b4.x);
          v4.y = f2bf(acc[m][n][1] + b4.y);
          v4.z = f2bf(acc[m][n][2] + b4.z);
          v4.w = f2bf(acc[m][n][3] + b4.w);
          *(ushort4*)(&ot[pch * 256 + (ob4 ^ ((pch & 7) << 3))]) = v4;
        }
      }
      __syncthreads();
      unsigned short* gb = On + ((size_t)b * 16384 + p0 + h * 32) * 256;
#pragma unroll
      for (int i = 0; i < 4; ++i) {
        int ch = tid + i * 256;              // 1024 cells x 16B = 16KB
        *(uint4*)(gb + ch * 8) = *(const uint4*)(&ot[ch * 8]);
      }
    }
  }
}

// ---------------- Gram bodies (merged dispatch) ----------------
template <int IDX>
DEVI void gram_body(int chk, int b,
                    const unsigned short* __restrict__ Qn,
                    const unsigned short* __restrict__ Kn,
                    float* __restrict__ scores, char* smem) {
  constexpr int HS = 2 << IDX, S = HS * HS, OH = 64 >> IDX, NSP = OH * OH;
  constexpr int SPW = (IDX == 2) ? 2 : 8;
  constexpr int DSUB = SPW * 64;
  constexpr int SPB = NSP / 32;
  constexpr int STEPS = SPB / SPW;
  constexpr int ROWS = S;
  constexpr int TPT = S * SPW * 8 / 256;
  constexpr int SCOFF = (IDX == 0) ? 0 : (IDX == 1) ? 128 : 2176;
  constexpr int HC = IDX * 64;
  constexpr int MT = (IDX == 2) ? 4 : 1;

  unsigned short* qg = (unsigned short*)smem;                       // ROWS*DSUB
  unsigned short* kg = (unsigned short*)(smem + ROWS * DSUB * 2);
  float* red = (float*)(smem + ROWS * DSUB * 4);                    // S*S floats

  const int tid = threadIdx.x;
  const int wave = tid >> 6, lane = tid & 63, lr = lane & 15, lk = lane >> 4;
  const size_t base = (size_t)b * 16384 * 256;

  f32x4 acc[MT][MT];
  for (int m = 0; m < MT; ++m)
    for (int n = 0; n < MT; ++n)
      for (int r = 0; r < 4; ++r) acc[m][n][r] = 0.f;

  for (int st = 0; st < STEPS; ++st) {
    const int sp0 = chk * SPB + st * SPW;
    __syncthreads();
#pragma unroll
    for (int r = 0; r < TPT; ++r) {
      int task = tid + r * 256;
      int cg = task & 7, pl = task >> 3;
      int spl = pl >> (2 * (IDX + 1)), s = pl & (S - 1);
      int sp = sp0 + spl;
      int ohi = sp >> (6 - IDX), owi = sp & (OH - 1);
      int ii = s >> (IDX + 1), jj = s & (HS - 1);
      int p = (ohi * HS + ii) * 128 + owi * HS + jj;
      size_t gaddr = base + (size_t)p * 256 + HC + ((cg ^ (p & 7)) << 3);
      int laddr = s * DSUB + (((spl * 8 + cg) ^ (s & 7)) << 3);
      *(uint4*)(qg + laddr) = *(const uint4*)(Qn + gaddr);
      *(uint4*)(kg + laddr) = *(const uint4*)(Kn + gaddr);
    }
    __syncthreads();
    if (IDX == 2) {
      int kgid = wave * 4 + lk;
      bf8 a[4], bb[4];
#pragma unroll
      for (int m = 0; m < 4; ++m) {
        int row = m * 16 + lr;
        int off = row * DSUB + ((kgid ^ (row & 7)) << 3);
        a[m] = *(const bf8*)(qg + off);
        bb[m] = *(const bf8*)(kg + off);
      }
#pragma unroll
      for (int m = 0; m < MT; ++m)
#pragma unroll
        for (int n = 0; n < MT; ++n)
          acc[m][n] = __builtin_amdgcn_mfma_f32_16x16x32_bf16(a[m], bb[n], acc[m][n], 0, 0, 0);
    } else {
      int row = lr & (ROWS - 1);
#pragma unroll
      for (int kk = 0; kk < 4; ++kk) {
        int kgid = (wave * 4 + kk) * 4 + lk;
        int off = row * DSUB + ((kgid ^ (row & 7)) << 3);
        bf8 a = *(const bf8*)(qg + off);
        bf8 bb = *(const bf8*)(kg + off);
        acc[0][0] = __builtin_amdgcn_mfma_f32_16x16x32_bf16(a, bb, acc[0][0], 0, 0, 0);
      }
    }
  }

  __syncthreads();
  for (int i2 = tid; i2 < S * S; i2 += 256) red[i2] = 0.f;
  __syncthreads();
  if (IDX == 2) {
#pragma unroll
    for (int m = 0; m < MT; ++m)
#pragma unroll
      for (int n = 0; n < MT; ++n)
#pragma unroll
        for (int r = 0; r < 4; ++r)
          atomicAdd(&red[(m * 16 + lk * 4 + r) * 64 + n * 16 + lr], acc[m][n][r]);
  } else if (IDX == 1) {
#pragma unroll
    for (int r = 0; r < 4; ++r)
      atomicAdd(&red[(lk * 4 + r) * 16 + lr], acc[0][0][r]);
  } else {
    if (lk == 0 && lr < 4) {
#pragma unroll
      for (int r = 0; r < 4; ++r)
        atomicAdd(&red[r * 4 + lr], acc[0][0][r]);
    }
  }
  __syncthreads();
  float* sc = scores + SCOFF + (size_t)b * S * S;
  for (int i2 = tid; i2 < S * S; i2 += 256) atomicAdd(sc + i2, red[i2]);
}

DEVI void gram3_body(int qc, int tq, int b,
                     const unsigned short* __restrict__ Qn,
                     const unsigned short* __restrict__ Kn,
                     float* __restrict__ part3, char* smem) {
  unsigned short* qg = (unsigned short*)smem;            // 256*64 = 32KB
  unsigned short* kg = (unsigned short*)(smem + 32768);  // 64*64  = 8KB

  const int tid = threadIdx.x;
  const int wave = tid >> 6, lane = tid & 63, lr = lane & 15, lk = lane >> 4;
  const size_t base = (size_t)b * 16384 * 256;

  f32x4 acc[4][4];
  for (int m = 0; m < 4; ++m)
    for (int n = 0; n < 4; ++n)
      for (int r = 0; r < 4; ++r) acc[m][n][r] = 0.f;

  for (int st = 0; st < 8; ++st) {
    int sp = qc * 8 + st;
    int ohi = sp >> 3, owi = sp & 7;
    __syncthreads();
#pragma unroll
    for (int r = 0; r < 8; ++r) {
      int task = tid + r * 256;
      int cg = task & 7, s = task >> 3;
      int p = (ohi * 16 + (s >> 4)) * 128 + owi * 16 + (s & 15);
      uint4 v = *(const uint4*)(Qn + base + (size_t)p * 256 + 192 + ((cg ^ (p & 7)) << 3));
      *(uint4*)(qg + s * 64 + ((cg ^ (s & 7)) << 3)) = v;
    }
#pragma unroll
    for (int r = 0; r < 2; ++r) {
      int task = tid + r * 256;
      int cg = task & 7, tl = task >> 3;
      int p = (ohi * 16 + tq * 4 + (tl >> 4)) * 128 + owi * 16 + (tl & 15);
      uint4 v = *(const uint4*)(Kn + base + (size_t)p * 256 + 192 + ((cg ^ (p & 7)) << 3));
      *(uint4*)(kg + tl * 64 + ((cg ^ (tl & 7)) << 3)) = v;
    }
    __syncthreads();
#pragma unroll
    for (int kk = 0; kk < 2; ++kk) {
      int kgid = kk * 4 + lk;
      bf8 a[4], bb[4];
#pragma unroll
      for (int m = 0; m < 4; ++m) {
        int row = wave * 64 + m * 16 + lr;
        a[m] = *(const bf8*)(qg + row * 64 + ((kgid ^ (row & 7)) << 3));
      }
#pragma unroll
      for (int n = 0; n < 4; ++n) {
        int rowb = n * 16 + lr;
        bb[n] = *(const bf8*)(kg + rowb * 64 + ((kgid ^ (rowb & 7)) << 3));
      }
#pragma unroll
      for (int m = 0; m < 4; ++m)
#pragma unroll
        for (int n = 0; n < 4; ++n)
          acc[m][n] = __builtin_amdgcn_mfma_f32_16x16x32_bf16(a[m], bb[n], acc[m][n], 0, 0, 0);
    }
  }

  float* pb = part3 + (((size_t)qc * 8 + b) * 65536);
#pragma unroll
  for (int m = 0; m < 4; ++m)
#pragma unroll
    for (int r = 0; r < 4; ++r) {
      int srow = wave * 64 + m * 16 + lk * 4 + r;
#pragma unroll
      for (int n = 0; n < 4; ++n)
        pb[srow * 256 + tq * 64 + n * 16 + lr] = acc[m][n][r];
    }
}

// merged gram dispatch: grid (128, 8)
__global__ __launch_bounds__(256) void k_gramA(
    const unsigned short* __restrict__ Qn, const unsigned short* __restrict__ Kn,
    float* __restrict__ scores, float* __restrict__ part3) {
  __shared__ __align__(16) char smem[49152];
  const int bx = blockIdx.x, b = blockIdx.y;
  if (bx < 32)       gram_body<0>(bx, b, Qn, Kn, scores, smem);
  else if (bx < 64)  gram_body<1>(bx - 32, b, Qn, Kn, scores, smem);
  else if (bx < 96)  gram_body<2>(bx - 64, b, Qn, Kn, scores, smem);
  else               gram3_body((bx - 96) & 7, (bx - 96) >> 3, b, Qn, Kn, part3, smem);
}

// ---------------- softmax bodies (merged) ----------------
DEVI void softmax_body(int idx, int b, const float* __restrict__ scores,
                       unsigned short* __restrict__ prb) {
  const int S = 4 << (2 * idx);
  const int off = (idx == 0 ? 0 : idx == 1 ? 128 : 2176) + b * S * S;
  const int s = threadIdx.x;
  if (s >= S) return;
  const float scale = rsqrtf(64.0f * (float)(4096 >> (2 * idx)));
  const float* row = scores + off + s * S;
  float m = -1e30f;
  for (int t = 0; t < S; ++t) m = fmaxf(m, row[t]);
  m *= scale;
  float sum = 0.f;
  for (int t = 0; t < S; ++t) sum += __expf(row[t] * scale - m);
  float inv = 1.0f / sum;
  unsigned short* prow = prb + off + s * S;
  for (int t = 0; t < S; ++t) prow[t] = f2bf(__expf(row[t] * scale - m) * inv);
}

DEVI void softmax3_body(int sc_, int b, const float* __restrict__ part3,
                        unsigned short* __restrict__ prb) {
  const int tid = threadIdx.x;
  const int s = sc_ * 32 + (tid >> 3);
  const int t0 = (tid & 7) * 32;
  float v[32];
#pragma unroll
  for (int k = 0; k < 32; ++k) v[k] = 0.f;
  for (int q = 0; q < 8; ++q) {
    const float4* pp = (const float4*)(part3 + (((size_t)q * 8 + b) * 256 + s) * 256 + t0);
#pragma unroll
    for (int k = 0; k < 8; ++k) {
      float4 u = pp[k];
      v[k * 4 + 0] += u.x; v[k * 4 + 1] += u.y; v[k * 4 + 2] += u.z; v[k * 4 + 3] += u.w;
    }
  }
  const float scale = 1.0f / 64.0f;
  float m = -1e30f;
#pragma unroll
  for (int k = 0; k < 32; ++k) { v[k] *= scale; m = fmaxf(m, v[k]); }
  m = fmaxf(m, __shfl_xor(m, 1));
  m = fmaxf(m, __shfl_xor(m, 2));
  m = fmaxf(m, __shfl_xor(m, 4));
  float sum = 0.f;
#pragma unroll
  for (int k = 0; k < 32; ++k) { v[k] = __expf(v[k] - m); sum += v[k]; }
  sum += __shfl_xor(sum, 1);
  sum += __shfl_xor(sum, 2);
  sum += __shfl_xor(sum, 4);
  float inv = 1.0f / sum;
  unsigned short* prw = prb + 34944 + (size_t)b * 65536 + s * 256 + t0;
#pragma unroll
  for (int k8 = 0; k8 < 4; ++k8) {
    unsigned short tmp[8];
#pragma unroll
    for (int e = 0; e < 8; ++e) tmp[e] = f2bf(v[k8 * 8 + e] * inv);
    *(uint4*)(prw + k8 * 8) = *(const uint4*)tmp;
  }
}

// merged softmax dispatch: grid (11, 8)
__global__ __launch_bounds__(256) void k_smA(const float* __restrict__ scores,
                                             const float* __restrict__ part3,
                                             unsigned short* __restrict__ prb) {
  const int bx = blockIdx.x, b = blockIdx.y;
  if (bx < 3) softmax_body(bx, b, scores, prb);
  else        softmax3_body(bx - 3, b, part3, prb);
}

// ---------------- PV bodies (merged) ----------------
template <int IDX>
DEVI void pv_body(int bx, int b, const unsigned short* __restrict__ Vn,
                  const unsigned short* __restrict__ prb,
                  unsigned short* __restrict__ Yn, char* smem) {
  constexpr int HS = 2 << IDX, S = HS * HS, OH = 64 >> IDX;
  constexpr int IT = (IDX == 0) ? 8 : (IDX == 1) ? 4 : 1;
  constexpr int POFF = (IDX == 0) ? 0 : (IDX == 1) ? 128 : 2176;
  float* pl = (float*)smem;                          // S*S floats (<=16KB)
  const int c = threadIdx.x & 63, spg = threadIdx.x >> 6;
  const unsigned short* pr = prb + POFF + (size_t)b * S * S;
  for (int i = threadIdx.x; i < S * S; i += 256) pl[i] = bf2f(pr[i]);
  __syncthreads();
  const int hc = IDX * 64;
  const unsigned short* vb = Vn + (size_t)b * 16384 * 256;
  unsigned short* yb = Yn + (size_t)b * 16384 * 256;
  for (int it = 0; it < IT; ++it) {
    int sp = bx * (4 * IT) + it * 4 + spg;
    int ohi = sp >> (6 - IDX), owi = sp & (OH - 1);
    float v[S];
#pragma unroll
    for (int t = 0; t < S; ++t) {
      int po = (ohi * HS + t / HS) * 128 + owi * HS + (t % HS);
      v[t] = bf2f(vb[(size_t)po * 256 + ((hc + c) ^ ((po & 7) << 3))]);
    }
    for (int s = 0; s < S; ++s) {
      const float4* p4 = (const float4*)(pl + s * S);
      float a = 0.f;
#pragma unroll
      for (int t4 = 0; t4 < S / 4; ++t4) {
        float4 pp = p4[t4];
        a += pp.x * v[t4 * 4] + pp.y * v[t4 * 4 + 1] + pp.z * v[t4 * 4 + 2] + pp.w * v[t4 * 4 + 3];
      }
      int po = ((s >> (IDX + 1)) * OH + ohi) * 128 + (s & (HS - 1)) * OH + owi;
      yb[(size_t)po * 256 + ((hc + c) ^ ((po & 7) << 3))] = f2bf(a);
    }
  }
}

DEVI void pv3_body(int sp, int b, const unsigned short* __restrict__ Vn,
                   const unsigned short* __restrict__ prb,
                   unsigned short* __restrict__ Yn, char* smem) {
  unsigned short* vl = (unsigned short*)smem;        // 64*256 = 32KB
  const int ohi = sp >> 3, owi = sp & 7;
  const int tid = threadIdx.x;
  const unsigned short* vb = Vn + (size_t)b * 16384 * 256;
  {
    int t = tid;
    int po = (ohi * 16 + (t >> 4)) * 128 + owi * 16 + (t & 15);
    const unsigned short* src = vb + (size_t)po * 256;
    int xv = (po & 7) << 3;
#pragma unroll
    for (int g = 0; g < 8; ++g) {
      ushort4 lo = *(const ushort4*)(src + ((192 + g * 8) ^ xv));
      ushort4 hi = *(const ushort4*)(src + ((192 + g * 8) ^ xv) + 4);
      unsigned short vv[8] = {lo.x, lo.y, lo.z, lo.w, hi.x, hi.y, hi.z, hi.w};
#pragma unroll
      for (int e = 0; e < 8; ++e) {
        int cc = g * 8 + e;
        vl[cc * 256 + (t ^ ((cc & 7) << 3))] = vv[e];
      }
    }
  }
  __syncthreads();

  const int wave = tid >> 6, lane = tid & 63;
  const int lr = lane & 15, lk = lane >> 4;
  const int sb = wave * 64;
  const unsigned short* pr = prb + 34944 + (size_t)b * 65536;

  f32x4 acc[4][4];
  for (int m = 0; m < 4; ++m)
    for (int n = 0; n < 4; ++n)
      for (int r = 0; r < 4; ++r) acc[m][n][r] = 0.f;

  for (int kk = 0; kk < 8; ++kk) {
    int t0 = kk * 32 + lk * 8;
    bf8 a[4], bb[4];
#pragma unroll
    for (int m = 0; m < 4; ++m)
      a[m] = *(const bf8*)(pr + (size_t)(sb + m * 16 + lr) * 256 + t0);
#pragma unroll
    for (int n = 0; n < 4; ++n) {
      int cc = n * 16 + lr;
      bb[n] = *(const bf8*)(&vl[cc * 256 + (t0 ^ ((cc & 7) << 3))]);
    }
#pragma unroll
    for (int m = 0; m < 4; ++m)
#pragma unroll
      for (int n = 0; n < 4; ++n)
        acc[m][n] = __builtin_amdgcn_mfma_f32_16x16x32_bf16(a[m], bb[n], acc[m][n], 0, 0, 0);
  }

  unsigned short* yb = Yn + (size_t)b * 16384 * 256;
#pragma unroll
  for (int m = 0; m < 4; ++m) {
#pragma unroll
    for (int r = 0; r < 4; ++r) {
      int s = sb + m * 16 + lk * 4 + r;
      int si = s >> 4, sj = s & 15;
      int po = (si * 8 + ohi) * 128 + sj * 8 + owi;
#pragma unroll
      for (int n = 0; n < 4; ++n) {
        int cc = 192 + n * 16 + lr;
        yb[(size_t)po * 256 + (cc ^ (owi << 3))] = f2bf(acc[m][n][r]);
      }
    }
  }
}

// merged PV dispatch: grid (320, 8)
__global__ __launch_bounds__(256) void k_pvA(
    const unsigned short* __restrict__ Vn, const unsigned short* __restrict__ prb,
    unsigned short* __restrict__ Yn) {
  __shared__ __align__(16) char smem[32768];
  const int bx = blockIdx.x, b = blockIdx.y;
  if (bx < 128)      pv_body<0>(bx, b, Vn, prb, Yn, smem);
  else if (bx < 192) pv_body<1>(bx - 128, b, Vn, prb, Yn, smem);
  else if (bx < 256) pv_body<2>(bx - 192, b, Vn, prb, Yn, smem);
  else               pv3_body(bx - 256, b, Vn, prb, Yn, smem);
}

// ---------------- 3x3 conv: 256x256x2304 GEMM, 8-slot ring (known-good) ----------------
#define CONV_PHASE(KT_, R_, PK_, DOSTAGE_, WAITMODE_)                            \
  do {                                                                           \
    if (DOSTAGE_) {                                                              \
      constexpr int type_ = (R_ == 0) ? 0 : (R_ == 1) ? 2 : (R_ == 2) ? 3 : 1;   \
      STAGE((1 - (PK_)) * 4 + (R_), type_, (KT_) + 1);                           \
    }                                                                            \
    if ((WAITMODE_) == 0) { asm volatile("s_waitcnt vmcnt(6)" ::: "memory"); }   \
    else if ((WAITMODE_) == 1) { asm volatile("s_waitcnt vmcnt(0)" ::: "memory"); } \
    __builtin_amdgcn_s_barrier();                                                \
    asm volatile("" ::: "memory");                                               \
    {                                                                            \
      constexpr int mh_ = (R_) >> 1, nh_ = (R_) & 1;                             \
      constexpr int sA_ = (PK_) * 4 + (mh_ ? 3 : 0);                             \
      constexpr int sB_ = (PK_) * 4 + (nh_ ? 2 : 1);                             \
      if (nh_ == 0) {                                                            \
        _Pragma("unroll") for (int m2 = 0; m2 < 4; ++m2) {                       \
          int row = wm * 64 + m2 * 16 + lr;                                      \
          _Pragma("unroll") for (int kk = 0; kk < 2; ++kk)                       \
            areg[m2][kk] = *(const bf8*)(&lds[sA_][row * 64 +                    \
                (((kk * 4 + lk) ^ (row & 7)) << 3)]);                            \
        }                                                                        \
      }                                                                          \
      bf8 breg[2][2];                                                            \
      _Pragma("unroll") for (int n2 = 0; n2 < 2; ++n2) {                         \
        int row = wn * 32 + n2 * 16 + lr;                                        \
        _Pragma("unroll") for (int kk = 0; kk < 2; ++kk)                         \
          breg[n2][kk] = *(const bf8*)(&lds[sB_][row * 64 +                      \
              (((kk * 4 + lk) ^ (row & 7)) << 3)]);                              \
      }                                                                          \
      __builtin_amdgcn_s_setprio(1);                                             \
      _Pragma("unroll") for (int kk = 0; kk < 2; ++kk)                           \
        _Pragma("unroll") for (int m2 = 0; m2 < 4; ++m2)                         \
          _Pragma("unroll") for (int n2 = 0; n2 < 2; ++n2)                       \
            acc[mh_ * 4 + m2][nh_ * 2 + n2] =                                    \
                __builtin_amdgcn_mfma_f32_16x16x32_bf16(                         \
                    areg[m2][kk], breg[n2][kk],                                  \
                    acc[mh_ * 4 + m2][nh_ * 2 + n2], 0, 0, 0);                   \
      __builtin_amdgcn_s_setprio(0);                                             \
      asm volatile("" ::: "memory");                                             \
    }                                                                            \
  } while (0)

__global__ __launch_bounds__(512, 2) void k_conv(
    const unsigned short* __restrict__ Yn, const unsigned short* __restrict__ Wob,
    const float* __restrict__ bo, const unsigned short* __restrict__ zp,
    unsigned short* __restrict__ co, float* __restrict__ bnp) {
  __shared__ __align__(16) unsigned short lds[8][8192];  // 8 x 16KB half-tile slots

  const int bid = blockIdx.x;
  const int swz = (bid & 7) * 64 + (bid >> 3);   // XCD-chunked, bijective (512=8*64)
  const int b = swz >> 6, tile = swz & 63;
  const int y0 = (tile >> 3) * 16, x0 = (tile & 7) * 16;
  const int tid = threadIdx.x;
  const int wave = tid >> 6, lane = tid & 63;
  const int lr = lane & 15, lk = lane >> 4;
  const int wm = wave >> 2, wn = wave & 3;
  const int cg = lane & 7;

  const unsigned short* yb = Yn + (size_t)b * 16384 * 256;

  auto STAGE = [&](int slot, int type, int KT) {
    if (type < 2) {
      const unsigned short* wsrc = Wob + (KT >> 2) * 256 + (KT & 3) * 64;
#pragma unroll
      for (int j = 0; j < 2; ++j) {
        int rp = (wave * 2 + j) * 8 + (lane >> 3);   // LDS row 0..127
        int o = ((rp >> 6) & 1) * 128 + type * 64 + (rp & 63);
        int kg = cg ^ (rp & 7);
        gload16(wsrc + o * 2304 + (kg << 3), &lds[slot][(wave * 2 + j) * 512]);
      }
    } else {
      int e = KT >> 2;
      int dy = e / 3 - 1, dx = e % 3 - 1, c8 = (KT & 3) * 8;
#pragma unroll
      for (int j = 0; j < 2; ++j) {
        int rp = (wave * 2 + j) * 8 + (lane >> 3);
        int n = ((rp >> 5) & 3) * 64 + (type - 2) * 32 + (rp & 31);
        int kg = cg ^ (rp & 7);
        int h = y0 + (n >> 4) + dy, ww = x0 + (n & 15) + dx;
        const unsigned short* src = zp;
        if (h >= 0 && h < 128 && ww >= 0 && ww < 128) {
          int pp = h * 128 + ww;
          src = yb + (size_t)pp * 256 + ((c8 + (kg ^ (pp & 7))) << 3);
        }
        gload16(src, &lds[slot][(wave * 2 + j) * 512]);
      }
    }
  };

  f32x4 acc[8][4];
#pragma unroll
  for (int m = 0; m < 8; ++m)
#pragma unroll
    for (int n = 0; n < 4; ++n)
#pragma unroll
      for (int r = 0; r < 4; ++r) acc[m][n][r] = 0.f;

  bf8 areg[4][2];

  STAGE(0, 0, 0); STAGE(1, 2, 0); STAGE(2, 3, 0); STAGE(3, 1, 0);
  asm volatile("s_waitcnt vmcnt(0)" ::: "memory");

  for (int gg = 0; gg < 17; ++gg) {
    const int k0 = gg * 2;
    CONV_PHASE(k0, 0, 0, true, 0);
    CONV_PHASE(k0, 1, 0, true, 0);
    CONV_PHASE(k0, 2, 0, true, 0);
    CONV_PHASE(k0, 3, 0, true, 0);
    CONV_PHASE(k0 + 1, 0, 1, true, 0);
    CONV_PHASE(k0 + 1, 1, 1, true, 0);
    CONV_PHASE(k0 + 1, 2, 1, true, 0);
    CONV_PHASE(k0 + 1, 3, 1, true, 0);
  }
  CONV_PHASE(34, 0, 0, true, 0);
  CONV_PHASE(34, 1, 0, true, 0);
  CONV_PHASE(34, 2, 0, true, 0);
  CONV_PHASE(34, 3, 0, true, 0);
  CONV_PHASE(35, 0, 1, false, 1);
  CONV_PHASE(35, 1, 1, false, 2);
  CONV_PHASE(35, 2, 1, false, 2);
  CONV_PHASE(35, 3, 1, false, 2);

  __syncthreads();
  unsigned short* cb = co + (size_t)b * 256 * 16384;
  float* red1 = (float*)&lds[0][0];     // [8][128]
  float* red2 = red1 + 1024;
#pragma unroll
  for (int m = 0; m < 8; ++m) {
#pragma unroll
    for (int r = 0; r < 4; ++r) {
      int o = wm * 128 + m * 16 + lk * 4 + r;
      float bvv = bo[o];
      float s1 = 0.f, s2 = 0.f;
#pragma unroll
      for (int n = 0; n < 4; ++n) {
        int pix = wn * 64 + n * 16 + lr;
        int py = pix >> 4, px = pix & 15;
        float v = acc[m][n][r] + bvv;
        cb[(size_t)o * 16384 + (y0 + py) * 128 + x0 + px] = f2bf(v);
        s1 += v;
        s2 += v * v;
      }
      for (int off = 1; off < 16; off <<= 1) {
        s1 += __shfl_xor(s1, off, 64);
        s2 += __shfl_xor(s2, off, 64);
      }
      if (lr == 0) {
        int ol = m * 16 + lk * 4 + r;
        red1[wave * 128 + ol] = s1;
        red2[wave * 128 + ol] = s2;
      }
    }
  }
  __syncthreads();
  {
    int o = tid & 255, stat = tid >> 8;
    int wm2 = o >> 7, ol = o & 127;
    const float* rd = stat ? red2 : red1;
    float s = rd[(wm2 * 4 + 0) * 128 + ol] + rd[(wm2 * 4 + 1) * 128 + ol] +
              rd[(wm2 * 4 + 2) * 128 + ol] + rd[(wm2 * 4 + 3) * 128 + ol];
    bnp[((size_t)(b * 64 + tile) * 256 + o) * 2 + stat] = s;
  }
}

// ---------------- BN reduce + apply ----------------
__global__ __launch_bounds__(256) void k_bnred(
    const float* __restrict__ bnp, const float* __restrict__ gamma,
    const float* __restrict__ beta, float* __restrict__ bns) {
  const int o = blockIdx.x;
  const int tid = threadIdx.x;
  float s1 = 0.f, s2 = 0.f;
  for (int k = tid; k < 512; k += 256) {
    s1 += bnp[((size_t)k * 256 + o) * 2 + 0];
    s2 += bnp[((size_t)k * 256 + o) * 2 + 1];
  }
  __shared__ float r1[256], r2[256];
  r1[tid] = s1; r2[tid] = s2;
  __syncthreads();
  for (int off = 128; off > 0; off >>= 1) {
    if (tid < off) { r1[tid] += r1[tid + off]; r2[tid] += r2[tid + off]; }
    __syncthreads();
  }
  if (tid == 0) {
    const float cnt = 8.0f * 16384.0f;
    float mean = r1[0] / cnt;
    float var = r2[0] / cnt - mean * mean;
    float sc = gamma[o] * rsqrtf(var + 1e-5f);
    bns[o] = sc;
    bns[256 + o] = beta[o] - mean * sc;
  }
}

__global__ void k_bnapply(const unsigned short* __restrict__ co, float* __restrict__ out,
                          const float* __restrict__ bns) {
  size_t i = ((size_t)blockIdx.x * 256 + threadIdx.x) * 8;
  const size_t total = 33554432;
  const size_t stride = (size_t)gridDim.x * 256 * 8;
  for (; i < total; i += stride) {
    uint4 v = *(const uint4*)(co + i);
    int o = (int)((i >> 14) & 255);
    float sc = bns[o], shv = bns[256 + o];
    const unsigned short* pv = (const unsigned short*)&v;
    float r[8];
#pragma unroll
    for (int e = 0; e < 8; ++e) {
      float f = bf2f(pv[e]) * sc + shv;
      r[e] = f > 0.f ? f : 0.2f * f;
    }
    *(float4*)(out + i) = *(const float4*)&r[0];
    *(float4*)(out + i + 4) = *(const float4*)&r[4];
  }
}

// ---------------- launcher ----------------
extern "C" void kernel_launch(void* const* d_in, const int* in_sizes, int n_in,
                              void* d_out, int out_size, void* d_ws, size_t ws_size,
                              hipStream_t stream) {
  if (ws_size < WS_NEED) return;

  const float* x     = (const float*)d_in[0];
  const float* wq    = (const float*)d_in[1];
  const float* bq    = (const float*)d_in[2];
  const float* wk    = (const float*)d_in[3];
  const float* bk    = (const float*)d_in[4];
  const float* wv    = (const float*)d_in[5];
  const float* bv    = (const float*)d_in[6];
  const float* wo    = (const float*)d_in[7];
  const float* bo    = (const float*)d_in[8];
  const float* gamma = (const float*)d_in[9];
  const float* beta  = (const float*)d_in[10];
  float* out = (float*)d_out;
  char* ws = (char*)d_ws;

  unsigned short* Wb  = (unsigned short*)(ws + WB_OFF);
  unsigned short* Wob = (unsigned short*)(ws + WOB_OFF);
  unsigned short* Qn  = (unsigned short*)(ws + QN_OFF);
  unsigned short* Kn  = (unsigned short*)(ws + KN_OFF);
  unsigned short* Vn  = (unsigned short*)(ws + VN_OFF);
  unsigned short* Yn  = (unsigned short*)(ws + YN_OFF);
  float* part3 = (float*)(ws + YN_OFF);          // overlay: used before Yn is written
  unsigned short* co = (unsigned short*)(ws + QN_OFF);  // overlay: Qn dead after grams
  float* scores = (float*)(ws + SC_OFF);
  unsigned short* prb = (unsigned short*)(ws + PRB_OFF);
  float* bnp    = (float*)(ws + BNP_OFF);
  float* bns    = (float*)(ws + BNS_OFF);
  unsigned short* zp = (unsigned short*)(ws + ZP_OFF);

  k_prep<<<dim3(3072), dim3(256), 0, stream>>>(wq, wk, wv, wo, Wb, Wob, scores, (float*)zp);
  k_qkv<<<dim3(256, 8), dim3(256), 0, stream>>>(x, Wb, bq, bk, bv, Qn, Kn, Vn);
  k_gramA<<<dim3(128, 8), dim3(256), 0, stream>>>(Qn, Kn, scores, part3);
  k_smA<<<dim3(11, 8), dim3(256), 0, stream>>>(scores, part3, prb);
  k_pvA<<<dim3(320, 8), dim3(256), 0, stream>>>(Vn, prb, Yn);
  k_conv<<<dim3(512), dim3(512), 0, stream>>>(Yn, Wob, bo, zp, co, bnp);
  k_bnred<<<dim3(256), dim3(256), 0, stream>>>(bnp, gamma, beta, bns);
  k_bnapply<<<dim3(4096), dim3(256), 0, stream>>>(co, out, bns);
}